// Round 13
// baseline (306.844 us; speedup 1.0000x reference)
//
#include <hip/hip_runtime.h>
#include <math.h>

#define D_MODEL 1024
#define NUM_HEADS 16
#define DK 64
#define BATCH 2
#define SEQ 2048

using f32x4  = __attribute__((ext_vector_type(4))) float;
using bf16x8 = __attribute__((ext_vector_type(8))) short;
using us8    = __attribute__((ext_vector_type(8))) unsigned short;

__device__ __forceinline__ unsigned short f2b(float x) {  // fp32 -> bf16 RNE
    unsigned u = __float_as_uint(x);
    return (unsigned short)((u + 0x7FFF + ((u >> 16) & 1)) >> 16);
}
__device__ __forceinline__ float b2f(unsigned short h) {
    return __uint_as_float(((unsigned)h) << 16);
}
__device__ __forceinline__ void gl_lds16(const unsigned short* g, unsigned short* l) {
    __builtin_amdgcn_global_load_lds(
        (const __attribute__((address_space(1))) void*)g,
        (__attribute__((address_space(3))) void*)l, 16, 0, 0);
}

// ---------------------------------------------------------------------------
// Per-batch prefix scan of mask: pos[b][s] = #valid keys before s, nc[b]=count
// ---------------------------------------------------------------------------
__global__ __launch_bounds__(256) void mask_scan_kernel(
    const int* __restrict__ mask, int* __restrict__ pos, int* __restrict__ nc)
{
    const int b = blockIdx.x;
    const int tid = threadIdx.x;
    __shared__ int sums[256];
    int v[8]; int cnt = 0;
    const int base = b * SEQ + tid * 8;
    #pragma unroll
    for (int e = 0; e < 8; ++e) { v[e] = (mask[base + e] != 0) ? 1 : 0; cnt += v[e]; }
    sums[tid] = cnt;
    __syncthreads();
    for (int off = 1; off < 256; off <<= 1) {
        int t = (tid >= off) ? sums[tid - off] : 0;
        __syncthreads();
        sums[tid] += t;
        __syncthreads();
    }
    int run = sums[tid] - cnt;           // exclusive prefix
    #pragma unroll
    for (int e = 0; e < 8; ++e) { pos[base + e] = run; run += v[e]; }
    if (tid == 255) nc[b] = sums[255];
}

// ---------------------------------------------------------------------------
// fp32 [rows][1024] -> bf16 [rows][2048] = [hi | lo], row-XOR swizzle baked
// in (stored 16B block ss = logical block ss ^ (STORED_row & 7)).
// COMPACT=0: dst row = src row. COMPACT=1: masked rows skipped, dst row =
// b*SEQ + pos[row] (swizzle keyed by the stored row). Up to 4 pairs via
// blockIdx.y; grid.x = rows.
// ---------------------------------------------------------------------------
template <int COMPACT>
__global__ __launch_bounds__(256) void conv_hilo_kernel(
    const float* s0, const float* s1, const float* s2, const float* s3,
    unsigned short* d0, unsigned short* d1, unsigned short* d2, unsigned short* d3,
    int rows, const int* __restrict__ mask, const int* __restrict__ pos)
{
    const int y = blockIdx.y;
    const float* src = (y == 0) ? s0 : (y == 1) ? s1 : (y == 2) ? s2 : s3;
    unsigned short* dst = (y == 0) ? d0 : (y == 1) ? d1 : (y == 2) ? d2 : d3;
    const int id = blockIdx.x * 256 + threadIdx.x;
    if (id >= rows * 256) return;
    const int row = id >> 8;
    int drow = row;
    if (COMPACT) {
        if (!mask[row]) return;
        drow = (row >> 11) * SEQ + pos[row];
    }
    const int s   = id & 255;                // stored 16B-block index in [0,256)
    const int g   = s >> 3, ss = s & 7;
    const int lb  = ss ^ (drow & 7);         // logical block (key = STORED row)
    const int srcg = g & 15;                 // source 64-col group
    const bool lo = (g >> 4) != 0;           // second K-half = residual

    const float* p = src + (size_t)row * 1024 + srcg * 64 + lb * 8;
    const float4 a = *(const float4*)p;
    const float4 bq = *(const float4*)(p + 4);
    const float xs[8] = {a.x, a.y, a.z, a.w, bq.x, bq.y, bq.z, bq.w};
    us8 o;
    #pragma unroll
    for (int e = 0; e < 8; ++e) {
        float x = xs[e];
        if (lo) { unsigned short h = f2b(x); x = x - b2f(h); }
        o[e] = f2b(x);
    }
    *(us8*)&dst[(size_t)drow * 2048 + s * 8] = o;
}

// ---------------------------------------------------------------------------
// bf16 MFMA GEMM, 128x64 tile (r7-proven: 48 KB LDS -> 3 blocks/CU, 512
// blocks), BK=64, 2-buf drain-sync. Virtual-K sweep of 48 tiles over [hi|lo]
// operands (3-term hi/lo product): vkt 0-15 Ahi*Whi, 16-31 Alo*Whi,
// 32-47 Ahi*Wlo.
// MODE epilogue:
//   0: fp32 [M][1024]  (output GEMM -> d_out)
//   1: Q2  bf16 [bh][s][128] = 0.125*(hi|lo), block-XOR by s&7
//   2: K2  bf16 [bh][p][128] hi|lo  (A2 rows pre-COMPACTED; store if p<nc)
//   3: VT2 bf16 [bh][d][2048] key-block swz (pre-COMPACTED; store if p<nc)
// MODE 2/3: whole tile early-exits when its 128-row stripe is >= nc[b].
// ---------------------------------------------------------------------------
template <int MODE>
__global__ __launch_bounds__(256) void mfma_gemm_kernel(
    const unsigned short* __restrict__ A2, const unsigned short* __restrict__ W2,
    const float* __restrict__ bias, float* __restrict__ Cf,
    unsigned short* __restrict__ Cb, const int* __restrict__ ncArr)
{
    constexpr int KS = 2048;
    __shared__ bf16x8 Asl[2][1024];   // 128 rows x 8 x 16B
    __shared__ bf16x8 Bsl[2][512];    // 64 rows x 8 x 16B

    const int bm = blockIdx.x * 128, bn = blockIdx.y * 64;
    if (MODE == 2 || MODE == 3) {
        if ((bm & (SEQ - 1)) >= ncArr[bm >> 11]) return;   // uniform exit
    }

    const int tid = threadIdx.x;
    const int wv = tid >> 6, ln = tid & 63;
    const int wm = wv >> 1, wn = wv & 1;
    const int x = ln & 15, y = ln >> 4;

    f32x4 acc[4][2] = {};

    const unsigned short* Ab = A2 + (size_t)bm * KS;
    const unsigned short* Bb = W2 + (size_t)bn * KS;
    const int srow = ln >> 3;
    const int scol = (ln & 7) * 8;

    auto stage = [&](int bufi, int vkt) {
        const int a_kt = (vkt < 32) ? vkt : vkt - 32;
        const int w_kt = (vkt < 32) ? (vkt & 15) : vkt - 16;
        #pragma unroll
        for (int c = 0; c < 4; ++c) {
            const int rowb = wv * 32 + c * 8;
            gl_lds16(Ab + (size_t)(rowb + srow) * KS + a_kt * 64 + scol,
                     (unsigned short*)&Asl[bufi][rowb << 3]);
        }
        #pragma unroll
        for (int c = 0; c < 2; ++c) {
            const int rowb = wv * 16 + c * 8;
            gl_lds16(Bb + (size_t)(rowb + srow) * KS + w_kt * 64 + scol,
                     (unsigned short*)&Bsl[bufi][rowb << 3]);
        }
    };

    stage(0, 0);
    asm volatile("s_waitcnt vmcnt(0)" ::: "memory");
    __syncthreads();

    int buf = 0;
    for (int kt = 0; kt < 48; ++kt) {
        if (kt < 47) stage(buf ^ 1, kt + 1);
        #pragma unroll
        for (int half = 0; half < 2; ++half) {
            bf16x8 af[4], bfr[2];
            #pragma unroll
            for (int mf = 0; mf < 4; ++mf) {
                const int r = wm * 64 + mf * 16 + x;
                af[mf] = Asl[buf][(r << 3) | ((half * 4 + y) ^ (r & 7))];
            }
            #pragma unroll
            for (int nf = 0; nf < 2; ++nf) {
                const int r = wn * 32 + nf * 16 + x;
                bfr[nf] = Bsl[buf][(r << 3) | ((half * 4 + y) ^ (r & 7))];
            }
            #pragma unroll
            for (int mf = 0; mf < 4; ++mf)
                #pragma unroll
                for (int nf = 0; nf < 2; ++nf)
                    acc[mf][nf] = __builtin_amdgcn_mfma_f32_16x16x32_bf16(
                        af[mf], bfr[nf], acc[mf][nf], 0, 0, 0);
        }
        asm volatile("s_waitcnt vmcnt(0)" ::: "memory");
        __syncthreads();
        buf ^= 1;
    }

    // epilogue: C/D layout col=lane&15 (n), row=(lane>>4)*4+r (m)  [m89]
    #pragma unroll
    for (int nf = 0; nf < 2; ++nf) {
        const int n = bn + wn * 32 + nf * 16 + x;
        const float bv = bias[n];
        #pragma unroll
        for (int mf = 0; mf < 4; ++mf) {
            const int mbase = bm + wm * 64 + mf * 16 + y * 4;
            #pragma unroll
            for (int r = 0; r < 4; ++r) {
                const int m = mbase + r;
                const float v = acc[mf][nf][r] + bv;
                const int b = m >> 11, s = m & (SEQ - 1);
                const int hh = n >> 6, dd = n & 63;
                if (MODE == 0) {
                    Cf[(size_t)m * D_MODEL + n] = v;
                } else if (MODE == 1) {
                    const float sv = v * 0.125f;
                    const unsigned short hi = f2b(sv);
                    const unsigned short lo = f2b(sv - b2f(hi));
                    const int blk = (dd >> 3) ^ (s & 7), i = dd & 7;
                    unsigned short* qp = Cb +
                        ((size_t)((b * NUM_HEADS + hh) * SEQ + s)) * 128;
                    qp[blk * 8 + i] = hi;
                    qp[64 + blk * 8 + i] = lo;
                } else if (MODE == 2) {
                    if (s < ncArr[b]) {          // s IS the compacted index p
                        const unsigned short hi = f2b(v);
                        const unsigned short lo = f2b(v - b2f(hi));
                        const int blk = (dd >> 3) ^ (s & 7), i = dd & 7;
                        unsigned short* kp = Cb +
                            ((size_t)((b * NUM_HEADS + hh) * SEQ + s)) * 128;
                        kp[blk * 8 + i] = hi;
                        kp[64 + blk * 8 + i] = lo;
                    }
                } else {
                    if (s < ncArr[b]) {
                        const int tile = s >> 6, w = s & 63;
                        const int blk = (w >> 3) ^ (dd & 7), i = w & 7;
                        Cb[((size_t)((b * NUM_HEADS + hh) * DK + dd)) * SEQ +
                           tile * 64 + blk * 8 + i] = f2b(v);
                    }
                }
            }
        }
    }
}

// ---------------------------------------------------------------------------
// MFMA flash attention over COMPACTED keys (r7/r9-proven: single 32 KB
// buffer). Q read pre-converted (Q2); epilogue writes the bf16 [hi|lo]
// row-XOR-swizzled O-GEMM activation directly.
// ---------------------------------------------------------------------------
__global__ __launch_bounds__(256, 3) void attn_mfma_kernel(
    const unsigned short* __restrict__ Q2, const unsigned short* __restrict__ K2,
    const unsigned short* __restrict__ VT2, const int* __restrict__ ncArr,
    unsigned short* __restrict__ ACT)
{
    __shared__ __align__(16) unsigned short SM[16384];   // 32 KB
    unsigned short* Khi = SM;            // [64 key][64 dk] (swz)
    unsigned short* Klo = SM + 4096;
    unsigned short* VTs = SM + 8192;     // [64 d][64 key] (swz)

    const int tid = threadIdx.x;
    const int wave = tid >> 6, lane = tid & 63;
    const int lo4 = lane & 15, hi4 = lane >> 4;
    unsigned short* Pw = SM + 12288 + wave * 1024;  // [16 q][64 key] bf16

    const int orig = blockIdx.x;
    const int swz = (orig & 7) * 128 + (orig >> 3);  // 1024%8==0: bijective
    const int bh = swz >> 5, qblk = swz & 31;
    const int b = bh >> 4, h = bh & 15;

    const unsigned short* Kb = K2 + (size_t)bh * SEQ * 128;
    const unsigned short* Vb = VT2 + (size_t)bh * DK * SEQ;

    const int ncb = ncArr[b];
    const int ntiles = (ncb + 63) >> 6;

    // Q fragments from Q2 (already 0.125-scaled hi/lo, XOR-swizzled by s&7)
    const int qr = qblk * 64 + wave * 16 + lo4;
    const unsigned short* Q2row = Q2 + (size_t)(bh * SEQ + qr) * 128;
    bf16x8 qhi[2], qlo[2];
    #pragma unroll
    for (int c = 0; c < 2; ++c) {
        const int blk = ((c * 4 + hi4) ^ (qr & 7)) * 8;
        qhi[c] = *(const bf16x8*)&Q2row[blk];
        qlo[c] = *(const bf16x8*)&Q2row[64 + blk];
    }

    f32x4 ctx[4] = {};   // ctx^T frags: row d = dt*16+hi4*4+r, col q = lo4
    float m = -INFINITY, l = 0.f;

    for (int t = 0; t < ntiles; ++t) {
        const int k0 = t * 64;
        __syncthreads();
        // stage 24 KB: Khi(512 x16B) | Klo(512) | VT(512)
        #pragma unroll
        for (int j = 0; j < 6; ++j) {
            const int g = j * 256 + wave * 64;   // wave-uniform dest base
            const int gi = g + lane;
            const unsigned short* src;
            if (gi < 512) {
                src = Kb + (size_t)(k0 + (gi >> 3)) * 128 + (gi & 7) * 8;
            } else if (gi < 1024) {
                const int g2 = gi - 512;
                src = Kb + (size_t)(k0 + (g2 >> 3)) * 128 + 64 + (g2 & 7) * 8;
            } else {
                const int g3 = gi - 1024;
                src = Vb + (size_t)(g3 >> 3) * SEQ + k0 + (g3 & 7) * 8;
            }
            gl_lds16(src, SM + (size_t)g * 8);
        }
        asm volatile("s_waitcnt vmcnt(0)" ::: "memory");
        __syncthreads();

        // S^T = K . Q^T : rows = key, cols = q (hi/lo 3-term, fp32-accurate)
        f32x4 sc[4];
        #pragma unroll
        for (int kt = 0; kt < 4; ++kt) {
            f32x4 s = {0.f, 0.f, 0.f, 0.f};
            const int row = kt * 16 + lo4;
            const int rx = row & 7;
            #pragma unroll
            for (int c = 0; c < 2; ++c) {
                const int blk = ((c * 4 + hi4) ^ rx) * 8;
                const bf16x8 kh = *(bf16x8*)&Khi[row * 64 + blk];
                const bf16x8 kl = *(bf16x8*)&Klo[row * 64 + blk];
                s = __builtin_amdgcn_mfma_f32_16x16x32_bf16(kh, qhi[c], s, 0, 0, 0);
                s = __builtin_amdgcn_mfma_f32_16x16x32_bf16(kl, qhi[c], s, 0, 0, 0);
                s = __builtin_amdgcn_mfma_f32_16x16x32_bf16(kh, qlo[c], s, 0, 0, 0);
            }
            sc[kt] = s;
        }

        // row-max; tail tile masks invalid keys (kidx >= ncb) to -1e30
        float cmax = -1e30f;
        if (k0 + 64 <= ncb) {
            #pragma unroll
            for (int kt = 0; kt < 4; ++kt)
                #pragma unroll
                for (int r = 0; r < 4; ++r) cmax = fmaxf(cmax, sc[kt][r]);
        } else {
            #pragma unroll
            for (int kt = 0; kt < 4; ++kt)
                #pragma unroll
                for (int r = 0; r < 4; ++r) {
                    const int kidx = k0 + kt * 16 + hi4 * 4 + r;
                    const float sv = (kidx < ncb) ? sc[kt][r] : -1e30f;
                    sc[kt][r] = sv;
                    cmax = fmaxf(cmax, sv);
                }
        }
        cmax = fmaxf(cmax, __shfl_xor(cmax, 16));
        cmax = fmaxf(cmax, __shfl_xor(cmax, 32));

        const float mnew = fmaxf(m, cmax);
        const float e1 = __expf(m - mnew);   // m=-inf pre-first-tile -> 0
        m = mnew;

        float ps = 0.f;
        #pragma unroll
        for (int kt = 0; kt < 4; ++kt) {
            const float pv0 = __expf(sc[kt][0] - mnew);  // -1e30 -> exp = 0
            const float pv1 = __expf(sc[kt][1] - mnew);
            const float pv2 = __expf(sc[kt][2] - mnew);
            const float pv3 = __expf(sc[kt][3] - mnew);
            ps += (pv0 + pv1) + (pv2 + pv3);
            const unsigned w0 = (unsigned)f2b(pv0) | ((unsigned)f2b(pv1) << 16);
            const unsigned w1 = (unsigned)f2b(pv2) | ((unsigned)f2b(pv3) << 16);
            const int blk16 = (kt * 2 + (hi4 >> 1)) ^ (lo4 & 7);
            unsigned* dst = (unsigned*)&Pw[lo4 * 64 + blk16 * 8 + (hi4 & 1) * 4];
            dst[0] = w0; dst[1] = w1;
        }
        ps += __shfl_xor(ps, 16);
        ps += __shfl_xor(ps, 32);
        l = l * e1 + ps;

        #pragma unroll
        for (int dt = 0; dt < 4; ++dt)
            #pragma unroll
            for (int r = 0; r < 4; ++r) ctx[dt][r] *= e1;

        // ctx^T += V^T . P^T  (same-wave LDS RAW: compiler orders via lgkmcnt)
        #pragma unroll
        for (int c = 0; c < 2; ++c) {
            const bf16x8 pf =
                *(bf16x8*)&Pw[lo4 * 64 + (((c * 4 + hi4) ^ (lo4 & 7)) * 8)];
            #pragma unroll
            for (int dt = 0; dt < 4; ++dt) {
                const int row = dt * 16 + lo4;
                const bf16x8 vf =
                    *(bf16x8*)&VTs[row * 64 + (((c * 4 + hi4) ^ (row & 7)) * 8)];
                ctx[dt] = __builtin_amdgcn_mfma_f32_16x16x32_bf16(vf, pf, ctx[dt], 0, 0, 0);
            }
        }
    }

    // epilogue: normalize, transpose via LDS (stride 68, conflict-free),
    // FUSED bf16 [hi|lo] swizzled activation write
    __syncthreads();
    const float inv = (l > 0.f) ? (1.f / l) : 0.f;   // l==0: fully masked -> 0
    float* OutL = (float*)SM;                        // [64 q][68] fp32
    #pragma unroll
    for (int dt = 0; dt < 4; ++dt)
        #pragma unroll
        for (int r = 0; r < 4; ++r)
            OutL[(wave * 16 + lo4) * 68 + dt * 16 + hi4 * 4 + r] = ctx[dt][r] * inv;
    __syncthreads();
    {
        const int row = tid >> 2, cb = (tid & 3) * 16;
        const int mrow = b * SEQ + qblk * 64 + row;      // global act row
        unsigned short* arow = ACT + (size_t)mrow * 2048;
        #pragma unroll
        for (int u = 0; u < 2; ++u) {
            const int lb = (cb >> 3) + u;                // logical 8-col block
            const int ss = lb ^ (mrow & 7);              // stored (swizzled)
            us8 hv, lv;
            #pragma unroll
            for (int i = 0; i < 8; ++i) {
                const float v = OutL[row * 68 + cb + u * 8 + i];
                const unsigned short hb = f2b(v);
                hv[i] = (short)hb;
                lv[i] = (short)f2b(v - b2f(hb));
            }
            *(us8*)&arow[h * 64 + ss * 8] = hv;          // hi half (group h)
            *(us8*)&arow[1024 + h * 64 + ss * 8] = lv;   // lo half
        }
    }
}

// ---------------------------------------------------------------------------
// fp32 fallback path (only if ws too small)
// ---------------------------------------------------------------------------
template <int SPLIT>
__global__ __launch_bounds__(256) void gemm_bias_kernel(
    const float* __restrict__ A, const float* __restrict__ W,
    const float* __restrict__ bias, float* __restrict__ C,
    int M, int N, int K)
{
    constexpr int TILE = 64, KT = 16;
    __shared__ float As[KT][TILE + 4];
    __shared__ float Ws[KT][TILE + 4];
    const int tid = threadIdx.x;
    const int tx = tid & 15, ty = tid >> 4;
    const int bm = blockIdx.x * TILE, bn = blockIdx.y * TILE;
    const int lrow = tid >> 2, lk4 = (tid & 3) << 2;
    float acc[4][4] = {{0.f}};
    for (int k0 = 0; k0 < K; k0 += KT) {
        const float4 a4 = *(const float4*)&A[(size_t)(bm + lrow) * K + k0 + lk4];
        const float4 w4 = *(const float4*)&W[(size_t)(bn + lrow) * K + k0 + lk4];
        __syncthreads();
        As[lk4 + 0][lrow] = a4.x; As[lk4 + 1][lrow] = a4.y;
        As[lk4 + 2][lrow] = a4.z; As[lk4 + 3][lrow] = a4.w;
        Ws[lk4 + 0][lrow] = w4.x; Ws[lk4 + 1][lrow] = w4.y;
        Ws[lk4 + 2][lrow] = w4.z; Ws[lk4 + 3][lrow] = w4.w;
        __syncthreads();
        #pragma unroll
        for (int kk = 0; kk < KT; ++kk) {
            const float4 av = *(const float4*)&As[kk][ty << 2];
            const float4 wv = *(const float4*)&Ws[kk][tx << 2];
            acc[0][0] += av.x * wv.x; acc[0][1] += av.x * wv.y; acc[0][2] += av.x * wv.z; acc[0][3] += av.x * wv.w;
            acc[1][0] += av.y * wv.x; acc[1][1] += av.y * wv.y; acc[1][2] += av.y * wv.z; acc[1][3] += av.y * wv.w;
            acc[2][0] += av.z * wv.x; acc[2][1] += av.z * wv.y; acc[2][2] += av.z * wv.z; acc[2][3] += av.z * wv.w;
            acc[3][0] += av.w * wv.x; acc[3][1] += av.w * wv.y; acc[3][2] += av.w * wv.z; acc[3][3] += av.w * wv.w;
        }
    }
    const float4 bb = *(const float4*)&bias[bn + (tx << 2)];
    #pragma unroll
    for (int i = 0; i < 4; ++i) {
        const int row = bm + (ty << 2) + i;
        float4 o;
        o.x = acc[i][0] + bb.x; o.y = acc[i][1] + bb.y;
        o.z = acc[i][2] + bb.z; o.w = acc[i][3] + bb.w;
        if (SPLIT) {
            const int b = row >> 11, s = row & (SEQ - 1), hh = bn >> 6;
            *(float4*)&C[((size_t)((b * NUM_HEADS + hh) * SEQ + s)) * DK + (tx << 2)] = o;
        } else {
            *(float4*)&C[(size_t)row * N + bn + (tx << 2)] = o;
        }
    }
}

__global__ __launch_bounds__(256, 2) void attn_fp32_kernel(
    const float* __restrict__ Q, const float* __restrict__ K,
    const float* __restrict__ V, const int* __restrict__ mask,
    float* __restrict__ OUT)
{
    const int qb = blockIdx.x, h = blockIdx.y, b = blockIdx.z;
    const int wave = threadIdx.x >> 6, lane = threadIdx.x & 63;
    const int tid = threadIdx.x;
    const int bh = b * NUM_HEADS + h;
    const float* Qb = Q + (size_t)bh * SEQ * DK;
    const float* Kb = K + (size_t)bh * SEQ * DK;
    const float* Vb = V + (size_t)bh * SEQ * DK;
    const int* mb = mask + b * SEQ;
    __shared__ float Ks[64][68];
    __shared__ float Vs[64][68];
    const int row = qb * 256 + wave * 64 + lane;
    float q[DK], ctx[DK];
    #pragma unroll
    for (int d4 = 0; d4 < 16; ++d4) {
        const float4 t = *(const float4*)&Qb[(size_t)row * DK + 4 * d4];
        q[4*d4] = t.x; q[4*d4+1] = t.y; q[4*d4+2] = t.z; q[4*d4+3] = t.w;
        ctx[4*d4] = 0.f; ctx[4*d4+1] = 0.f; ctx[4*d4+2] = 0.f; ctx[4*d4+3] = 0.f;
    }
    float m = -INFINITY, l = 0.f;
    for (int t = 0; t < SEQ / 64; ++t) {
        const int k0 = t * 64;
        const float* Kt = Kb + (size_t)k0 * DK;
        const float* Vt = Vb + (size_t)k0 * DK;
        __syncthreads();
        #pragma unroll
        for (int i = 0; i < 4; ++i) {
            const int f4 = i * 256 + tid;
            const int r = f4 >> 4, c = (f4 & 15) << 2;
            *(float4*)&Ks[r][c] = *(const float4*)&Kt[4 * f4];
            *(float4*)&Vs[r][c] = *(const float4*)&Vt[4 * f4];
        }
        __syncthreads();
        const unsigned long long mbits = __ballot(mb[k0 + lane] != 0);
        if (mbits == 0ULL) continue;
        for (int c0 = 0; c0 < 64; c0 += 16) {
            const unsigned bits = (unsigned)((mbits >> c0) & 0xFFFFULL);
            if (!bits) continue;
            float sc[16];
            #pragma unroll
            for (int j = 0; j < 16; ++j) {
                if (!((bits >> j) & 1u)) { sc[j] = -INFINITY; continue; }
                float a0 = 0.f, a1 = 0.f, a2 = 0.f, a3 = 0.f;
                #pragma unroll
                for (int d4 = 0; d4 < 16; ++d4) {
                    const float4 kv = *(const float4*)&Ks[c0 + j][4 * d4];
                    a0 += q[4*d4] * kv.x; a1 += q[4*d4+1] * kv.y;
                    a2 += q[4*d4+2] * kv.z; a3 += q[4*d4+3] * kv.w;
                }
                sc[j] = ((a0 + a1) + (a2 + a3)) * 0.125f;
            }
            float cmax = sc[0];
            #pragma unroll
            for (int j = 1; j < 16; ++j) cmax = fmaxf(cmax, sc[j]);
            if (cmax > m) {
                const float scale = __expf(m - cmax);
                l *= scale;
                #pragma unroll
                for (int d = 0; d < DK; ++d) ctx[d] *= scale;
                m = cmax;
            }
            #pragma unroll
            for (int j = 0; j < 16; ++j) {
                if (!((bits >> j) & 1u)) continue;
                const float p = __expf(sc[j] - m);
                l += p;
                #pragma unroll
                for (int d4 = 0; d4 < 16; ++d4) {
                    const float4 vv = *(const float4*)&Vs[c0 + j][4 * d4];
                    ctx[4*d4] += p * vv.x; ctx[4*d4+1] += p * vv.y;
                    ctx[4*d4+2] += p * vv.z; ctx[4*d4+3] += p * vv.w;
                }
            }
        }
    }
    const float inv = (l > 0.f) ? (1.f / l) : 0.f;
    float* dst = OUT + ((size_t)(b * SEQ + row)) * D_MODEL + h * DK;
    #pragma unroll
    for (int d4 = 0; d4 < 16; ++d4) {
        float4 o;
        o.x = ctx[4*d4] * inv; o.y = ctx[4*d4+1] * inv;
        o.z = ctx[4*d4+2] * inv; o.w = ctx[4*d4+3] * inv;
        *(float4*)&dst[4 * d4] = o;
    }
}

// ---------------------------------------------------------------------------
extern "C" void kernel_launch(void* const* d_in, const int* in_sizes, int n_in,
                              void* d_out, int out_size, void* d_ws, size_t ws_size,
                              hipStream_t stream)
{
    const float* query = (const float*)d_in[0];
    const float* key_  = (const float*)d_in[1];
    const float* value = (const float*)d_in[2];
    const int*   mask  = (const int*)d_in[3];
    const float* Wq = (const float*)d_in[4];
    const float* bq = (const float*)d_in[5];
    const float* Wk = (const float*)d_in[6];
    const float* bk = (const float*)d_in[7];
    const float* Wv = (const float*)d_in[8];
    const float* bv = (const float*)d_in[9];
    const float* Wo = (const float*)d_in[10];
    const float* bo = (const float*)d_in[11];
    float* out = (float*)d_out;

    const int M = BATCH * SEQ;                            // 4096
    const size_t ACT_B  = (size_t)M * 2048 * 2;           // 16.78 MB
    const size_t W2_B   = (size_t)D_MODEL * 2048 * 2;     // 4.19 MB
    const size_t K2_B   = (size_t)32 * SEQ * 128 * 2;     // 16.78 MB
    const size_t VT2_B  = (size_t)32 * DK * SEQ * 2;      // 8.39 MB
    const size_t Q2_B   = K2_B;                           // 16.78 MB
    const size_t POS_B  = (size_t)BATCH * SEQ * 4 + 256;

    char* base = (char*)d_ws;
    unsigned short* actQ = (unsigned short*)(base);
    unsigned short* actK = (unsigned short*)(base + ACT_B);
    unsigned short* actV = (unsigned short*)(base + 2 * ACT_B);
    unsigned short* w2q  = (unsigned short*)(base + 3 * ACT_B);
    unsigned short* w2k  = (unsigned short*)((char*)w2q + W2_B);
    unsigned short* w2v  = (unsigned short*)((char*)w2k + W2_B);
    unsigned short* w2o  = (unsigned short*)((char*)w2v + W2_B);
    unsigned short* k2   = (unsigned short*)((char*)w2o + W2_B);
    unsigned short* vt2  = (unsigned short*)((char*)k2 + K2_B);
    unsigned short* q2   = (unsigned short*)((char*)vt2 + VT2_B);
    int* posArr = (int*)((char*)q2 + Q2_B);
    int* ncArr  = posArr + BATCH * SEQ;
    const size_t need = 3 * ACT_B + 4 * W2_B + K2_B + VT2_B + Q2_B + POS_B; // ~109 MB

    if (ws_size >= need) {
        mask_scan_kernel<<<BATCH, 256, 0, stream>>>(mask, posArr, ncArr);

        conv_hilo_kernel<0><<<dim3(D_MODEL, 4), 256, 0, stream>>>(
            Wq, Wk, Wv, Wo, w2q, w2k, w2v, w2o, D_MODEL, nullptr, nullptr);
        conv_hilo_kernel<0><<<dim3(M, 1), 256, 0, stream>>>(
            query, nullptr, nullptr, nullptr, actQ, nullptr, nullptr, nullptr,
            M, nullptr, nullptr);
        conv_hilo_kernel<1><<<dim3(M, 2), 256, 0, stream>>>(   // compacted rows
            key_, value, nullptr, nullptr, actK, actV, nullptr, nullptr,
            M, mask, posArr);

        dim3 ggrid(M / 128, D_MODEL / 64);                // 32 x 16 = 512 blocks
        mfma_gemm_kernel<2><<<ggrid, 256, 0, stream>>>(actK, w2k, bk, nullptr, k2, ncArr);
        mfma_gemm_kernel<3><<<ggrid, 256, 0, stream>>>(actV, w2v, bv, nullptr, vt2, ncArr);
        mfma_gemm_kernel<1><<<ggrid, 256, 0, stream>>>(actQ, w2q, bq, nullptr, q2, ncArr);

        // attn writes the O-GEMM activation (actK is dead) directly as hi|lo
        attn_mfma_kernel<<<1024, 256, 0, stream>>>(q2, k2, vt2, ncArr, actK);

        mfma_gemm_kernel<0><<<ggrid, 256, 0, stream>>>(actK, w2o, bo, out, nullptr, ncArr);
    } else {
        float* q_ws = (float*)(base);
        float* k_ws = (float*)(base + (size_t)M * D_MODEL * 4);
        float* v_ws = (float*)(base + 2 * (size_t)M * D_MODEL * 4);
        float* c_ws = (float*)(base + 3 * (size_t)M * D_MODEL * 4);
        dim3 ggrid(M / 64, D_MODEL / 64);
        gemm_bias_kernel<1><<<ggrid, 256, 0, stream>>>(query, Wq, bq, q_ws, M, D_MODEL, D_MODEL);
        gemm_bias_kernel<1><<<ggrid, 256, 0, stream>>>(key_,  Wk, bk, k_ws, M, D_MODEL, D_MODEL);
        gemm_bias_kernel<1><<<ggrid, 256, 0, stream>>>(value, Wv, bv, v_ws, M, D_MODEL, D_MODEL);
        dim3 agrid(SEQ / 256, NUM_HEADS, BATCH);
        attn_fp32_kernel<<<agrid, 256, 0, stream>>>(q_ws, k_ws, v_ws, mask, c_ws);
        gemm_bias_kernel<0><<<ggrid, 256, 0, stream>>>(c_ws, Wo, bo, out, M, D_MODEL, D_MODEL);
    }
}

// Round 14
// 300.649 us; speedup vs baseline: 1.0206x; 1.0206x over previous
//
#include <hip/hip_runtime.h>
#include <math.h>

#define D_MODEL 1024
#define NUM_HEADS 16
#define DK 64
#define BATCH 2
#define SEQ 2048

using f32x4  = __attribute__((ext_vector_type(4))) float;
using bf16x8 = __attribute__((ext_vector_type(8))) short;
using us8    = __attribute__((ext_vector_type(8))) unsigned short;

__device__ __forceinline__ unsigned short f2b(float x) {  // fp32 -> bf16 RNE
    unsigned u = __float_as_uint(x);
    return (unsigned short)((u + 0x7FFF + ((u >> 16) & 1)) >> 16);
}
__device__ __forceinline__ float b2f(unsigned short h) {
    return __uint_as_float(((unsigned)h) << 16);
}
__device__ __forceinline__ void gl_lds16(const unsigned short* g, unsigned short* l) {
    __builtin_amdgcn_global_load_lds(
        (const __attribute__((address_space(1))) void*)g,
        (__attribute__((address_space(3))) void*)l, 16, 0, 0);
}

// ---------------------------------------------------------------------------
// Per-batch prefix scan of mask: pos[b][s] = #valid keys before s, nc[b]=count
// ---------------------------------------------------------------------------
__global__ __launch_bounds__(256) void mask_scan_kernel(
    const int* __restrict__ mask, int* __restrict__ pos, int* __restrict__ nc)
{
    const int b = blockIdx.x;
    const int tid = threadIdx.x;
    __shared__ int sums[256];
    int v[8]; int cnt = 0;
    const int base = b * SEQ + tid * 8;
    #pragma unroll
    for (int e = 0; e < 8; ++e) { v[e] = (mask[base + e] != 0) ? 1 : 0; cnt += v[e]; }
    sums[tid] = cnt;
    __syncthreads();
    for (int off = 1; off < 256; off <<= 1) {
        int t = (tid >= off) ? sums[tid - off] : 0;
        __syncthreads();
        sums[tid] += t;
        __syncthreads();
    }
    int run = sums[tid] - cnt;           // exclusive prefix
    #pragma unroll
    for (int e = 0; e < 8; ++e) { pos[base + e] = run; run += v[e]; }
    if (tid == 255) nc[b] = sums[255];
}

// ---------------------------------------------------------------------------
// fp32 [rows][1024] -> bf16 [rows][2048] = [hi | lo], row-XOR swizzle baked
// in (stored 16B block ss = logical block ss ^ (STORED_row & 7)).
// COMPACT=0: dst row = src row. COMPACT=1: masked rows skipped, dst row =
// b*SEQ + pos[row] (swizzle keyed by the stored row). Up to 4 pairs via
// blockIdx.y; grid.x = rows.
// ---------------------------------------------------------------------------
template <int COMPACT>
__global__ __launch_bounds__(256) void conv_hilo_kernel(
    const float* s0, const float* s1, const float* s2, const float* s3,
    unsigned short* d0, unsigned short* d1, unsigned short* d2, unsigned short* d3,
    int rows, const int* __restrict__ mask, const int* __restrict__ pos)
{
    const int y = blockIdx.y;
    const float* src = (y == 0) ? s0 : (y == 1) ? s1 : (y == 2) ? s2 : s3;
    unsigned short* dst = (y == 0) ? d0 : (y == 1) ? d1 : (y == 2) ? d2 : d3;
    const int id = blockIdx.x * 256 + threadIdx.x;
    if (id >= rows * 256) return;
    const int row = id >> 8;
    int drow = row;
    if (COMPACT) {
        if (!mask[row]) return;
        drow = (row >> 11) * SEQ + pos[row];
    }
    const int s   = id & 255;                // stored 16B-block index in [0,256)
    const int g   = s >> 3, ss = s & 7;
    const int lb  = ss ^ (drow & 7);         // logical block (key = STORED row)
    const int srcg = g & 15;                 // source 64-col group
    const bool lo = (g >> 4) != 0;           // second K-half = residual

    const float* p = src + (size_t)row * 1024 + srcg * 64 + lb * 8;
    const float4 a = *(const float4*)p;
    const float4 bq = *(const float4*)(p + 4);
    const float xs[8] = {a.x, a.y, a.z, a.w, bq.x, bq.y, bq.z, bq.w};
    us8 o;
    #pragma unroll
    for (int e = 0; e < 8; ++e) {
        float x = xs[e];
        if (lo) { unsigned short h = f2b(x); x = x - b2f(h); }
        o[e] = f2b(x);
    }
    *(us8*)&dst[(size_t)drow * 2048 + s * 8] = o;
}

// ---------------------------------------------------------------------------
// bf16 MFMA GEMM, 128x64 tile, BK=64. Virtual-K sweep of 48 tiles over
// [hi|lo] operands (3-term hi/lo product): vkt 0-15 Ahi*Whi, 16-31 Alo*Whi,
// 32-47 Ahi*Wlo.
// NEW (r13): 3-buffer LDS rotation (72 KB), loads issued 2 tiles ahead,
// counted s_waitcnt vmcnt(6) + RAW s_barrier (no vmcnt(0) drain per iter).
// r9 proved this counted-vmcnt pattern numerically correct; occupancy
// unchanged (grid 512 = 2 blocks/CU caps it regardless of 48 vs 72 KB).
// MODE epilogue:
//   0: fp32 [M][1024]  (output GEMM -> d_out)
//   1: Q2  bf16 [bh][s][128] = 0.125*(hi|lo), block-XOR by s&7
//   2: K2  bf16 [bh][p][128] hi|lo  (A2 rows pre-COMPACTED; store if p<nc)
//   3: VT2 bf16 [bh][d][2048] key-block swz (pre-COMPACTED; store if p<nc)
// MODE 2/3: whole tile early-exits when its 128-row stripe is >= nc[b].
// ---------------------------------------------------------------------------
template <int MODE>
__global__ __launch_bounds__(256) void mfma_gemm_kernel(
    const unsigned short* __restrict__ A2, const unsigned short* __restrict__ W2,
    const float* __restrict__ bias, float* __restrict__ Cf,
    unsigned short* __restrict__ Cb, const int* __restrict__ ncArr)
{
    constexpr int KS = 2048;
    __shared__ bf16x8 Asl[3][1024];   // 3 bufs x 128 rows x 8 x 16B = 48 KB
    __shared__ bf16x8 Bsl[3][512];    // 3 bufs x  64 rows x 8 x 16B = 24 KB

    const int bm = blockIdx.x * 128, bn = blockIdx.y * 64;
    if (MODE == 2 || MODE == 3) {
        if ((bm & (SEQ - 1)) >= ncArr[bm >> 11]) return;   // uniform exit
    }

    const int tid = threadIdx.x;
    const int wv = tid >> 6, ln = tid & 63;
    const int wm = wv >> 1, wn = wv & 1;
    const int x = ln & 15, y = ln >> 4;

    f32x4 acc[4][2] = {};

    const unsigned short* Ab = A2 + (size_t)bm * KS;
    const unsigned short* Bb = W2 + (size_t)bn * KS;
    const int srow = ln >> 3;
    const int scol = (ln & 7) * 8;

    auto stage = [&](int bufi, int vkt) {    // 6 loads per wave per stage
        const int a_kt = (vkt < 32) ? vkt : vkt - 32;
        const int w_kt = (vkt < 32) ? (vkt & 15) : vkt - 16;
        #pragma unroll
        for (int c = 0; c < 4; ++c) {
            const int rowb = wv * 32 + c * 8;
            gl_lds16(Ab + (size_t)(rowb + srow) * KS + a_kt * 64 + scol,
                     (unsigned short*)&Asl[bufi][rowb << 3]);
        }
        #pragma unroll
        for (int c = 0; c < 2; ++c) {
            const int rowb = wv * 16 + c * 8;
            gl_lds16(Bb + (size_t)(rowb + srow) * KS + w_kt * 64 + scol,
                     (unsigned short*)&Bsl[bufi][rowb << 3]);
        }
    };

    stage(0, 0);
    stage(1, 1);                 // 12 loads/wave in flight

    int buf = 0, sbuf = 2;
    for (int kt = 0; kt < 48; ++kt) {
        // retire tile kt's 6 loads; keep the next stage(s) in flight
        if (kt < 47) asm volatile("s_waitcnt vmcnt(6)" ::: "memory");
        else         asm volatile("s_waitcnt vmcnt(0)" ::: "memory");
        __builtin_amdgcn_s_barrier();        // raw: no vmcnt drain
        if (kt + 2 < 48) stage(sbuf, kt + 2);
        #pragma unroll
        for (int half = 0; half < 2; ++half) {
            bf16x8 af[4], bfr[2];
            #pragma unroll
            for (int mf = 0; mf < 4; ++mf) {
                const int r = wm * 64 + mf * 16 + x;
                af[mf] = Asl[buf][(r << 3) | ((half * 4 + y) ^ (r & 7))];
            }
            #pragma unroll
            for (int nf = 0; nf < 2; ++nf) {
                const int r = wn * 32 + nf * 16 + x;
                bfr[nf] = Bsl[buf][(r << 3) | ((half * 4 + y) ^ (r & 7))];
            }
            #pragma unroll
            for (int mf = 0; mf < 4; ++mf)
                #pragma unroll
                for (int nf = 0; nf < 2; ++nf)
                    acc[mf][nf] = __builtin_amdgcn_mfma_f32_16x16x32_bf16(
                        af[mf], bfr[nf], acc[mf][nf], 0, 0, 0);
        }
        buf  = (buf  == 2) ? 0 : buf  + 1;
        sbuf = (sbuf == 2) ? 0 : sbuf + 1;
    }

    // epilogue: C/D layout col=lane&15 (n), row=(lane>>4)*4+r (m)  [m89]
    #pragma unroll
    for (int nf = 0; nf < 2; ++nf) {
        const int n = bn + wn * 32 + nf * 16 + x;
        const float bv = bias[n];
        #pragma unroll
        for (int mf = 0; mf < 4; ++mf) {
            const int mbase = bm + wm * 64 + mf * 16 + y * 4;
            #pragma unroll
            for (int r = 0; r < 4; ++r) {
                const int m = mbase + r;
                const float v = acc[mf][nf][r] + bv;
                const int b = m >> 11, s = m & (SEQ - 1);
                const int hh = n >> 6, dd = n & 63;
                if (MODE == 0) {
                    Cf[(size_t)m * D_MODEL + n] = v;
                } else if (MODE == 1) {
                    const float sv = v * 0.125f;
                    const unsigned short hi = f2b(sv);
                    const unsigned short lo = f2b(sv - b2f(hi));
                    const int blk = (dd >> 3) ^ (s & 7), i = dd & 7;
                    unsigned short* qp = Cb +
                        ((size_t)((b * NUM_HEADS + hh) * SEQ + s)) * 128;
                    qp[blk * 8 + i] = hi;
                    qp[64 + blk * 8 + i] = lo;
                } else if (MODE == 2) {
                    if (s < ncArr[b]) {          // s IS the compacted index p
                        const unsigned short hi = f2b(v);
                        const unsigned short lo = f2b(v - b2f(hi));
                        const int blk = (dd >> 3) ^ (s & 7), i = dd & 7;
                        unsigned short* kp = Cb +
                            ((size_t)((b * NUM_HEADS + hh) * SEQ + s)) * 128;
                        kp[blk * 8 + i] = hi;
                        kp[64 + blk * 8 + i] = lo;
                    }
                } else {
                    if (s < ncArr[b]) {
                        const int tile = s >> 6, w = s & 63;
                        const int blk = (w >> 3) ^ (dd & 7), i = w & 7;
                        Cb[((size_t)((b * NUM_HEADS + hh) * DK + dd)) * SEQ +
                           tile * 64 + blk * 8 + i] = f2b(v);
                    }
                }
            }
        }
    }
}

// ---------------------------------------------------------------------------
// MFMA flash attention over COMPACTED keys (r7/r9-proven: single 32 KB
// buffer). Q read pre-converted (Q2); epilogue writes the bf16 [hi|lo]
// row-XOR-swizzled O-GEMM activation directly.
// ---------------------------------------------------------------------------
__global__ __launch_bounds__(256, 3) void attn_mfma_kernel(
    const unsigned short* __restrict__ Q2, const unsigned short* __restrict__ K2,
    const unsigned short* __restrict__ VT2, const int* __restrict__ ncArr,
    unsigned short* __restrict__ ACT)
{
    __shared__ __align__(16) unsigned short SM[16384];   // 32 KB
    unsigned short* Khi = SM;            // [64 key][64 dk] (swz)
    unsigned short* Klo = SM + 4096;
    unsigned short* VTs = SM + 8192;     // [64 d][64 key] (swz)

    const int tid = threadIdx.x;
    const int wave = tid >> 6, lane = tid & 63;
    const int lo4 = lane & 15, hi4 = lane >> 4;
    unsigned short* Pw = SM + 12288 + wave * 1024;  // [16 q][64 key] bf16

    const int orig = blockIdx.x;
    const int swz = (orig & 7) * 128 + (orig >> 3);  // 1024%8==0: bijective
    const int bh = swz >> 5, qblk = swz & 31;
    const int b = bh >> 4, h = bh & 15;

    const unsigned short* Kb = K2 + (size_t)bh * SEQ * 128;
    const unsigned short* Vb = VT2 + (size_t)bh * DK * SEQ;

    const int ncb = ncArr[b];
    const int ntiles = (ncb + 63) >> 6;

    // Q fragments from Q2 (already 0.125-scaled hi/lo, XOR-swizzled by s&7)
    const int qr = qblk * 64 + wave * 16 + lo4;
    const unsigned short* Q2row = Q2 + (size_t)(bh * SEQ + qr) * 128;
    bf16x8 qhi[2], qlo[2];
    #pragma unroll
    for (int c = 0; c < 2; ++c) {
        const int blk = ((c * 4 + hi4) ^ (qr & 7)) * 8;
        qhi[c] = *(const bf16x8*)&Q2row[blk];
        qlo[c] = *(const bf16x8*)&Q2row[64 + blk];
    }

    f32x4 ctx[4] = {};   // ctx^T frags: row d = dt*16+hi4*4+r, col q = lo4
    float m = -INFINITY, l = 0.f;

    for (int t = 0; t < ntiles; ++t) {
        const int k0 = t * 64;
        __syncthreads();
        // stage 24 KB: Khi(512 x16B) | Klo(512) | VT(512)
        #pragma unroll
        for (int j = 0; j < 6; ++j) {
            const int g = j * 256 + wave * 64;   // wave-uniform dest base
            const int gi = g + lane;
            const unsigned short* src;
            if (gi < 512) {
                src = Kb + (size_t)(k0 + (gi >> 3)) * 128 + (gi & 7) * 8;
            } else if (gi < 1024) {
                const int g2 = gi - 512;
                src = Kb + (size_t)(k0 + (g2 >> 3)) * 128 + 64 + (g2 & 7) * 8;
            } else {
                const int g3 = gi - 1024;
                src = Vb + (size_t)(g3 >> 3) * SEQ + k0 + (g3 & 7) * 8;
            }
            gl_lds16(src, SM + (size_t)g * 8);
        }
        asm volatile("s_waitcnt vmcnt(0)" ::: "memory");
        __syncthreads();

        // S^T = K . Q^T : rows = key, cols = q (hi/lo 3-term, fp32-accurate)
        f32x4 sc[4];
        #pragma unroll
        for (int kt = 0; kt < 4; ++kt) {
            f32x4 s = {0.f, 0.f, 0.f, 0.f};
            const int row = kt * 16 + lo4;
            const int rx = row & 7;
            #pragma unroll
            for (int c = 0; c < 2; ++c) {
                const int blk = ((c * 4 + hi4) ^ rx) * 8;
                const bf16x8 kh = *(bf16x8*)&Khi[row * 64 + blk];
                const bf16x8 kl = *(bf16x8*)&Klo[row * 64 + blk];
                s = __builtin_amdgcn_mfma_f32_16x16x32_bf16(kh, qhi[c], s, 0, 0, 0);
                s = __builtin_amdgcn_mfma_f32_16x16x32_bf16(kl, qhi[c], s, 0, 0, 0);
                s = __builtin_amdgcn_mfma_f32_16x16x32_bf16(kh, qlo[c], s, 0, 0, 0);
            }
            sc[kt] = s;
        }

        // row-max; tail tile masks invalid keys (kidx >= ncb) to -1e30
        float cmax = -1e30f;
        if (k0 + 64 <= ncb) {
            #pragma unroll
            for (int kt = 0; kt < 4; ++kt)
                #pragma unroll
                for (int r = 0; r < 4; ++r) cmax = fmaxf(cmax, sc[kt][r]);
        } else {
            #pragma unroll
            for (int kt = 0; kt < 4; ++kt)
                #pragma unroll
                for (int r = 0; r < 4; ++r) {
                    const int kidx = k0 + kt * 16 + hi4 * 4 + r;
                    const float sv = (kidx < ncb) ? sc[kt][r] : -1e30f;
                    sc[kt][r] = sv;
                    cmax = fmaxf(cmax, sv);
                }
        }
        cmax = fmaxf(cmax, __shfl_xor(cmax, 16));
        cmax = fmaxf(cmax, __shfl_xor(cmax, 32));

        const float mnew = fmaxf(m, cmax);
        const float e1 = __expf(m - mnew);   // m=-inf pre-first-tile -> 0
        m = mnew;

        float ps = 0.f;
        #pragma unroll
        for (int kt = 0; kt < 4; ++kt) {
            const float pv0 = __expf(sc[kt][0] - mnew);  // -1e30 -> exp = 0
            const float pv1 = __expf(sc[kt][1] - mnew);
            const float pv2 = __expf(sc[kt][2] - mnew);
            const float pv3 = __expf(sc[kt][3] - mnew);
            ps += (pv0 + pv1) + (pv2 + pv3);
            const unsigned w0 = (unsigned)f2b(pv0) | ((unsigned)f2b(pv1) << 16);
            const unsigned w1 = (unsigned)f2b(pv2) | ((unsigned)f2b(pv3) << 16);
            const int blk16 = (kt * 2 + (hi4 >> 1)) ^ (lo4 & 7);
            unsigned* dst = (unsigned*)&Pw[lo4 * 64 + blk16 * 8 + (hi4 & 1) * 4];
            dst[0] = w0; dst[1] = w1;
        }
        ps += __shfl_xor(ps, 16);
        ps += __shfl_xor(ps, 32);
        l = l * e1 + ps;

        #pragma unroll
        for (int dt = 0; dt < 4; ++dt)
            #pragma unroll
            for (int r = 0; r < 4; ++r) ctx[dt][r] *= e1;

        // ctx^T += V^T . P^T  (same-wave LDS RAW: compiler orders via lgkmcnt)
        #pragma unroll
        for (int c = 0; c < 2; ++c) {
            const bf16x8 pf =
                *(bf16x8*)&Pw[lo4 * 64 + (((c * 4 + hi4) ^ (lo4 & 7)) * 8)];
            #pragma unroll
            for (int dt = 0; dt < 4; ++dt) {
                const int row = dt * 16 + lo4;
                const bf16x8 vf =
                    *(bf16x8*)&VTs[row * 64 + (((c * 4 + hi4) ^ (row & 7)) * 8)];
                ctx[dt] = __builtin_amdgcn_mfma_f32_16x16x32_bf16(vf, pf, ctx[dt], 0, 0, 0);
            }
        }
    }

    // epilogue: normalize, transpose via LDS (stride 68, conflict-free),
    // FUSED bf16 [hi|lo] swizzled activation write
    __syncthreads();
    const float inv = (l > 0.f) ? (1.f / l) : 0.f;   // l==0: fully masked -> 0
    float* OutL = (float*)SM;                        // [64 q][68] fp32
    #pragma unroll
    for (int dt = 0; dt < 4; ++dt)
        #pragma unroll
        for (int r = 0; r < 4; ++r)
            OutL[(wave * 16 + lo4) * 68 + dt * 16 + hi4 * 4 + r] = ctx[dt][r] * inv;
    __syncthreads();
    {
        const int row = tid >> 2, cb = (tid & 3) * 16;
        const int mrow = b * SEQ + qblk * 64 + row;      // global act row
        unsigned short* arow = ACT + (size_t)mrow * 2048;
        #pragma unroll
        for (int u = 0; u < 2; ++u) {
            const int lb = (cb >> 3) + u;                // logical 8-col block
            const int ss = lb ^ (mrow & 7);              // stored (swizzled)
            us8 hv, lv;
            #pragma unroll
            for (int i = 0; i < 8; ++i) {
                const float v = OutL[row * 68 + cb + u * 8 + i];
                const unsigned short hb = f2b(v);
                hv[i] = (short)hb;
                lv[i] = (short)f2b(v - b2f(hb));
            }
            *(us8*)&arow[h * 64 + ss * 8] = hv;          // hi half (group h)
            *(us8*)&arow[1024 + h * 64 + ss * 8] = lv;   // lo half
        }
    }
}

// ---------------------------------------------------------------------------
// fp32 fallback path (only if ws too small)
// ---------------------------------------------------------------------------
template <int SPLIT>
__global__ __launch_bounds__(256) void gemm_bias_kernel(
    const float* __restrict__ A, const float* __restrict__ W,
    const float* __restrict__ bias, float* __restrict__ C,
    int M, int N, int K)
{
    constexpr int TILE = 64, KT = 16;
    __shared__ float As[KT][TILE + 4];
    __shared__ float Ws[KT][TILE + 4];
    const int tid = threadIdx.x;
    const int tx = tid & 15, ty = tid >> 4;
    const int bm = blockIdx.x * TILE, bn = blockIdx.y * TILE;
    const int lrow = tid >> 2, lk4 = (tid & 3) << 2;
    float acc[4][4] = {{0.f}};
    for (int k0 = 0; k0 < K; k0 += KT) {
        const float4 a4 = *(const float4*)&A[(size_t)(bm + lrow) * K + k0 + lk4];
        const float4 w4 = *(const float4*)&W[(size_t)(bn + lrow) * K + k0 + lk4];
        __syncthreads();
        As[lk4 + 0][lrow] = a4.x; As[lk4 + 1][lrow] = a4.y;
        As[lk4 + 2][lrow] = a4.z; As[lk4 + 3][lrow] = a4.w;
        Ws[lk4 + 0][lrow] = w4.x; Ws[lk4 + 1][lrow] = w4.y;
        Ws[lk4 + 2][lrow] = w4.z; Ws[lk4 + 3][lrow] = w4.w;
        __syncthreads();
        #pragma unroll
        for (int kk = 0; kk < KT; ++kk) {
            const float4 av = *(const float4*)&As[kk][ty << 2];
            const float4 wv = *(const float4*)&Ws[kk][tx << 2];
            acc[0][0] += av.x * wv.x; acc[0][1] += av.x * wv.y; acc[0][2] += av.x * wv.z; acc[0][3] += av.x * wv.w;
            acc[1][0] += av.y * wv.x; acc[1][1] += av.y * wv.y; acc[1][2] += av.y * wv.z; acc[1][3] += av.y * wv.w;
            acc[2][0] += av.z * wv.x; acc[2][1] += av.z * wv.y; acc[2][2] += av.z * wv.z; acc[2][3] += av.z * wv.w;
            acc[3][0] += av.w * wv.x; acc[3][1] += av.w * wv.y; acc[3][2] += av.w * wv.z; acc[3][3] += av.w * wv.w;
        }
    }
    const float4 bb = *(const float4*)&bias[bn + (tx << 2)];
    #pragma unroll
    for (int i = 0; i < 4; ++i) {
        const int row = bm + (ty << 2) + i;
        float4 o;
        o.x = acc[i][0] + bb.x; o.y = acc[i][1] + bb.y;
        o.z = acc[i][2] + bb.z; o.w = acc[i][3] + bb.w;
        if (SPLIT) {
            const int b = row >> 11, s = row & (SEQ - 1), hh = bn >> 6;
            *(float4*)&C[((size_t)((b * NUM_HEADS + hh) * SEQ + s)) * DK + (tx << 2)] = o;
        } else {
            *(float4*)&C[(size_t)row * N + bn + (tx << 2)] = o;
        }
    }
}

__global__ __launch_bounds__(256, 2) void attn_fp32_kernel(
    const float* __restrict__ Q, const float* __restrict__ K,
    const float* __restrict__ V, const int* __restrict__ mask,
    float* __restrict__ OUT)
{
    const int qb = blockIdx.x, h = blockIdx.y, b = blockIdx.z;
    const int wave = threadIdx.x >> 6, lane = threadIdx.x & 63;
    const int tid = threadIdx.x;
    const int bh = b * NUM_HEADS + h;
    const float* Qb = Q + (size_t)bh * SEQ * DK;
    const float* Kb = K + (size_t)bh * SEQ * DK;
    const float* Vb = V + (size_t)bh * SEQ * DK;
    const int* mb = mask + b * SEQ;
    __shared__ float Ks[64][68];
    __shared__ float Vs[64][68];
    const int row = qb * 256 + wave * 64 + lane;
    float q[DK], ctx[DK];
    #pragma unroll
    for (int d4 = 0; d4 < 16; ++d4) {
        const float4 t = *(const float4*)&Qb[(size_t)row * DK + 4 * d4];
        q[4*d4] = t.x; q[4*d4+1] = t.y; q[4*d4+2] = t.z; q[4*d4+3] = t.w;
        ctx[4*d4] = 0.f; ctx[4*d4+1] = 0.f; ctx[4*d4+2] = 0.f; ctx[4*d4+3] = 0.f;
    }
    float m = -INFINITY, l = 0.f;
    for (int t = 0; t < SEQ / 64; ++t) {
        const int k0 = t * 64;
        const float* Kt = Kb + (size_t)k0 * DK;
        const float* Vt = Vb + (size_t)k0 * DK;
        __syncthreads();
        #pragma unroll
        for (int i = 0; i < 4; ++i) {
            const int f4 = i * 256 + tid;
            const int r = f4 >> 4, c = (f4 & 15) << 2;
            *(float4*)&Ks[r][c] = *(const float4*)&Kt[4 * f4];
            *(float4*)&Vs[r][c] = *(const float4*)&Vt[4 * f4];
        }
        __syncthreads();
        const unsigned long long mbits = __ballot(mb[k0 + lane] != 0);
        if (mbits == 0ULL) continue;
        for (int c0 = 0; c0 < 64; c0 += 16) {
            const unsigned bits = (unsigned)((mbits >> c0) & 0xFFFFULL);
            if (!bits) continue;
            float sc[16];
            #pragma unroll
            for (int j = 0; j < 16; ++j) {
                if (!((bits >> j) & 1u)) { sc[j] = -INFINITY; continue; }
                float a0 = 0.f, a1 = 0.f, a2 = 0.f, a3 = 0.f;
                #pragma unroll
                for (int d4 = 0; d4 < 16; ++d4) {
                    const float4 kv = *(const float4*)&Ks[c0 + j][4 * d4];
                    a0 += q[4*d4] * kv.x; a1 += q[4*d4+1] * kv.y;
                    a2 += q[4*d4+2] * kv.z; a3 += q[4*d4+3] * kv.w;
                }
                sc[j] = ((a0 + a1) + (a2 + a3)) * 0.125f;
            }
            float cmax = sc[0];
            #pragma unroll
            for (int j = 1; j < 16; ++j) cmax = fmaxf(cmax, sc[j]);
            if (cmax > m) {
                const float scale = __expf(m - cmax);
                l *= scale;
                #pragma unroll
                for (int d = 0; d < DK; ++d) ctx[d] *= scale;
                m = cmax;
            }
            #pragma unroll
            for (int j = 0; j < 16; ++j) {
                if (!((bits >> j) & 1u)) continue;
                const float p = __expf(sc[j] - m);
                l += p;
                #pragma unroll
                for (int d4 = 0; d4 < 16; ++d4) {
                    const float4 vv = *(const float4*)&Vs[c0 + j][4 * d4];
                    ctx[4*d4] += p * vv.x; ctx[4*d4+1] += p * vv.y;
                    ctx[4*d4+2] += p * vv.z; ctx[4*d4+3] += p * vv.w;
                }
            }
        }
    }
    const float inv = (l > 0.f) ? (1.f / l) : 0.f;
    float* dst = OUT + ((size_t)(b * SEQ + row)) * D_MODEL + h * DK;
    #pragma unroll
    for (int d4 = 0; d4 < 16; ++d4) {
        float4 o;
        o.x = ctx[4*d4] * inv; o.y = ctx[4*d4+1] * inv;
        o.z = ctx[4*d4+2] * inv; o.w = ctx[4*d4+3] * inv;
        *(float4*)&dst[4 * d4] = o;
    }
}

// ---------------------------------------------------------------------------
extern "C" void kernel_launch(void* const* d_in, const int* in_sizes, int n_in,
                              void* d_out, int out_size, void* d_ws, size_t ws_size,
                              hipStream_t stream)
{
    const float* query = (const float*)d_in[0];
    const float* key_  = (const float*)d_in[1];
    const float* value = (const float*)d_in[2];
    const int*   mask  = (const int*)d_in[3];
    const float* Wq = (const float*)d_in[4];
    const float* bq = (const float*)d_in[5];
    const float* Wk = (const float*)d_in[6];
    const float* bk = (const float*)d_in[7];
    const float* Wv = (const float*)d_in[8];
    const float* bv = (const float*)d_in[9];
    const float* Wo = (const float*)d_in[10];
    const float* bo = (const float*)d_in[11];
    float* out = (float*)d_out;

    const int M = BATCH * SEQ;                            // 4096
    const size_t ACT_B  = (size_t)M * 2048 * 2;           // 16.78 MB
    const size_t W2_B   = (size_t)D_MODEL * 2048 * 2;     // 4.19 MB
    const size_t K2_B   = (size_t)32 * SEQ * 128 * 2;     // 16.78 MB
    const size_t VT2_B  = (size_t)32 * DK * SEQ * 2;      // 8.39 MB
    const size_t Q2_B   = K2_B;                           // 16.78 MB
    const size_t POS_B  = (size_t)BATCH * SEQ * 4 + 256;

    char* base = (char*)d_ws;
    unsigned short* actQ = (unsigned short*)(base);
    unsigned short* actK = (unsigned short*)(base + ACT_B);
    unsigned short* actV = (unsigned short*)(base + 2 * ACT_B);
    unsigned short* w2q  = (unsigned short*)(base + 3 * ACT_B);
    unsigned short* w2k  = (unsigned short*)((char*)w2q + W2_B);
    unsigned short* w2v  = (unsigned short*)((char*)w2k + W2_B);
    unsigned short* w2o  = (unsigned short*)((char*)w2v + W2_B);
    unsigned short* k2   = (unsigned short*)((char*)w2o + W2_B);
    unsigned short* vt2  = (unsigned short*)((char*)k2 + K2_B);
    unsigned short* q2   = (unsigned short*)((char*)vt2 + VT2_B);
    int* posArr = (int*)((char*)q2 + Q2_B);
    int* ncArr  = posArr + BATCH * SEQ;
    const size_t need = 3 * ACT_B + 4 * W2_B + K2_B + VT2_B + Q2_B + POS_B; // ~109 MB

    if (ws_size >= need) {
        mask_scan_kernel<<<BATCH, 256, 0, stream>>>(mask, posArr, ncArr);

        conv_hilo_kernel<0><<<dim3(D_MODEL, 4), 256, 0, stream>>>(
            Wq, Wk, Wv, Wo, w2q, w2k, w2v, w2o, D_MODEL, nullptr, nullptr);
        conv_hilo_kernel<0><<<dim3(M, 1), 256, 0, stream>>>(
            query, nullptr, nullptr, nullptr, actQ, nullptr, nullptr, nullptr,
            M, nullptr, nullptr);
        conv_hilo_kernel<1><<<dim3(M, 2), 256, 0, stream>>>(   // compacted rows
            key_, value, nullptr, nullptr, actK, actV, nullptr, nullptr,
            M, mask, posArr);

        dim3 ggrid(M / 128, D_MODEL / 64);                // 32 x 16 = 512 blocks
        mfma_gemm_kernel<2><<<ggrid, 256, 0, stream>>>(actK, w2k, bk, nullptr, k2, ncArr);
        mfma_gemm_kernel<3><<<ggrid, 256, 0, stream>>>(actV, w2v, bv, nullptr, vt2, ncArr);
        mfma_gemm_kernel<1><<<ggrid, 256, 0, stream>>>(actQ, w2q, bq, nullptr, q2, ncArr);

        // attn writes the O-GEMM activation (actK is dead) directly as hi|lo
        attn_mfma_kernel<<<1024, 256, 0, stream>>>(q2, k2, vt2, ncArr, actK);

        mfma_gemm_kernel<0><<<ggrid, 256, 0, stream>>>(actK, w2o, bo, out, nullptr, ncArr);
    } else {
        float* q_ws = (float*)(base);
        float* k_ws = (float*)(base + (size_t)M * D_MODEL * 4);
        float* v_ws = (float*)(base + 2 * (size_t)M * D_MODEL * 4);
        float* c_ws = (float*)(base + 3 * (size_t)M * D_MODEL * 4);
        dim3 ggrid(M / 64, D_MODEL / 64);
        gemm_bias_kernel<1><<<ggrid, 256, 0, stream>>>(query, Wq, bq, q_ws, M, D_MODEL, D_MODEL);
        gemm_bias_kernel<1><<<ggrid, 256, 0, stream>>>(key_,  Wk, bk, k_ws, M, D_MODEL, D_MODEL);
        gemm_bias_kernel<1><<<ggrid, 256, 0, stream>>>(value, Wv, bv, v_ws, M, D_MODEL, D_MODEL);
        dim3 agrid(SEQ / 256, NUM_HEADS, BATCH);
        attn_fp32_kernel<<<agrid, 256, 0, stream>>>(q_ws, k_ws, v_ws, mask, c_ws);
        gemm_bias_kernel<0><<<ggrid, 256, 0, stream>>>(c_ws, Wo, bo, out, M, D_MODEL, D_MODEL);
    }
}

// Round 16
// 191.399 us; speedup vs baseline: 1.6032x; 1.5708x over previous
//
#include <hip/hip_runtime.h>
#include <math.h>

#define D_MODEL 1024
#define NUM_HEADS 16
#define DK 64
#define BATCH 2
#define SEQ 2048

using f32x4  = __attribute__((ext_vector_type(4))) float;
using bf16x8 = __attribute__((ext_vector_type(8))) short;
using us8    = __attribute__((ext_vector_type(8))) unsigned short;
using f16x8  = __attribute__((ext_vector_type(8))) _Float16;

__device__ __forceinline__ unsigned short f2b(float x) {  // fp32 -> bf16 RNE
    unsigned u = __float_as_uint(x);
    return (unsigned short)((u + 0x7FFF + ((u >> 16) & 1)) >> 16);
}
__device__ __forceinline__ float b2f(unsigned short h) {
    return __uint_as_float(((unsigned)h) << 16);
}
__device__ __forceinline__ void gl_lds16(const void* g, void* l) {
    __builtin_amdgcn_global_load_lds(
        (const __attribute__((address_space(1))) void*)g,
        (__attribute__((address_space(3))) void*)l, 16, 0, 0);
}

// ---------------------------------------------------------------------------
// Per-batch prefix scan of mask: pos[b][s] = #valid keys before s, nc[b]=count
// ---------------------------------------------------------------------------
__global__ __launch_bounds__(256) void mask_scan_kernel(
    const int* __restrict__ mask, int* __restrict__ pos, int* __restrict__ nc)
{
    const int b = blockIdx.x;
    const int tid = threadIdx.x;
    __shared__ int sums[256];
    int v[8]; int cnt = 0;
    const int base = b * SEQ + tid * 8;
    #pragma unroll
    for (int e = 0; e < 8; ++e) { v[e] = (mask[base + e] != 0) ? 1 : 0; cnt += v[e]; }
    sums[tid] = cnt;
    __syncthreads();
    for (int off = 1; off < 256; off <<= 1) {
        int t = (tid >= off) ? sums[tid - off] : 0;
        __syncthreads();
        sums[tid] += t;
        __syncthreads();
    }
    int run = sums[tid] - cnt;           // exclusive prefix
    #pragma unroll
    for (int e = 0; e < 8; ++e) { pos[base + e] = run; run += v[e]; }
    if (tid == 255) nc[b] = sums[255];
}

// ---------------------------------------------------------------------------
// fp32 [rows][1024] -> bf16 [rows][2048] = [hi | lo], row-XOR swizzle baked
// in. Used only for Wo.
// ---------------------------------------------------------------------------
template <int COMPACT>
__global__ __launch_bounds__(256) void conv_hilo_kernel(
    const float* s0, const float* s1, const float* s2, const float* s3,
    unsigned short* d0, unsigned short* d1, unsigned short* d2, unsigned short* d3,
    int rows, const int* __restrict__ mask, const int* __restrict__ pos)
{
    const int y = blockIdx.y;
    const float* src = (y == 0) ? s0 : (y == 1) ? s1 : (y == 2) ? s2 : s3;
    unsigned short* dst = (y == 0) ? d0 : (y == 1) ? d1 : (y == 2) ? d2 : d3;
    const int id = blockIdx.x * 256 + threadIdx.x;
    if (id >= rows * 256) return;
    const int row = id >> 8;
    int drow = row;
    if (COMPACT) {
        if (!mask[row]) return;
        drow = (row >> 11) * SEQ + pos[row];
    }
    const int s   = id & 255;
    const int g   = s >> 3, ss = s & 7;
    const int lb  = ss ^ (drow & 7);
    const int srcg = g & 15;
    const bool lo = (g >> 4) != 0;

    const float* p = src + (size_t)row * 1024 + srcg * 64 + lb * 8;
    const float4 a = *(const float4*)p;
    const float4 bq = *(const float4*)(p + 4);
    const float xs[8] = {a.x, a.y, a.z, a.w, bq.x, bq.y, bq.z, bq.w};
    us8 o;
    #pragma unroll
    for (int e = 0; e < 8; ++e) {
        float x = xs[e];
        if (lo) { unsigned short h = f2b(x); x = x - b2f(h); }
        o[e] = f2b(x);
    }
    *(us8*)&dst[(size_t)drow * 2048 + s * 8] = o;
}

// ---------------------------------------------------------------------------
// fp32 [rows][1024] -> fp16 [rows][1024], row-XOR swizzle baked in.
// COMPACT=1: y>0 streams row-compacted via pos[]. Up to 3 pairs via
// blockIdx.y; grid.x = rows/2.
// ---------------------------------------------------------------------------
template <int COMPACT>
__global__ __launch_bounds__(256) void conv_f16_kernel(
    const float* s0, const float* s1, const float* s2,
    _Float16* d0, _Float16* d1, _Float16* d2,
    int rows, const int* __restrict__ mask, const int* __restrict__ pos)
{
    const int y = blockIdx.y;
    const float* src = (y == 0) ? s0 : (y == 1) ? s1 : s2;
    _Float16* dst = (y == 0) ? d0 : (y == 1) ? d1 : d2;
    const int id = blockIdx.x * 256 + threadIdx.x;
    if (id >= rows * 128) return;
    const int row = id >> 7;
    int drow = row;
    if (COMPACT && y != 0) {
        if (!mask[row]) return;
        drow = (row >> 11) * SEQ + pos[row];
    }
    const int s  = id & 127;
    const int g  = s >> 3, ss = s & 7;
    const int lb = ss ^ (drow & 7);

    const float* p = src + (size_t)row * 1024 + g * 64 + lb * 8;
    const float4 a = *(const float4*)p;
    const float4 bq = *(const float4*)(p + 4);
    f16x8 o;
    o[0] = (_Float16)a.x;  o[1] = (_Float16)a.y;
    o[2] = (_Float16)a.z;  o[3] = (_Float16)a.w;
    o[4] = (_Float16)bq.x; o[5] = (_Float16)bq.y;
    o[6] = (_Float16)bq.z; o[7] = (_Float16)bq.w;
    *(f16x8*)&dst[(size_t)drow * 1024 + s * 8] = o;
}

// ---------------------------------------------------------------------------
// fp16 MFMA GEMM (QKV projections): K=1024, 16 k-steps, 128x64 tile,
// 3-buffer LDS + counted vmcnt + raw s_barrier (r13/r14-proven pipeline).
// MODE 1: Q2 bf16 0.125*(hi|lo) swz; 2: K2 hi|lo compacted; 3: VT2 compacted.
// ---------------------------------------------------------------------------
template <int MODE>
__global__ __launch_bounds__(256) void mfma_gemm_f16_kernel(
    const _Float16* __restrict__ A2, const _Float16* __restrict__ W2,
    const float* __restrict__ bias, unsigned short* __restrict__ Cb,
    const int* __restrict__ ncArr)
{
    constexpr int KS = 1024;
    __shared__ f16x8 Asl[3][1024];
    __shared__ f16x8 Bsl[3][512];

    const int bm = blockIdx.x * 128, bn = blockIdx.y * 64;
    if (MODE == 2 || MODE == 3) {
        if ((bm & (SEQ - 1)) >= ncArr[bm >> 11]) return;   // uniform exit
    }

    const int tid = threadIdx.x;
    const int wv = tid >> 6, ln = tid & 63;
    const int wm = wv >> 1, wn = wv & 1;
    const int x = ln & 15, y = ln >> 4;

    f32x4 acc[4][2] = {};

    const _Float16* Ab = A2 + (size_t)bm * KS;
    const _Float16* Bb = W2 + (size_t)bn * KS;
    const int srow = ln >> 3;
    const int scol = (ln & 7) * 8;

    auto stage = [&](int bufi, int kt) {
        #pragma unroll
        for (int c = 0; c < 4; ++c) {
            const int rowb = wv * 32 + c * 8;
            gl_lds16(Ab + (size_t)(rowb + srow) * KS + kt * 64 + scol,
                     &Asl[bufi][rowb << 3]);
        }
        #pragma unroll
        for (int c = 0; c < 2; ++c) {
            const int rowb = wv * 16 + c * 8;
            gl_lds16(Bb + (size_t)(rowb + srow) * KS + kt * 64 + scol,
                     &Bsl[bufi][rowb << 3]);
        }
    };

    stage(0, 0);
    stage(1, 1);

    int buf = 0, sbuf = 2;
    for (int kt = 0; kt < 16; ++kt) {
        if (kt < 15) asm volatile("s_waitcnt vmcnt(6)" ::: "memory");
        else         asm volatile("s_waitcnt vmcnt(0)" ::: "memory");
        __builtin_amdgcn_s_barrier();
        if (kt + 2 < 16) stage(sbuf, kt + 2);
        #pragma unroll
        for (int half = 0; half < 2; ++half) {
            f16x8 af[4], bfr[2];
            #pragma unroll
            for (int mf = 0; mf < 4; ++mf) {
                const int r = wm * 64 + mf * 16 + x;
                af[mf] = Asl[buf][(r << 3) | ((half * 4 + y) ^ (r & 7))];
            }
            #pragma unroll
            for (int nf = 0; nf < 2; ++nf) {
                const int r = wn * 32 + nf * 16 + x;
                bfr[nf] = Bsl[buf][(r << 3) | ((half * 4 + y) ^ (r & 7))];
            }
            #pragma unroll
            for (int mf = 0; mf < 4; ++mf)
                #pragma unroll
                for (int nf = 0; nf < 2; ++nf)
                    acc[mf][nf] = __builtin_amdgcn_mfma_f32_16x16x32_f16(
                        af[mf], bfr[nf], acc[mf][nf], 0, 0, 0);
        }
        buf  = (buf  == 2) ? 0 : buf  + 1;
        sbuf = (sbuf == 2) ? 0 : sbuf + 1;
    }

    // epilogue (C/D: col=lane&15, row=(lane>>4)*4+r)
    #pragma unroll
    for (int nf = 0; nf < 2; ++nf) {
        const int n = bn + wn * 32 + nf * 16 + x;
        const float bv = bias[n];
        #pragma unroll
        for (int mf = 0; mf < 4; ++mf) {
            const int mbase = bm + wm * 64 + mf * 16 + y * 4;
            #pragma unroll
            for (int r = 0; r < 4; ++r) {
                const int m = mbase + r;
                const float v = acc[mf][nf][r] + bv;
                const int b = m >> 11, s = m & (SEQ - 1);
                const int hh = n >> 6, dd = n & 63;
                if (MODE == 1) {
                    const float sv = v * 0.125f;
                    const unsigned short hi = f2b(sv);
                    const unsigned short lo = f2b(sv - b2f(hi));
                    const int blk = (dd >> 3) ^ (s & 7), i = dd & 7;
                    unsigned short* qp = Cb +
                        ((size_t)((b * NUM_HEADS + hh) * SEQ + s)) * 128;
                    qp[blk * 8 + i] = hi;
                    qp[64 + blk * 8 + i] = lo;
                } else if (MODE == 2) {
                    if (s < ncArr[b]) {
                        const unsigned short hi = f2b(v);
                        const unsigned short lo = f2b(v - b2f(hi));
                        const int blk = (dd >> 3) ^ (s & 7), i = dd & 7;
                        unsigned short* kp = Cb +
                            ((size_t)((b * NUM_HEADS + hh) * SEQ + s)) * 128;
                        kp[blk * 8 + i] = hi;
                        kp[64 + blk * 8 + i] = lo;
                    }
                } else {
                    if (s < ncArr[b]) {
                        const int tile = s >> 6, w = s & 63;
                        const int blk = (w >> 3) ^ (dd & 7), i = w & 7;
                        Cb[((size_t)((b * NUM_HEADS + hh) * DK + dd)) * SEQ +
                           tile * 64 + blk * 8 + i] = f2b(v);
                    }
                }
            }
        }
    }
}

// ---------------------------------------------------------------------------
// bf16 hi/lo MFMA GEMM (output projection): virtual-K 48 tiles, 3-buf
// counted-vmcnt pipeline (r13/r14-proven). Output fp32 [M][1024] -> d_out.
// ---------------------------------------------------------------------------
__global__ __launch_bounds__(256) void mfma_gemm_o_kernel(
    const unsigned short* __restrict__ A2, const unsigned short* __restrict__ W2,
    const float* __restrict__ bias, float* __restrict__ Cf)
{
    constexpr int KS = 2048;
    __shared__ bf16x8 Asl[3][1024];
    __shared__ bf16x8 Bsl[3][512];

    const int bm = blockIdx.x * 128, bn = blockIdx.y * 64;
    const int tid = threadIdx.x;
    const int wv = tid >> 6, ln = tid & 63;
    const int wm = wv >> 1, wn = wv & 1;
    const int x = ln & 15, y = ln >> 4;

    f32x4 acc[4][2] = {};

    const unsigned short* Ab = A2 + (size_t)bm * KS;
    const unsigned short* Bb = W2 + (size_t)bn * KS;
    const int srow = ln >> 3;
    const int scol = (ln & 7) * 8;

    auto stage = [&](int bufi, int vkt) {
        const int a_kt = (vkt < 32) ? vkt : vkt - 32;
        const int w_kt = (vkt < 32) ? (vkt & 15) : vkt - 16;
        #pragma unroll
        for (int c = 0; c < 4; ++c) {
            const int rowb = wv * 32 + c * 8;
            gl_lds16(Ab + (size_t)(rowb + srow) * KS + a_kt * 64 + scol,
                     &Asl[bufi][rowb << 3]);
        }
        #pragma unroll
        for (int c = 0; c < 2; ++c) {
            const int rowb = wv * 16 + c * 8;
            gl_lds16(Bb + (size_t)(rowb + srow) * KS + w_kt * 64 + scol,
                     &Bsl[bufi][rowb << 3]);
        }
    };

    stage(0, 0);
    stage(1, 1);

    int buf = 0, sbuf = 2;
    for (int kt = 0; kt < 48; ++kt) {
        if (kt < 47) asm volatile("s_waitcnt vmcnt(6)" ::: "memory");
        else         asm volatile("s_waitcnt vmcnt(0)" ::: "memory");
        __builtin_amdgcn_s_barrier();
        if (kt + 2 < 48) stage(sbuf, kt + 2);
        #pragma unroll
        for (int half = 0; half < 2; ++half) {
            bf16x8 af[4], bfr[2];
            #pragma unroll
            for (int mf = 0; mf < 4; ++mf) {
                const int r = wm * 64 + mf * 16 + x;
                af[mf] = Asl[buf][(r << 3) | ((half * 4 + y) ^ (r & 7))];
            }
            #pragma unroll
            for (int nf = 0; nf < 2; ++nf) {
                const int r = wn * 32 + nf * 16 + x;
                bfr[nf] = Bsl[buf][(r << 3) | ((half * 4 + y) ^ (r & 7))];
            }
            #pragma unroll
            for (int mf = 0; mf < 4; ++mf)
                #pragma unroll
                for (int nf = 0; nf < 2; ++nf)
                    acc[mf][nf] = __builtin_amdgcn_mfma_f32_16x16x32_bf16(
                        af[mf], bfr[nf], acc[mf][nf], 0, 0, 0);
        }
        buf  = (buf  == 2) ? 0 : buf  + 1;
        sbuf = (sbuf == 2) ? 0 : sbuf + 1;
    }

    #pragma unroll
    for (int nf = 0; nf < 2; ++nf) {
        const int n = bn + wn * 32 + nf * 16 + x;
        const float bv = bias[n];
        #pragma unroll
        for (int mf = 0; mf < 4; ++mf) {
            const int mbase = bm + wm * 64 + mf * 16 + y * 4;
            #pragma unroll
            for (int r = 0; r < 4; ++r) {
                const int m = mbase + r;
                Cf[(size_t)m * D_MODEL + n] = acc[mf][nf][r] + bv;
            }
        }
    }
}

// ---------------------------------------------------------------------------
// MFMA flash attention over COMPACTED keys — EXACT r14 version (proven
// 61 us / absmax 4.88e-4): manual f2b packing, unconditional rescale.
// ---------------------------------------------------------------------------
__global__ __launch_bounds__(256, 3) void attn_mfma_kernel(
    const unsigned short* __restrict__ Q2, const unsigned short* __restrict__ K2,
    const unsigned short* __restrict__ VT2, const int* __restrict__ ncArr,
    unsigned short* __restrict__ ACT)
{
    __shared__ __align__(16) unsigned short SM[16384];   // 32 KB
    unsigned short* Khi = SM;
    unsigned short* Klo = SM + 4096;
    unsigned short* VTs = SM + 8192;

    const int tid = threadIdx.x;
    const int wave = tid >> 6, lane = tid & 63;
    const int lo4 = lane & 15, hi4 = lane >> 4;
    unsigned short* Pw = SM + 12288 + wave * 1024;

    const int orig = blockIdx.x;
    const int swz = (orig & 7) * 128 + (orig >> 3);
    const int bh = swz >> 5, qblk = swz & 31;
    const int b = bh >> 4, h = bh & 15;

    const unsigned short* Kb = K2 + (size_t)bh * SEQ * 128;
    const unsigned short* Vb = VT2 + (size_t)bh * DK * SEQ;

    const int ncb = ncArr[b];
    const int ntiles = (ncb + 63) >> 6;

    const int qr = qblk * 64 + wave * 16 + lo4;
    const unsigned short* Q2row = Q2 + (size_t)(bh * SEQ + qr) * 128;
    bf16x8 qhi[2], qlo[2];
    #pragma unroll
    for (int c = 0; c < 2; ++c) {
        const int blk = ((c * 4 + hi4) ^ (qr & 7)) * 8;
        qhi[c] = *(const bf16x8*)&Q2row[blk];
        qlo[c] = *(const bf16x8*)&Q2row[64 + blk];
    }

    f32x4 ctx[4] = {};
    float m = -INFINITY, l = 0.f;

    for (int t = 0; t < ntiles; ++t) {
        const int k0 = t * 64;
        __syncthreads();
        #pragma unroll
        for (int j = 0; j < 6; ++j) {
            const int g = j * 256 + wave * 64;
            const int gi = g + lane;
            const unsigned short* src;
            if (gi < 512) {
                src = Kb + (size_t)(k0 + (gi >> 3)) * 128 + (gi & 7) * 8;
            } else if (gi < 1024) {
                const int g2 = gi - 512;
                src = Kb + (size_t)(k0 + (g2 >> 3)) * 128 + 64 + (g2 & 7) * 8;
            } else {
                const int g3 = gi - 1024;
                src = Vb + (size_t)(g3 >> 3) * SEQ + k0 + (g3 & 7) * 8;
            }
            gl_lds16(src, SM + (size_t)g * 8);
        }
        asm volatile("s_waitcnt vmcnt(0)" ::: "memory");
        __syncthreads();

        // S^T = K . Q^T (hi/lo 3-term)
        f32x4 sc[4];
        #pragma unroll
        for (int kt = 0; kt < 4; ++kt) {
            f32x4 s = {0.f, 0.f, 0.f, 0.f};
            const int row = kt * 16 + lo4;
            const int rx = row & 7;
            #pragma unroll
            for (int c = 0; c < 2; ++c) {
                const int blk = ((c * 4 + hi4) ^ rx) * 8;
                const bf16x8 kh = *(bf16x8*)&Khi[row * 64 + blk];
                const bf16x8 kl = *(bf16x8*)&Klo[row * 64 + blk];
                s = __builtin_amdgcn_mfma_f32_16x16x32_bf16(kh, qhi[c], s, 0, 0, 0);
                s = __builtin_amdgcn_mfma_f32_16x16x32_bf16(kl, qhi[c], s, 0, 0, 0);
                s = __builtin_amdgcn_mfma_f32_16x16x32_bf16(kh, qlo[c], s, 0, 0, 0);
            }
            sc[kt] = s;
        }

        float cmax = -1e30f;
        if (k0 + 64 <= ncb) {
            #pragma unroll
            for (int kt = 0; kt < 4; ++kt)
                #pragma unroll
                for (int r = 0; r < 4; ++r) cmax = fmaxf(cmax, sc[kt][r]);
        } else {
            #pragma unroll
            for (int kt = 0; kt < 4; ++kt)
                #pragma unroll
                for (int r = 0; r < 4; ++r) {
                    const int kidx = k0 + kt * 16 + hi4 * 4 + r;
                    const float sv = (kidx < ncb) ? sc[kt][r] : -1e30f;
                    sc[kt][r] = sv;
                    cmax = fmaxf(cmax, sv);
                }
        }
        cmax = fmaxf(cmax, __shfl_xor(cmax, 16));
        cmax = fmaxf(cmax, __shfl_xor(cmax, 32));

        const float mnew = fmaxf(m, cmax);
        const float e1 = __expf(m - mnew);   // m=-inf pre-first-tile -> 0
        m = mnew;

        float ps = 0.f;
        #pragma unroll
        for (int kt = 0; kt < 4; ++kt) {
            const float pv0 = __expf(sc[kt][0] - mnew);  // -1e30 -> exp = 0
            const float pv1 = __expf(sc[kt][1] - mnew);
            const float pv2 = __expf(sc[kt][2] - mnew);
            const float pv3 = __expf(sc[kt][3] - mnew);
            ps += (pv0 + pv1) + (pv2 + pv3);
            const unsigned w0 = (unsigned)f2b(pv0) | ((unsigned)f2b(pv1) << 16);
            const unsigned w1 = (unsigned)f2b(pv2) | ((unsigned)f2b(pv3) << 16);
            const int blk16 = (kt * 2 + (hi4 >> 1)) ^ (lo4 & 7);
            unsigned* dst = (unsigned*)&Pw[lo4 * 64 + blk16 * 8 + (hi4 & 1) * 4];
            dst[0] = w0; dst[1] = w1;
        }
        ps += __shfl_xor(ps, 16);
        ps += __shfl_xor(ps, 32);
        l = l * e1 + ps;

        #pragma unroll
        for (int dt = 0; dt < 4; ++dt)
            #pragma unroll
            for (int r = 0; r < 4; ++r) ctx[dt][r] *= e1;

        // ctx^T += V^T . P^T
        #pragma unroll
        for (int c = 0; c < 2; ++c) {
            const bf16x8 pf =
                *(bf16x8*)&Pw[lo4 * 64 + (((c * 4 + hi4) ^ (lo4 & 7)) * 8)];
            #pragma unroll
            for (int dt = 0; dt < 4; ++dt) {
                const int row = dt * 16 + lo4;
                const bf16x8 vf =
                    *(bf16x8*)&VTs[row * 64 + (((c * 4 + hi4) ^ (row & 7)) * 8)];
                ctx[dt] = __builtin_amdgcn_mfma_f32_16x16x32_bf16(vf, pf, ctx[dt], 0, 0, 0);
            }
        }
    }

    // epilogue: normalize, LDS transpose (stride 68), fused bf16 hi|lo write
    __syncthreads();
    const float inv = (l > 0.f) ? (1.f / l) : 0.f;
    float* OutL = (float*)SM;
    #pragma unroll
    for (int dt = 0; dt < 4; ++dt)
        #pragma unroll
        for (int r = 0; r < 4; ++r)
            OutL[(wave * 16 + lo4) * 68 + dt * 16 + hi4 * 4 + r] = ctx[dt][r] * inv;
    __syncthreads();
    {
        const int row = tid >> 2, cb = (tid & 3) * 16;
        const int mrow = b * SEQ + qblk * 64 + row;
        unsigned short* arow = ACT + (size_t)mrow * 2048;
        #pragma unroll
        for (int u = 0; u < 2; ++u) {
            const int lb = (cb >> 3) + u;
            const int ss = lb ^ (mrow & 7);
            us8 hv, lv;
            #pragma unroll
            for (int i = 0; i < 8; ++i) {
                const float v = OutL[row * 68 + cb + u * 8 + i];
                const unsigned short hb = f2b(v);
                hv[i] = (short)hb;
                lv[i] = (short)f2b(v - b2f(hb));
            }
            *(us8*)&arow[h * 64 + ss * 8] = hv;
            *(us8*)&arow[1024 + h * 64 + ss * 8] = lv;
        }
    }
}

// ---------------------------------------------------------------------------
// fp32 fallback path (only if ws too small)
// ---------------------------------------------------------------------------
template <int SPLIT>
__global__ __launch_bounds__(256) void gemm_bias_kernel(
    const float* __restrict__ A, const float* __restrict__ W,
    const float* __restrict__ bias, float* __restrict__ C,
    int M, int N, int K)
{
    constexpr int TILE = 64, KT = 16;
    __shared__ float As[KT][TILE + 4];
    __shared__ float Ws[KT][TILE + 4];
    const int tid = threadIdx.x;
    const int tx = tid & 15, ty = tid >> 4;
    const int bm = blockIdx.x * TILE, bn = blockIdx.y * TILE;
    const int lrow = tid >> 2, lk4 = (tid & 3) << 2;
    float acc[4][4] = {{0.f}};
    for (int k0 = 0; k0 < K; k0 += KT) {
        const float4 a4 = *(const float4*)&A[(size_t)(bm + lrow) * K + k0 + lk4];
        const float4 w4 = *(const float4*)&W[(size_t)(bn + lrow) * K + k0 + lk4];
        __syncthreads();
        As[lk4 + 0][lrow] = a4.x; As[lk4 + 1][lrow] = a4.y;
        As[lk4 + 2][lrow] = a4.z; As[lk4 + 3][lrow] = a4.w;
        Ws[lk4 + 0][lrow] = w4.x; Ws[lk4 + 1][lrow] = w4.y;
        Ws[lk4 + 2][lrow] = w4.z; Ws[lk4 + 3][lrow] = w4.w;
        __syncthreads();
        #pragma unroll
        for (int kk = 0; kk < KT; ++kk) {
            const float4 av = *(const float4*)&As[kk][ty << 2];
            const float4 wv = *(const float4*)&Ws[kk][tx << 2];
            acc[0][0] += av.x * wv.x; acc[0][1] += av.x * wv.y; acc[0][2] += av.x * wv.z; acc[0][3] += av.x * wv.w;
            acc[1][0] += av.y * wv.x; acc[1][1] += av.y * wv.y; acc[1][2] += av.y * wv.z; acc[1][3] += av.y * wv.w;
            acc[2][0] += av.z * wv.x; acc[2][1] += av.z * wv.y; acc[2][2] += av.z * wv.z; acc[2][3] += av.z * wv.w;
            acc[3][0] += av.w * wv.x; acc[3][1] += av.w * wv.y; acc[3][2] += av.w * wv.z; acc[3][3] += av.w * wv.w;
        }
    }
    const float4 bb = *(const float4*)&bias[bn + (tx << 2)];
    #pragma unroll
    for (int i = 0; i < 4; ++i) {
        const int row = bm + (ty << 2) + i;
        float4 o;
        o.x = acc[i][0] + bb.x; o.y = acc[i][1] + bb.y;
        o.z = acc[i][2] + bb.z; o.w = acc[i][3] + bb.w;
        if (SPLIT) {
            const int b = row >> 11, s = row & (SEQ - 1), hh = bn >> 6;
            *(float4*)&C[((size_t)((b * NUM_HEADS + hh) * SEQ + s)) * DK + (tx << 2)] = o;
        } else {
            *(float4*)&C[(size_t)row * N + bn + (tx << 2)] = o;
        }
    }
}

__global__ __launch_bounds__(256, 2) void attn_fp32_kernel(
    const float* __restrict__ Q, const float* __restrict__ K,
    const float* __restrict__ V, const int* __restrict__ mask,
    float* __restrict__ OUT)
{
    const int qb = blockIdx.x, h = blockIdx.y, b = blockIdx.z;
    const int wave = threadIdx.x >> 6, lane = threadIdx.x & 63;
    const int tid = threadIdx.x;
    const int bh = b * NUM_HEADS + h;
    const float* Qb = Q + (size_t)bh * SEQ * DK;
    const float* Kb = K + (size_t)bh * SEQ * DK;
    const float* Vb = V + (size_t)bh * SEQ * DK;
    const int* mb = mask + b * SEQ;
    __shared__ float Ks[64][68];
    __shared__ float Vs[64][68];
    const int row = qb * 256 + wave * 64 + lane;
    float q[DK], ctx[DK];
    #pragma unroll
    for (int d4 = 0; d4 < 16; ++d4) {
        const float4 t = *(const float4*)&Qb[(size_t)row * DK + 4 * d4];
        q[4*d4] = t.x; q[4*d4+1] = t.y; q[4*d4+2] = t.z; q[4*d4+3] = t.w;
        ctx[4*d4] = 0.f; ctx[4*d4+1] = 0.f; ctx[4*d4+2] = 0.f; ctx[4*d4+3] = 0.f;
    }
    float m = -INFINITY, l = 0.f;
    for (int t = 0; t < SEQ / 64; ++t) {
        const int k0 = t * 64;
        const float* Kt = Kb + (size_t)k0 * DK;
        const float* Vt = Vb + (size_t)k0 * DK;
        __syncthreads();
        #pragma unroll
        for (int i = 0; i < 4; ++i) {
            const int f4 = i * 256 + tid;
            const int r = f4 >> 4, c = (f4 & 15) << 2;
            *(float4*)&Ks[r][c] = *(const float4*)&Kt[4 * f4];
            *(float4*)&Vs[r][c] = *(const float4*)&Vt[4 * f4];
        }
        __syncthreads();
        const unsigned long long mbits = __ballot(mb[k0 + lane] != 0);
        if (mbits == 0ULL) continue;
        for (int c0 = 0; c0 < 64; c0 += 16) {
            const unsigned bits = (unsigned)((mbits >> c0) & 0xFFFFULL);
            if (!bits) continue;
            float sc[16];
            #pragma unroll
            for (int j = 0; j < 16; ++j) {
                if (!((bits >> j) & 1u)) { sc[j] = -INFINITY; continue; }
                float a0 = 0.f, a1 = 0.f, a2 = 0.f, a3 = 0.f;
                #pragma unroll
                for (int d4 = 0; d4 < 16; ++d4) {
                    const float4 kv = *(const float4*)&Ks[c0 + j][4 * d4];
                    a0 += q[4*d4] * kv.x; a1 += q[4*d4+1] * kv.y;
                    a2 += q[4*d4+2] * kv.z; a3 += q[4*d4+3] * kv.w;
                }
                sc[j] = ((a0 + a1) + (a2 + a3)) * 0.125f;
            }
            float cmax = sc[0];
            #pragma unroll
            for (int j = 1; j < 16; ++j) cmax = fmaxf(cmax, sc[j]);
            if (cmax > m) {
                const float scale = __expf(m - cmax);
                l *= scale;
                #pragma unroll
                for (int d = 0; d < DK; ++d) ctx[d] *= scale;
                m = cmax;
            }
            #pragma unroll
            for (int j = 0; j < 16; ++j) {
                if (!((bits >> j) & 1u)) continue;
                const float p = __expf(sc[j] - m);
                l += p;
                #pragma unroll
                for (int d4 = 0; d4 < 16; ++d4) {
                    const float4 vv = *(const float4*)&Vs[c0 + j][4 * d4];
                    ctx[4*d4] += p * vv.x; ctx[4*d4+1] += p * vv.y;
                    ctx[4*d4+2] += p * vv.z; ctx[4*d4+3] += p * vv.w;
                }
            }
        }
    }
    const float inv = (l > 0.f) ? (1.f / l) : 0.f;
    float* dst = OUT + ((size_t)(b * SEQ + row)) * D_MODEL + h * DK;
    #pragma unroll
    for (int d4 = 0; d4 < 16; ++d4) {
        float4 o;
        o.x = ctx[4*d4] * inv; o.y = ctx[4*d4+1] * inv;
        o.z = ctx[4*d4+2] * inv; o.w = ctx[4*d4+3] * inv;
        *(float4*)&dst[4 * d4] = o;
    }
}

// ---------------------------------------------------------------------------
extern "C" void kernel_launch(void* const* d_in, const int* in_sizes, int n_in,
                              void* d_out, int out_size, void* d_ws, size_t ws_size,
                              hipStream_t stream)
{
    const float* query = (const float*)d_in[0];
    const float* key_  = (const float*)d_in[1];
    const float* value = (const float*)d_in[2];
    const int*   mask  = (const int*)d_in[3];
    const float* Wq = (const float*)d_in[4];
    const float* bq = (const float*)d_in[5];
    const float* Wk = (const float*)d_in[6];
    const float* bk = (const float*)d_in[7];
    const float* Wv = (const float*)d_in[8];
    const float* bv = (const float*)d_in[9];
    const float* Wo = (const float*)d_in[10];
    const float* bo = (const float*)d_in[11];
    float* out = (float*)d_out;

    const int M = BATCH * SEQ;                            // 4096
    const size_t ACTH_B = (size_t)M * 1024 * 2;           // 8.39 MB (fp16 act)
    const size_t ACTO_B = (size_t)M * 2048 * 2;           // 16.78 MB (bf16 hilo)
    const size_t WH_B   = (size_t)D_MODEL * 1024 * 2;     // 2.10 MB (fp16 W)
    const size_t W2O_B  = (size_t)D_MODEL * 2048 * 2;     // 4.19 MB
    const size_t K2_B   = (size_t)32 * SEQ * 128 * 2;     // 16.78 MB
    const size_t VT2_B  = (size_t)32 * DK * SEQ * 2;      // 8.39 MB
    const size_t Q2_B   = K2_B;                           // 16.78 MB
    const size_t POS_B  = (size_t)BATCH * SEQ * 4 + 256;

    char* base = (char*)d_ws;
    _Float16* actQh = (_Float16*)(base);
    _Float16* actKh = (_Float16*)(base + ACTH_B);
    _Float16* actVh = (_Float16*)(base + 2 * ACTH_B);
    unsigned short* actO = (unsigned short*)(base + 3 * ACTH_B);
    _Float16* w2qh = (_Float16*)(base + 3 * ACTH_B + ACTO_B);
    _Float16* w2kh = (_Float16*)((char*)w2qh + WH_B);
    _Float16* w2vh = (_Float16*)((char*)w2kh + WH_B);
    unsigned short* w2o = (unsigned short*)((char*)w2vh + WH_B);
    unsigned short* k2  = (unsigned short*)((char*)w2o + W2O_B);
    unsigned short* vt2 = (unsigned short*)((char*)k2 + K2_B);
    unsigned short* q2  = (unsigned short*)((char*)vt2 + VT2_B);
    int* posArr = (int*)((char*)q2 + Q2_B);
    int* ncArr  = posArr + BATCH * SEQ;
    const size_t need = 3 * ACTH_B + ACTO_B + 3 * WH_B + W2O_B
                      + K2_B + VT2_B + Q2_B + POS_B;      // ~93 MB

    if (ws_size >= need) {
        mask_scan_kernel<<<BATCH, 256, 0, stream>>>(mask, posArr, ncArr);

        // weights: Wq/Wk/Wv -> fp16 (one dispatch), Wo -> bf16 hi/lo
        conv_f16_kernel<0><<<dim3(D_MODEL / 2, 3), 256, 0, stream>>>(
            Wq, Wk, Wv, w2qh, w2kh, w2vh, D_MODEL, nullptr, nullptr);
        conv_hilo_kernel<0><<<dim3(D_MODEL, 1), 256, 0, stream>>>(
            Wo, nullptr, nullptr, nullptr, w2o, nullptr, nullptr, nullptr,
            D_MODEL, nullptr, nullptr);

        // inputs: query plain, key_/value row-compacted (one dispatch)
        conv_f16_kernel<1><<<dim3(M / 2, 3), 256, 0, stream>>>(
            query, key_, value, actQh, actKh, actVh, M, mask, posArr);

        dim3 ggrid(M / 128, D_MODEL / 64);                // 32 x 16 = 512 blocks
        mfma_gemm_f16_kernel<2><<<ggrid, 256, 0, stream>>>(actKh, w2kh, bk, k2, ncArr);
        mfma_gemm_f16_kernel<3><<<ggrid, 256, 0, stream>>>(actVh, w2vh, bv, vt2, ncArr);
        mfma_gemm_f16_kernel<1><<<ggrid, 256, 0, stream>>>(actQh, w2qh, bq, q2, ncArr);

        attn_mfma_kernel<<<1024, 256, 0, stream>>>(q2, k2, vt2, ncArr, actO);

        mfma_gemm_o_kernel<<<ggrid, 256, 0, stream>>>(actO, w2o, bo, out);
    } else {
        float* q_ws = (float*)(base);
        float* k_ws = (float*)(base + (size_t)M * D_MODEL * 4);
        float* v_ws = (float*)(base + 2 * (size_t)M * D_MODEL * 4);
        float* c_ws = (float*)(base + 3 * (size_t)M * D_MODEL * 4);
        dim3 ggrid(M / 64, D_MODEL / 64);
        gemm_bias_kernel<1><<<ggrid, 256, 0, stream>>>(query, Wq, bq, q_ws, M, D_MODEL, D_MODEL);
        gemm_bias_kernel<1><<<ggrid, 256, 0, stream>>>(key_,  Wk, bk, k_ws, M, D_MODEL, D_MODEL);
        gemm_bias_kernel<1><<<ggrid, 256, 0, stream>>>(value, Wv, bv, v_ws, M, D_MODEL, D_MODEL);
        dim3 agrid(SEQ / 256, NUM_HEADS, BATCH);
        attn_fp32_kernel<<<agrid, 256, 0, stream>>>(q_ws, k_ws, v_ws, mask, c_ws);
        gemm_bias_kernel<0><<<ggrid, 256, 0, stream>>>(c_ws, Wo, bo, out, M, D_MODEL, D_MODEL);
    }
}

// Round 17
// 134.791 us; speedup vs baseline: 2.2764x; 1.4200x over previous
//
#include <hip/hip_runtime.h>
#include <math.h>

#define D_MODEL 1024
#define NUM_HEADS 16
#define DK 64
#define BATCH 2
#define SEQ 2048

using f32x4  = __attribute__((ext_vector_type(4))) float;
using f16x8  = __attribute__((ext_vector_type(8))) _Float16;

__device__ __forceinline__ void gl_lds16(const void* g, void* l) {
    __builtin_amdgcn_global_load_lds(
        (const __attribute__((address_space(1))) void*)g,
        (__attribute__((address_space(3))) void*)l, 16, 0, 0);
}

// ---------------------------------------------------------------------------
// Per-batch prefix scan of mask: pos[b][s] = #valid keys before s, nc[b]=count
// ---------------------------------------------------------------------------
__global__ __launch_bounds__(256) void mask_scan_kernel(
    const int* __restrict__ mask, int* __restrict__ pos, int* __restrict__ nc)
{
    const int b = blockIdx.x;
    const int tid = threadIdx.x;
    __shared__ int sums[256];
    int v[8]; int cnt = 0;
    const int base = b * SEQ + tid * 8;
    #pragma unroll
    for (int e = 0; e < 8; ++e) { v[e] = (mask[base + e] != 0) ? 1 : 0; cnt += v[e]; }
    sums[tid] = cnt;
    __syncthreads();
    for (int off = 1; off < 256; off <<= 1) {
        int t = (tid >= off) ? sums[tid - off] : 0;
        __syncthreads();
        sums[tid] += t;
        __syncthreads();
    }
    int run = sums[tid] - cnt;           // exclusive prefix
    #pragma unroll
    for (int e = 0; e < 8; ++e) { pos[base + e] = run; run += v[e]; }
    if (tid == 255) nc[b] = sums[255];
}

// ---------------------------------------------------------------------------
// fp32 [rows][1024] -> fp16 [rows][1024], row-XOR swizzle baked in (stored
// 16B block ss = logical block ss ^ (STORED_row & 7), per 64-col group).
// COMPACT=1: y>0 streams row-compacted via pos[]. Up to 4 pairs via
// blockIdx.y; grid.x = rows/2.
// ---------------------------------------------------------------------------
template <int COMPACT>
__global__ __launch_bounds__(256) void conv_f16_kernel(
    const float* s0, const float* s1, const float* s2, const float* s3,
    _Float16* d0, _Float16* d1, _Float16* d2, _Float16* d3,
    int rows, const int* __restrict__ mask, const int* __restrict__ pos)
{
    const int y = blockIdx.y;
    const float* src = (y == 0) ? s0 : (y == 1) ? s1 : (y == 2) ? s2 : s3;
    _Float16* dst = (y == 0) ? d0 : (y == 1) ? d1 : (y == 2) ? d2 : d3;
    const int id = blockIdx.x * 256 + threadIdx.x;
    if (id >= rows * 128) return;
    const int row = id >> 7;
    int drow = row;
    if (COMPACT && y != 0) {
        if (!mask[row]) return;
        drow = (row >> 11) * SEQ + pos[row];
    }
    const int s  = id & 127;             // 16B block (8 f16) in [0,128)
    const int g  = s >> 3, ss = s & 7;
    const int lb = ss ^ (drow & 7);

    const float* p = src + (size_t)row * 1024 + g * 64 + lb * 8;
    const float4 a = *(const float4*)p;
    const float4 bq = *(const float4*)(p + 4);
    f16x8 o;
    o[0] = (_Float16)a.x;  o[1] = (_Float16)a.y;
    o[2] = (_Float16)a.z;  o[3] = (_Float16)a.w;
    o[4] = (_Float16)bq.x; o[5] = (_Float16)bq.y;
    o[6] = (_Float16)bq.z; o[7] = (_Float16)bq.w;
    *(f16x8*)&dst[(size_t)drow * 1024 + s * 8] = o;
}

// ---------------------------------------------------------------------------
// fp16 MFMA GEMM: K=1024, 16 k-steps, 128x64 tile, 3-buffer LDS + counted
// vmcnt + raw s_barrier (r13/r16-proven pipeline).
// MODE epilogue:
//   0: fp32 [M][1024] -> d_out        (output projection)
//   1: Q2  fp16 [bh][s][64] = 0.125*v, block-XOR by s&7
//   2: K2  fp16 [bh][p][64] swz      (rows pre-COMPACTED; store if p<nc)
//   3: VT2 fp16 [bh][d][2048] key-block swz (pre-COMPACTED; store if p<nc)
// MODE 2/3: whole tile early-exits when its 128-row stripe is >= nc[b].
// ---------------------------------------------------------------------------
template <int MODE>
__global__ __launch_bounds__(256) void mfma_gemm_f16_kernel(
    const _Float16* __restrict__ A2, const _Float16* __restrict__ W2,
    const float* __restrict__ bias, float* __restrict__ Cf,
    _Float16* __restrict__ Ch, const int* __restrict__ ncArr)
{
    constexpr int KS = 1024;
    __shared__ f16x8 Asl[3][1024];
    __shared__ f16x8 Bsl[3][512];

    const int bm = blockIdx.x * 128, bn = blockIdx.y * 64;
    if (MODE == 2 || MODE == 3) {
        if ((bm & (SEQ - 1)) >= ncArr[bm >> 11]) return;   // uniform exit
    }

    const int tid = threadIdx.x;
    const int wv = tid >> 6, ln = tid & 63;
    const int wm = wv >> 1, wn = wv & 1;
    const int x = ln & 15, y = ln >> 4;

    f32x4 acc[4][2] = {};

    const _Float16* Ab = A2 + (size_t)bm * KS;
    const _Float16* Bb = W2 + (size_t)bn * KS;
    const int srow = ln >> 3;
    const int scol = (ln & 7) * 8;

    auto stage = [&](int bufi, int kt) {
        #pragma unroll
        for (int c = 0; c < 4; ++c) {
            const int rowb = wv * 32 + c * 8;
            gl_lds16(Ab + (size_t)(rowb + srow) * KS + kt * 64 + scol,
                     &Asl[bufi][rowb << 3]);
        }
        #pragma unroll
        for (int c = 0; c < 2; ++c) {
            const int rowb = wv * 16 + c * 8;
            gl_lds16(Bb + (size_t)(rowb + srow) * KS + kt * 64 + scol,
                     &Bsl[bufi][rowb << 3]);
        }
    };

    stage(0, 0);
    stage(1, 1);

    int buf = 0, sbuf = 2;
    for (int kt = 0; kt < 16; ++kt) {
        if (kt < 15) asm volatile("s_waitcnt vmcnt(6)" ::: "memory");
        else         asm volatile("s_waitcnt vmcnt(0)" ::: "memory");
        __builtin_amdgcn_s_barrier();
        if (kt + 2 < 16) stage(sbuf, kt + 2);
        #pragma unroll
        for (int half = 0; half < 2; ++half) {
            f16x8 af[4], bfr[2];
            #pragma unroll
            for (int mf = 0; mf < 4; ++mf) {
                const int r = wm * 64 + mf * 16 + x;
                af[mf] = Asl[buf][(r << 3) | ((half * 4 + y) ^ (r & 7))];
            }
            #pragma unroll
            for (int nf = 0; nf < 2; ++nf) {
                const int r = wn * 32 + nf * 16 + x;
                bfr[nf] = Bsl[buf][(r << 3) | ((half * 4 + y) ^ (r & 7))];
            }
            #pragma unroll
            for (int mf = 0; mf < 4; ++mf)
                #pragma unroll
                for (int nf = 0; nf < 2; ++nf)
                    acc[mf][nf] = __builtin_amdgcn_mfma_f32_16x16x32_f16(
                        af[mf], bfr[nf], acc[mf][nf], 0, 0, 0);
        }
        buf  = (buf  == 2) ? 0 : buf  + 1;
        sbuf = (sbuf == 2) ? 0 : sbuf + 1;
    }

    // epilogue (C/D: col=lane&15, row=(lane>>4)*4+r)  [m89-verified]
    #pragma unroll
    for (int nf = 0; nf < 2; ++nf) {
        const int n = bn + wn * 32 + nf * 16 + x;
        const float bv = bias[n];
        #pragma unroll
        for (int mf = 0; mf < 4; ++mf) {
            const int mbase = bm + wm * 64 + mf * 16 + y * 4;
            #pragma unroll
            for (int r = 0; r < 4; ++r) {
                const int m = mbase + r;
                const float v = acc[mf][nf][r] + bv;
                const int b = m >> 11, s = m & (SEQ - 1);
                const int hh = n >> 6, dd = n & 63;
                if (MODE == 0) {
                    Cf[(size_t)m * D_MODEL + n] = v;
                } else if (MODE == 1) {
                    const int blk = (dd >> 3) ^ (s & 7), i = dd & 7;
                    Ch[((size_t)((b * NUM_HEADS + hh) * SEQ + s)) * 64 +
                       blk * 8 + i] = (_Float16)(v * 0.125f);
                } else if (MODE == 2) {
                    if (s < ncArr[b]) {          // s IS the compacted index
                        const int blk = (dd >> 3) ^ (s & 7), i = dd & 7;
                        Ch[((size_t)((b * NUM_HEADS + hh) * SEQ + s)) * 64 +
                           blk * 8 + i] = (_Float16)v;
                    }
                } else {
                    if (s < ncArr[b]) {
                        const int tile = s >> 6, w = s & 63;
                        const int blk = (w >> 3) ^ (dd & 7), i = w & 7;
                        Ch[((size_t)((b * NUM_HEADS + hh) * DK + dd)) * SEQ +
                           tile * 64 + blk * 8 + i] = (_Float16)v;
                    }
                }
            }
        }
    }
}

// ---------------------------------------------------------------------------
// All-fp16 MFMA flash attention over COMPACTED keys (r14/r16-proven
// structure, fp16 operands): single 24 KB buffer; per tile 8 QK + 8 PV
// MFMAs (was 24+8 with bf16 hi/lo). fp32 softmax state; P packed fp16 RNE.
// Epilogue writes the fp16 swizzled O-GEMM activation directly.
// ---------------------------------------------------------------------------
__global__ __launch_bounds__(256, 3) void attn_mfma_kernel(
    const _Float16* __restrict__ Q2, const _Float16* __restrict__ K2,
    const _Float16* __restrict__ VT2, const int* __restrict__ ncArr,
    _Float16* __restrict__ ACT)
{
    __shared__ __align__(16) _Float16 SM[12288];   // 24 KB
    // Ks [64k][64d] @0, VTs [64d][64k] @4096, Pw 4x[16q][64k] @8192

    const int tid = threadIdx.x;
    const int wave = tid >> 6, lane = tid & 63;
    const int lo4 = lane & 15, hi4 = lane >> 4;
    _Float16* Pw = SM + 8192 + wave * 1024;

    const int orig = blockIdx.x;
    const int swz = (orig & 7) * 128 + (orig >> 3);  // 1024%8==0: bijective
    const int bh = swz >> 5, qblk = swz & 31;
    const int b = bh >> 4, h = bh & 15;

    const _Float16* Kb = K2 + (size_t)bh * SEQ * 64;
    const _Float16* Vb = VT2 + (size_t)bh * DK * SEQ;

    const int ncb = ncArr[b];
    const int ntiles = (ncb + 63) >> 6;

    // Q fragments (0.125-scaled fp16, XOR-swizzled by s&7)
    const int qr = qblk * 64 + wave * 16 + lo4;
    const _Float16* Q2row = Q2 + (size_t)(bh * SEQ + qr) * 64;
    f16x8 qf[2];
    #pragma unroll
    for (int c = 0; c < 2; ++c)
        qf[c] = *(const f16x8*)&Q2row[(((c * 4 + hi4) ^ (qr & 7)) * 8)];

    f32x4 ctx[4] = {};   // ctx^T frags: row d = dt*16+hi4*4+r, col q = lo4
    float m = -INFINITY, l = 0.f;

    for (int t = 0; t < ntiles; ++t) {
        const int k0 = t * 64;
        __syncthreads();
        // stage 16 KB: Ks (512 x16B) | VTs (512 x16B)
        #pragma unroll
        for (int j = 0; j < 4; ++j) {
            const int g = j * 256 + wave * 64;   // wave-uniform dest base
            const int gi = g + lane;
            const _Float16* src;
            if (gi < 512) {
                src = Kb + (size_t)(k0 + (gi >> 3)) * 64 + (gi & 7) * 8;
            } else {
                const int g2 = gi - 512;
                src = Vb + (size_t)(g2 >> 3) * SEQ + k0 + (g2 & 7) * 8;
            }
            gl_lds16(src, SM + (size_t)g * 8);
        }
        asm volatile("s_waitcnt vmcnt(0)" ::: "memory");
        __syncthreads();

        // S^T = K . Q^T : rows = key, cols = q (single fp16 term)
        f32x4 sc[4];
        #pragma unroll
        for (int kt = 0; kt < 4; ++kt) {
            f32x4 s = {0.f, 0.f, 0.f, 0.f};
            const int row = kt * 16 + lo4;
            const int rx = row & 7;
            #pragma unroll
            for (int c = 0; c < 2; ++c) {
                const f16x8 kf = *(f16x8*)&SM[row * 64 + (((c * 4 + hi4) ^ rx) * 8)];
                s = __builtin_amdgcn_mfma_f32_16x16x32_f16(kf, qf[c], s, 0, 0, 0);
            }
            sc[kt] = s;
        }

        // row-max; tail tile masks invalid keys (kidx >= ncb) to -1e30
        float cmax = -1e30f;
        if (k0 + 64 <= ncb) {
            #pragma unroll
            for (int kt = 0; kt < 4; ++kt)
                #pragma unroll
                for (int r = 0; r < 4; ++r) cmax = fmaxf(cmax, sc[kt][r]);
        } else {
            #pragma unroll
            for (int kt = 0; kt < 4; ++kt)
                #pragma unroll
                for (int r = 0; r < 4; ++r) {
                    const int kidx = k0 + kt * 16 + hi4 * 4 + r;
                    const float sv = (kidx < ncb) ? sc[kt][r] : -1e30f;
                    sc[kt][r] = sv;
                    cmax = fmaxf(cmax, sv);
                }
        }
        cmax = fmaxf(cmax, __shfl_xor(cmax, 16));
        cmax = fmaxf(cmax, __shfl_xor(cmax, 32));

        const float mnew = fmaxf(m, cmax);
        const float e1 = __expf(m - mnew);   // m=-inf pre-first-tile -> 0
        m = mnew;

        float ps = 0.f;
        #pragma unroll
        for (int kt = 0; kt < 4; ++kt) {
            const float pv0 = __expf(sc[kt][0] - mnew);  // -1e30 -> exp = 0
            const float pv1 = __expf(sc[kt][1] - mnew);
            const float pv2 = __expf(sc[kt][2] - mnew);
            const float pv3 = __expf(sc[kt][3] - mnew);
            ps += (pv0 + pv1) + (pv2 + pv3);
            union { _Float16 hh[2]; unsigned u; } pk0, pk1;   // fp16 RNE pack
            pk0.hh[0] = (_Float16)pv0; pk0.hh[1] = (_Float16)pv1;
            pk1.hh[0] = (_Float16)pv2; pk1.hh[1] = (_Float16)pv3;
            const int blk16 = (kt * 2 + (hi4 >> 1)) ^ (lo4 & 7);
            unsigned* dst = (unsigned*)&Pw[lo4 * 64 + blk16 * 8 + (hi4 & 1) * 4];
            dst[0] = pk0.u; dst[1] = pk1.u;
        }
        ps += __shfl_xor(ps, 16);
        ps += __shfl_xor(ps, 32);
        l = l * e1 + ps;

        #pragma unroll
        for (int dt = 0; dt < 4; ++dt)
            #pragma unroll
            for (int r = 0; r < 4; ++r) ctx[dt][r] *= e1;

        // ctx^T += V^T . P^T  (same-wave LDS RAW: compiler orders via lgkmcnt)
        #pragma unroll
        for (int c = 0; c < 2; ++c) {
            const f16x8 pf = *(f16x8*)&Pw[lo4 * 64 + (((c * 4 + hi4) ^ (lo4 & 7)) * 8)];
            #pragma unroll
            for (int dt = 0; dt < 4; ++dt) {
                const int row = dt * 16 + lo4;
                const f16x8 vf =
                    *(f16x8*)&SM[4096 + row * 64 + (((c * 4 + hi4) ^ (row & 7)) * 8)];
                ctx[dt] = __builtin_amdgcn_mfma_f32_16x16x32_f16(vf, pf, ctx[dt], 0, 0, 0);
            }
        }
    }

    // epilogue: normalize, LDS transpose (stride 68, conflict-free),
    // fused fp16 swizzled activation write
    __syncthreads();
    const float inv = (l > 0.f) ? (1.f / l) : 0.f;   // l==0: fully masked -> 0
    float* OutL = (float*)SM;                        // [64 q][68] fp32
    #pragma unroll
    for (int dt = 0; dt < 4; ++dt)
        #pragma unroll
        for (int r = 0; r < 4; ++r)
            OutL[(wave * 16 + lo4) * 68 + dt * 16 + hi4 * 4 + r] = ctx[dt][r] * inv;
    __syncthreads();
    {
        const int row = tid >> 2, cb = (tid & 3) * 16;
        const int mrow = b * SEQ + qblk * 64 + row;      // global act row
        _Float16* arow = ACT + (size_t)mrow * 1024;
        #pragma unroll
        for (int u = 0; u < 2; ++u) {
            const int lb = (cb >> 3) + u;                // logical 8-col block
            const int ss = lb ^ (mrow & 7);              // stored (swizzled)
            f16x8 hv;
            #pragma unroll
            for (int i = 0; i < 8; ++i)
                hv[i] = (_Float16)OutL[row * 68 + cb + u * 8 + i];
            *(f16x8*)&arow[h * 64 + ss * 8] = hv;
        }
    }
}

// ---------------------------------------------------------------------------
// fp32 fallback path (only if ws too small)
// ---------------------------------------------------------------------------
template <int SPLIT>
__global__ __launch_bounds__(256) void gemm_bias_kernel(
    const float* __restrict__ A, const float* __restrict__ W,
    const float* __restrict__ bias, float* __restrict__ C,
    int M, int N, int K)
{
    constexpr int TILE = 64, KT = 16;
    __shared__ float As[KT][TILE + 4];
    __shared__ float Ws[KT][TILE + 4];
    const int tid = threadIdx.x;
    const int tx = tid & 15, ty = tid >> 4;
    const int bm = blockIdx.x * TILE, bn = blockIdx.y * TILE;
    const int lrow = tid >> 2, lk4 = (tid & 3) << 2;
    float acc[4][4] = {{0.f}};
    for (int k0 = 0; k0 < K; k0 += KT) {
        const float4 a4 = *(const float4*)&A[(size_t)(bm + lrow) * K + k0 + lk4];
        const float4 w4 = *(const float4*)&W[(size_t)(bn + lrow) * K + k0 + lk4];
        __syncthreads();
        As[lk4 + 0][lrow] = a4.x; As[lk4 + 1][lrow] = a4.y;
        As[lk4 + 2][lrow] = a4.z; As[lk4 + 3][lrow] = a4.w;
        Ws[lk4 + 0][lrow] = w4.x; Ws[lk4 + 1][lrow] = w4.y;
        Ws[lk4 + 2][lrow] = w4.z; Ws[lk4 + 3][lrow] = w4.w;
        __syncthreads();
        #pragma unroll
        for (int kk = 0; kk < KT; ++kk) {
            const float4 av = *(const float4*)&As[kk][ty << 2];
            const float4 wv = *(const float4*)&Ws[kk][tx << 2];
            acc[0][0] += av.x * wv.x; acc[0][1] += av.x * wv.y; acc[0][2] += av.x * wv.z; acc[0][3] += av.x * wv.w;
            acc[1][0] += av.y * wv.x; acc[1][1] += av.y * wv.y; acc[1][2] += av.y * wv.z; acc[1][3] += av.y * wv.w;
            acc[2][0] += av.z * wv.x; acc[2][1] += av.z * wv.y; acc[2][2] += av.z * wv.z; acc[2][3] += av.z * wv.w;
            acc[3][0] += av.w * wv.x; acc[3][1] += av.w * wv.y; acc[3][2] += av.w * wv.z; acc[3][3] += av.w * wv.w;
        }
    }
    const float4 bb = *(const float4*)&bias[bn + (tx << 2)];
    #pragma unroll
    for (int i = 0; i < 4; ++i) {
        const int row = bm + (ty << 2) + i;
        float4 o;
        o.x = acc[i][0] + bb.x; o.y = acc[i][1] + bb.y;
        o.z = acc[i][2] + bb.z; o.w = acc[i][3] + bb.w;
        if (SPLIT) {
            const int b = row >> 11, s = row & (SEQ - 1), hh = bn >> 6;
            *(float4*)&C[((size_t)((b * NUM_HEADS + hh) * SEQ + s)) * DK + (tx << 2)] = o;
        } else {
            *(float4*)&C[(size_t)row * N + bn + (tx << 2)] = o;
        }
    }
}

__global__ __launch_bounds__(256, 2) void attn_fp32_kernel(
    const float* __restrict__ Q, const float* __restrict__ K,
    const float* __restrict__ V, const int* __restrict__ mask,
    float* __restrict__ OUT)
{
    const int qb = blockIdx.x, h = blockIdx.y, b = blockIdx.z;
    const int wave = threadIdx.x >> 6, lane = threadIdx.x & 63;
    const int tid = threadIdx.x;
    const int bh = b * NUM_HEADS + h;
    const float* Qb = Q + (size_t)bh * SEQ * DK;
    const float* Kb = K + (size_t)bh * SEQ * DK;
    const float* Vb = V + (size_t)bh * SEQ * DK;
    const int* mb = mask + b * SEQ;
    __shared__ float Ks[64][68];
    __shared__ float Vs[64][68];
    const int row = qb * 256 + wave * 64 + lane;
    float q[DK], ctx[DK];
    #pragma unroll
    for (int d4 = 0; d4 < 16; ++d4) {
        const float4 t = *(const float4*)&Qb[(size_t)row * DK + 4 * d4];
        q[4*d4] = t.x; q[4*d4+1] = t.y; q[4*d4+2] = t.z; q[4*d4+3] = t.w;
        ctx[4*d4] = 0.f; ctx[4*d4+1] = 0.f; ctx[4*d4+2] = 0.f; ctx[4*d4+3] = 0.f;
    }
    float m = -INFINITY, l = 0.f;
    for (int t = 0; t < SEQ / 64; ++t) {
        const int k0 = t * 64;
        const float* Kt = Kb + (size_t)k0 * DK;
        const float* Vt = Vb + (size_t)k0 * DK;
        __syncthreads();
        #pragma unroll
        for (int i = 0; i < 4; ++i) {
            const int f4 = i * 256 + tid;
            const int r = f4 >> 4, c = (f4 & 15) << 2;
            *(float4*)&Ks[r][c] = *(const float4*)&Kt[4 * f4];
            *(float4*)&Vs[r][c] = *(const float4*)&Vt[4 * f4];
        }
        __syncthreads();
        const unsigned long long mbits = __ballot(mb[k0 + lane] != 0);
        if (mbits == 0ULL) continue;
        for (int c0 = 0; c0 < 64; c0 += 16) {
            const unsigned bits = (unsigned)((mbits >> c0) & 0xFFFFULL);
            if (!bits) continue;
            float sc[16];
            #pragma unroll
            for (int j = 0; j < 16; ++j) {
                if (!((bits >> j) & 1u)) { sc[j] = -INFINITY; continue; }
                float a0 = 0.f, a1 = 0.f, a2 = 0.f, a3 = 0.f;
                #pragma unroll
                for (int d4 = 0; d4 < 16; ++d4) {
                    const float4 kv = *(const float4*)&Ks[c0 + j][4 * d4];
                    a0 += q[4*d4] * kv.x; a1 += q[4*d4+1] * kv.y;
                    a2 += q[4*d4+2] * kv.z; a3 += q[4*d4+3] * kv.w;
                }
                sc[j] = ((a0 + a1) + (a2 + a3)) * 0.125f;
            }
            float cmax = sc[0];
            #pragma unroll
            for (int j = 1; j < 16; ++j) cmax = fmaxf(cmax, sc[j]);
            if (cmax > m) {
                const float scale = __expf(m - cmax);
                l *= scale;
                #pragma unroll
                for (int d = 0; d < DK; ++d) ctx[d] *= scale;
                m = cmax;
            }
            #pragma unroll
            for (int j = 0; j < 16; ++j) {
                if (!((bits >> j) & 1u)) continue;
                const float p = __expf(sc[j] - m);
                l += p;
                #pragma unroll
                for (int d4 = 0; d4 < 16; ++d4) {
                    const float4 vv = *(const float4*)&Vs[c0 + j][4 * d4];
                    ctx[4*d4] += p * vv.x; ctx[4*d4+1] += p * vv.y;
                    ctx[4*d4+2] += p * vv.z; ctx[4*d4+3] += p * vv.w;
                }
            }
        }
    }
    const float inv = (l > 0.f) ? (1.f / l) : 0.f;
    float* dst = OUT + ((size_t)(b * SEQ + row)) * D_MODEL + h * DK;
    #pragma unroll
    for (int d4 = 0; d4 < 16; ++d4) {
        float4 o;
        o.x = ctx[4*d4] * inv; o.y = ctx[4*d4+1] * inv;
        o.z = ctx[4*d4+2] * inv; o.w = ctx[4*d4+3] * inv;
        *(float4*)&dst[4 * d4] = o;
    }
}

// ---------------------------------------------------------------------------
extern "C" void kernel_launch(void* const* d_in, const int* in_sizes, int n_in,
                              void* d_out, int out_size, void* d_ws, size_t ws_size,
                              hipStream_t stream)
{
    const float* query = (const float*)d_in[0];
    const float* key_  = (const float*)d_in[1];
    const float* value = (const float*)d_in[2];
    const int*   mask  = (const int*)d_in[3];
    const float* Wq = (const float*)d_in[4];
    const float* bq = (const float*)d_in[5];
    const float* Wk = (const float*)d_in[6];
    const float* bk = (const float*)d_in[7];
    const float* Wv = (const float*)d_in[8];
    const float* bv = (const float*)d_in[9];
    const float* Wo = (const float*)d_in[10];
    const float* bo = (const float*)d_in[11];
    float* out = (float*)d_out;

    const int M = BATCH * SEQ;                            // 4096
    const size_t ACT_B = (size_t)M * 1024 * 2;            // 8.39 MB (fp16)
    const size_t W_B   = (size_t)D_MODEL * 1024 * 2;      // 2.10 MB (fp16)
    const size_t K2_B  = (size_t)32 * SEQ * 64 * 2;       // 8.39 MB
    const size_t VT2_B = (size_t)32 * DK * SEQ * 2;       // 8.39 MB
    const size_t Q2_B  = K2_B;                            // 8.39 MB
    const size_t POS_B = (size_t)BATCH * SEQ * 4 + 256;

    char* base = (char*)d_ws;
    _Float16* actQh = (_Float16*)(base);
    _Float16* actKh = (_Float16*)(base + ACT_B);
    _Float16* actVh = (_Float16*)(base + 2 * ACT_B);
    _Float16* actO  = (_Float16*)(base + 3 * ACT_B);
    _Float16* w2qh  = (_Float16*)(base + 4 * ACT_B);
    _Float16* w2kh  = (_Float16*)((char*)w2qh + W_B);
    _Float16* w2vh  = (_Float16*)((char*)w2kh + W_B);
    _Float16* w2oh  = (_Float16*)((char*)w2vh + W_B);
    _Float16* k2    = (_Float16*)((char*)w2oh + W_B);
    _Float16* vt2   = (_Float16*)((char*)k2 + K2_B);
    _Float16* q2    = (_Float16*)((char*)vt2 + VT2_B);
    int* posArr = (int*)((char*)q2 + Q2_B);
    int* ncArr  = posArr + BATCH * SEQ;
    const size_t need = 4 * ACT_B + 4 * W_B + K2_B + VT2_B + Q2_B + POS_B; // ~67 MB

    if (ws_size >= need) {
        mask_scan_kernel<<<BATCH, 256, 0, stream>>>(mask, posArr, ncArr);

        // all 4 weights -> fp16 (one dispatch)
        conv_f16_kernel<0><<<dim3(D_MODEL / 2, 4), 256, 0, stream>>>(
            Wq, Wk, Wv, Wo, w2qh, w2kh, w2vh, w2oh, D_MODEL, nullptr, nullptr);

        // inputs: query plain, key_/value row-compacted (one dispatch)
        conv_f16_kernel<1><<<dim3(M / 2, 3), 256, 0, stream>>>(
            query, key_, value, nullptr, actQh, actKh, actVh, nullptr,
            M, mask, posArr);

        dim3 ggrid(M / 128, D_MODEL / 64);                // 32 x 16 = 512 blocks
        mfma_gemm_f16_kernel<2><<<ggrid, 256, 0, stream>>>(
            actKh, w2kh, bk, nullptr, k2, ncArr);
        mfma_gemm_f16_kernel<3><<<ggrid, 256, 0, stream>>>(
            actVh, w2vh, bv, nullptr, vt2, ncArr);
        mfma_gemm_f16_kernel<1><<<ggrid, 256, 0, stream>>>(
            actQh, w2qh, bq, nullptr, q2, ncArr);

        attn_mfma_kernel<<<1024, 256, 0, stream>>>(q2, k2, vt2, ncArr, actO);

        mfma_gemm_f16_kernel<0><<<ggrid, 256, 0, stream>>>(
            actO, w2oh, bo, out, nullptr, ncArr);
    } else {
        float* q_ws = (float*)(base);
        float* k_ws = (float*)(base + (size_t)M * D_MODEL * 4);
        float* v_ws = (float*)(base + 2 * (size_t)M * D_MODEL * 4);
        float* c_ws = (float*)(base + 3 * (size_t)M * D_MODEL * 4);
        dim3 ggrid(M / 64, D_MODEL / 64);
        gemm_bias_kernel<1><<<ggrid, 256, 0, stream>>>(query, Wq, bq, q_ws, M, D_MODEL, D_MODEL);
        gemm_bias_kernel<1><<<ggrid, 256, 0, stream>>>(key_,  Wk, bk, k_ws, M, D_MODEL, D_MODEL);
        gemm_bias_kernel<1><<<ggrid, 256, 0, stream>>>(value, Wv, bv, v_ws, M, D_MODEL, D_MODEL);
        dim3 agrid(SEQ / 256, NUM_HEADS, BATCH);
        attn_fp32_kernel<<<agrid, 256, 0, stream>>>(q_ws, k_ws, v_ws, mask, c_ws);
        gemm_bias_kernel<0><<<ggrid, 256, 0, stream>>>(c_ws, Wo, bo, out, M, D_MODEL, D_MODEL);
    }
}

// Round 18
// 134.009 us; speedup vs baseline: 2.2897x; 1.0058x over previous
//
#include <hip/hip_runtime.h>
#include <math.h>

#define D_MODEL 1024
#define NUM_HEADS 16
#define DK 64
#define BATCH 2
#define SEQ 2048

using f32x4  = __attribute__((ext_vector_type(4))) float;
using f16x8  = __attribute__((ext_vector_type(8))) _Float16;

__device__ __forceinline__ void gl_lds16(const void* g, void* l) {
    __builtin_amdgcn_global_load_lds(
        (const __attribute__((address_space(1))) void*)g,
        (__attribute__((address_space(3))) void*)l, 16, 0, 0);
}

// ---------------------------------------------------------------------------
// Per-batch prefix scan of mask: pos[b][s] = #valid keys before s, nc[b]=count
// ---------------------------------------------------------------------------
__global__ __launch_bounds__(256) void mask_scan_kernel(
    const int* __restrict__ mask, int* __restrict__ pos, int* __restrict__ nc)
{
    const int b = blockIdx.x;
    const int tid = threadIdx.x;
    __shared__ int sums[256];
    int v[8]; int cnt = 0;
    const int base = b * SEQ + tid * 8;
    #pragma unroll
    for (int e = 0; e < 8; ++e) { v[e] = (mask[base + e] != 0) ? 1 : 0; cnt += v[e]; }
    sums[tid] = cnt;
    __syncthreads();
    for (int off = 1; off < 256; off <<= 1) {
        int t = (tid >= off) ? sums[tid - off] : 0;
        __syncthreads();
        sums[tid] += t;
        __syncthreads();
    }
    int run = sums[tid] - cnt;           // exclusive prefix
    #pragma unroll
    for (int e = 0; e < 8; ++e) { pos[base + e] = run; run += v[e]; }
    if (tid == 255) nc[b] = sums[255];
}

// ---------------------------------------------------------------------------
// fp32 [rows][1024] -> fp16 [rows][1024], row-XOR swizzle baked in (stored
// 16B block ss = logical block ss ^ (STORED_row & 7), per 64-col group).
// COMPACT=1: y>0 streams row-compacted via pos[]. Up to 4 pairs via
// blockIdx.y; grid.x = rows/2.
// ---------------------------------------------------------------------------
template <int COMPACT>
__global__ __launch_bounds__(256) void conv_f16_kernel(
    const float* s0, const float* s1, const float* s2, const float* s3,
    _Float16* d0, _Float16* d1, _Float16* d2, _Float16* d3,
    int rows, const int* __restrict__ mask, const int* __restrict__ pos)
{
    const int y = blockIdx.y;
    const float* src = (y == 0) ? s0 : (y == 1) ? s1 : (y == 2) ? s2 : s3;
    _Float16* dst = (y == 0) ? d0 : (y == 1) ? d1 : (y == 2) ? d2 : d3;
    const int id = blockIdx.x * 256 + threadIdx.x;
    if (id >= rows * 128) return;
    const int row = id >> 7;
    int drow = row;
    if (COMPACT && y != 0) {
        if (!mask[row]) return;
        drow = (row >> 11) * SEQ + pos[row];
    }
    const int s  = id & 127;             // 16B block (8 f16) in [0,128)
    const int g  = s >> 3, ss = s & 7;
    const int lb = ss ^ (drow & 7);

    const float* p = src + (size_t)row * 1024 + g * 64 + lb * 8;
    const float4 a = *(const float4*)p;
    const float4 bq = *(const float4*)(p + 4);
    f16x8 o;
    o[0] = (_Float16)a.x;  o[1] = (_Float16)a.y;
    o[2] = (_Float16)a.z;  o[3] = (_Float16)a.w;
    o[4] = (_Float16)bq.x; o[5] = (_Float16)bq.y;
    o[6] = (_Float16)bq.z; o[7] = (_Float16)bq.w;
    *(f16x8*)&dst[(size_t)drow * 1024 + s * 8] = o;
}

// ---------------------------------------------------------------------------
// fp16 MFMA GEMM: K=1024, 16 k-steps, 128x64 tile, 3-buffer LDS + counted
// vmcnt + raw s_barrier (r13/r16/r17-proven pipeline).
// MODE epilogue:
//   0: fp32 [M][1024] -> d_out        (output projection)
//   1: Q2  fp16 [bh][s][64] = 0.125*v, block-XOR by s&7
//   2: K2  fp16 [bh][p][64] swz      (rows pre-COMPACTED; store if p<nc)
//   3: VT2 fp16 [bh][d][2048] key-block swz (pre-COMPACTED; store if p<nc)
// MODE 2/3: whole tile early-exits when its 128-row stripe is >= nc[b].
// ---------------------------------------------------------------------------
template <int MODE>
__global__ __launch_bounds__(256) void mfma_gemm_f16_kernel(
    const _Float16* __restrict__ A2, const _Float16* __restrict__ W2,
    const float* __restrict__ bias, float* __restrict__ Cf,
    _Float16* __restrict__ Ch, const int* __restrict__ ncArr)
{
    constexpr int KS = 1024;
    __shared__ f16x8 Asl[3][1024];
    __shared__ f16x8 Bsl[3][512];

    const int bm = blockIdx.x * 128, bn = blockIdx.y * 64;
    if (MODE == 2 || MODE == 3) {
        if ((bm & (SEQ - 1)) >= ncArr[bm >> 11]) return;   // uniform exit
    }

    const int tid = threadIdx.x;
    const int wv = tid >> 6, ln = tid & 63;
    const int wm = wv >> 1, wn = wv & 1;
    const int x = ln & 15, y = ln >> 4;

    f32x4 acc[4][2] = {};

    const _Float16* Ab = A2 + (size_t)bm * KS;
    const _Float16* Bb = W2 + (size_t)bn * KS;
    const int srow = ln >> 3;
    const int scol = (ln & 7) * 8;

    auto stage = [&](int bufi, int kt) {
        #pragma unroll
        for (int c = 0; c < 4; ++c) {
            const int rowb = wv * 32 + c * 8;
            gl_lds16(Ab + (size_t)(rowb + srow) * KS + kt * 64 + scol,
                     &Asl[bufi][rowb << 3]);
        }
        #pragma unroll
        for (int c = 0; c < 2; ++c) {
            const int rowb = wv * 16 + c * 8;
            gl_lds16(Bb + (size_t)(rowb + srow) * KS + kt * 64 + scol,
                     &Bsl[bufi][rowb << 3]);
        }
    };

    stage(0, 0);
    stage(1, 1);

    int buf = 0, sbuf = 2;
    for (int kt = 0; kt < 16; ++kt) {
        if (kt < 15) asm volatile("s_waitcnt vmcnt(6)" ::: "memory");
        else         asm volatile("s_waitcnt vmcnt(0)" ::: "memory");
        __builtin_amdgcn_s_barrier();
        if (kt + 2 < 16) stage(sbuf, kt + 2);
        #pragma unroll
        for (int half = 0; half < 2; ++half) {
            f16x8 af[4], bfr[2];
            #pragma unroll
            for (int mf = 0; mf < 4; ++mf) {
                const int r = wm * 64 + mf * 16 + x;
                af[mf] = Asl[buf][(r << 3) | ((half * 4 + y) ^ (r & 7))];
            }
            #pragma unroll
            for (int nf = 0; nf < 2; ++nf) {
                const int r = wn * 32 + nf * 16 + x;
                bfr[nf] = Bsl[buf][(r << 3) | ((half * 4 + y) ^ (r & 7))];
            }
            #pragma unroll
            for (int mf = 0; mf < 4; ++mf)
                #pragma unroll
                for (int nf = 0; nf < 2; ++nf)
                    acc[mf][nf] = __builtin_amdgcn_mfma_f32_16x16x32_f16(
                        af[mf], bfr[nf], acc[mf][nf], 0, 0, 0);
        }
        buf  = (buf  == 2) ? 0 : buf  + 1;
        sbuf = (sbuf == 2) ? 0 : sbuf + 1;
    }

    // epilogue (C/D: col=lane&15, row=(lane>>4)*4+r)  [m89-verified]
    #pragma unroll
    for (int nf = 0; nf < 2; ++nf) {
        const int n = bn + wn * 32 + nf * 16 + x;
        const float bv = bias[n];
        #pragma unroll
        for (int mf = 0; mf < 4; ++mf) {
            const int mbase = bm + wm * 64 + mf * 16 + y * 4;
            #pragma unroll
            for (int r = 0; r < 4; ++r) {
                const int m = mbase + r;
                const float v = acc[mf][nf][r] + bv;
                const int b = m >> 11, s = m & (SEQ - 1);
                const int hh = n >> 6, dd = n & 63;
                if (MODE == 0) {
                    Cf[(size_t)m * D_MODEL + n] = v;
                } else if (MODE == 1) {
                    const int blk = (dd >> 3) ^ (s & 7), i = dd & 7;
                    Ch[((size_t)((b * NUM_HEADS + hh) * SEQ + s)) * 64 +
                       blk * 8 + i] = (_Float16)(v * 0.125f);
                } else if (MODE == 2) {
                    if (s < ncArr[b]) {          // s IS the compacted index
                        const int blk = (dd >> 3) ^ (s & 7), i = dd & 7;
                        Ch[((size_t)((b * NUM_HEADS + hh) * SEQ + s)) * 64 +
                           blk * 8 + i] = (_Float16)v;
                    }
                } else {
                    if (s < ncArr[b]) {
                        const int tile = s >> 6, w = s & 63;
                        const int blk = (w >> 3) ^ (dd & 7), i = w & 7;
                        Ch[((size_t)((b * NUM_HEADS + hh) * DK + dd)) * SEQ +
                           tile * 64 + blk * 8 + i] = (_Float16)v;
                    }
                }
            }
        }
    }
}

// ---------------------------------------------------------------------------
// All-fp16 MFMA flash attention over COMPACTED keys.
// NEW (r18): double-buffered K/V staging (LDS 40 KB) — issue tile t+1's
// loads before computing tile t, retire with counted vmcnt(4) + raw
// s_barrier (r13-proven pattern); s_setprio(1) around MFMA clusters (T5).
// ---------------------------------------------------------------------------
__global__ __launch_bounds__(256, 3) void attn_mfma_kernel(
    const _Float16* __restrict__ Q2, const _Float16* __restrict__ K2,
    const _Float16* __restrict__ VT2, const int* __restrict__ ncArr,
    _Float16* __restrict__ ACT)
{
    __shared__ __align__(16) _Float16 SM[20480];   // 40 KB
    // buf0: Ks@0 VTs@4096 | buf1: Ks@8192 VTs@12288 | Pw@16384 (4x1024)

    const int tid = threadIdx.x;
    const int wave = tid >> 6, lane = tid & 63;
    const int lo4 = lane & 15, hi4 = lane >> 4;
    _Float16* Pw = SM + 16384 + wave * 1024;

    const int orig = blockIdx.x;
    const int swz = (orig & 7) * 128 + (orig >> 3);  // 1024%8==0: bijective
    const int bh = swz >> 5, qblk = swz & 31;
    const int b = bh >> 4, h = bh & 15;

    const _Float16* Kb = K2 + (size_t)bh * SEQ * 64;
    const _Float16* Vb = VT2 + (size_t)bh * DK * SEQ;

    const int ncb = ncArr[b];
    const int ntiles = (ncb + 63) >> 6;

    // Q fragments (0.125-scaled fp16, XOR-swizzled by s&7)
    const int qr = qblk * 64 + wave * 16 + lo4;
    const _Float16* Q2row = Q2 + (size_t)(bh * SEQ + qr) * 64;
    f16x8 qf[2];
    #pragma unroll
    for (int c = 0; c < 2; ++c)
        qf[c] = *(const f16x8*)&Q2row[(((c * 4 + hi4) ^ (qr & 7)) * 8)];

    // 4 loads/thread per tile: Ks (512 x16B) | VTs (512 x16B)
    auto stage_kv = [&](int base, int k0) {
        #pragma unroll
        for (int j = 0; j < 4; ++j) {
            const int g = j * 256 + wave * 64;   // wave-uniform dest base
            const int gi = g + lane;
            const _Float16* src;
            if (gi < 512) {
                src = Kb + (size_t)(k0 + (gi >> 3)) * 64 + (gi & 7) * 8;
            } else {
                const int g2 = gi - 512;
                src = Vb + (size_t)(g2 >> 3) * SEQ + k0 + (g2 & 7) * 8;
            }
            gl_lds16(src, SM + base + (size_t)g * 8);
        }
    };

    f32x4 ctx[4] = {};   // ctx^T frags: row d = dt*16+hi4*4+r, col q = lo4
    float m = -INFINITY, l = 0.f;

    stage_kv(0, 0);
    for (int t = 0; t < ntiles; ++t) {
        if (t + 1 < ntiles) {
            stage_kv(((t + 1) & 1) * 8192, (t + 1) * 64);  // prefetch next
            asm volatile("s_waitcnt vmcnt(4)" ::: "memory"); // retire tile t
        } else {
            asm volatile("s_waitcnt vmcnt(0)" ::: "memory");
        }
        __builtin_amdgcn_s_barrier();        // tile t visible to all waves

        const _Float16* Ks = SM + (t & 1) * 8192;
        const _Float16* VTs = Ks + 4096;
        const int k0 = t * 64;

        // S^T = K . Q^T : rows = key, cols = q (single fp16 term)
        f32x4 sc[4];
        __builtin_amdgcn_s_setprio(1);
        #pragma unroll
        for (int kt = 0; kt < 4; ++kt) {
            f32x4 s = {0.f, 0.f, 0.f, 0.f};
            const int row = kt * 16 + lo4;
            const int rx = row & 7;
            #pragma unroll
            for (int c = 0; c < 2; ++c) {
                const f16x8 kf = *(f16x8*)&Ks[row * 64 + (((c * 4 + hi4) ^ rx) * 8)];
                s = __builtin_amdgcn_mfma_f32_16x16x32_f16(kf, qf[c], s, 0, 0, 0);
            }
            sc[kt] = s;
        }
        __builtin_amdgcn_s_setprio(0);

        // row-max; tail tile masks invalid keys (kidx >= ncb) to -1e30
        float cmax = -1e30f;
        if (k0 + 64 <= ncb) {
            #pragma unroll
            for (int kt = 0; kt < 4; ++kt)
                #pragma unroll
                for (int r = 0; r < 4; ++r) cmax = fmaxf(cmax, sc[kt][r]);
        } else {
            #pragma unroll
            for (int kt = 0; kt < 4; ++kt)
                #pragma unroll
                for (int r = 0; r < 4; ++r) {
                    const int kidx = k0 + kt * 16 + hi4 * 4 + r;
                    const float sv = (kidx < ncb) ? sc[kt][r] : -1e30f;
                    sc[kt][r] = sv;
                    cmax = fmaxf(cmax, sv);
                }
        }
        cmax = fmaxf(cmax, __shfl_xor(cmax, 16));
        cmax = fmaxf(cmax, __shfl_xor(cmax, 32));

        const float mnew = fmaxf(m, cmax);
        const float e1 = __expf(m - mnew);   // m=-inf pre-first-tile -> 0
        m = mnew;

        float ps = 0.f;
        #pragma unroll
        for (int kt = 0; kt < 4; ++kt) {
            const float pv0 = __expf(sc[kt][0] - mnew);  // -1e30 -> exp = 0
            const float pv1 = __expf(sc[kt][1] - mnew);
            const float pv2 = __expf(sc[kt][2] - mnew);
            const float pv3 = __expf(sc[kt][3] - mnew);
            ps += (pv0 + pv1) + (pv2 + pv3);
            union { _Float16 hh[2]; unsigned u; } pk0, pk1;   // fp16 RNE pack
            pk0.hh[0] = (_Float16)pv0; pk0.hh[1] = (_Float16)pv1;
            pk1.hh[0] = (_Float16)pv2; pk1.hh[1] = (_Float16)pv3;
            const int blk16 = (kt * 2 + (hi4 >> 1)) ^ (lo4 & 7);
            unsigned* dst = (unsigned*)&Pw[lo4 * 64 + blk16 * 8 + (hi4 & 1) * 4];
            dst[0] = pk0.u; dst[1] = pk1.u;
        }
        ps += __shfl_xor(ps, 16);
        ps += __shfl_xor(ps, 32);
        l = l * e1 + ps;

        #pragma unroll
        for (int dt = 0; dt < 4; ++dt)
            #pragma unroll
            for (int r = 0; r < 4; ++r) ctx[dt][r] *= e1;

        // ctx^T += V^T . P^T  (same-wave LDS RAW: compiler orders via lgkmcnt)
        __builtin_amdgcn_s_setprio(1);
        #pragma unroll
        for (int c = 0; c < 2; ++c) {
            const f16x8 pf = *(f16x8*)&Pw[lo4 * 64 + (((c * 4 + hi4) ^ (lo4 & 7)) * 8)];
            #pragma unroll
            for (int dt = 0; dt < 4; ++dt) {
                const int row = dt * 16 + lo4;
                const f16x8 vf =
                    *(f16x8*)&VTs[row * 64 + (((c * 4 + hi4) ^ (row & 7)) * 8)];
                ctx[dt] = __builtin_amdgcn_mfma_f32_16x16x32_f16(vf, pf, ctx[dt], 0, 0, 0);
            }
        }
        __builtin_amdgcn_s_setprio(0);

        __builtin_amdgcn_s_barrier();        // all waves done reading buf t
    }

    // epilogue: normalize, LDS transpose (stride 68, conflict-free),
    // fused fp16 swizzled activation write
    __syncthreads();
    const float inv = (l > 0.f) ? (1.f / l) : 0.f;   // l==0: fully masked -> 0
    float* OutL = (float*)SM;                        // [64 q][68] fp32
    #pragma unroll
    for (int dt = 0; dt < 4; ++dt)
        #pragma unroll
        for (int r = 0; r < 4; ++r)
            OutL[(wave * 16 + lo4) * 68 + dt * 16 + hi4 * 4 + r] = ctx[dt][r] * inv;
    __syncthreads();
    {
        const int row = tid >> 2, cb = (tid & 3) * 16;
        const int mrow = b * SEQ + qblk * 64 + row;      // global act row
        _Float16* arow = ACT + (size_t)mrow * 1024;
        #pragma unroll
        for (int u = 0; u < 2; ++u) {
            const int lb = (cb >> 3) + u;                // logical 8-col block
            const int ss = lb ^ (mrow & 7);              // stored (swizzled)
            f16x8 hv;
            #pragma unroll
            for (int i = 0; i < 8; ++i)
                hv[i] = (_Float16)OutL[row * 68 + cb + u * 8 + i];
            *(f16x8*)&arow[h * 64 + ss * 8] = hv;
        }
    }
}

// ---------------------------------------------------------------------------
// fp32 fallback path (only if ws too small)
// ---------------------------------------------------------------------------
template <int SPLIT>
__global__ __launch_bounds__(256) void gemm_bias_kernel(
    const float* __restrict__ A, const float* __restrict__ W,
    const float* __restrict__ bias, float* __restrict__ C,
    int M, int N, int K)
{
    constexpr int TILE = 64, KT = 16;
    __shared__ float As[KT][TILE + 4];
    __shared__ float Ws[KT][TILE + 4];
    const int tid = threadIdx.x;
    const int tx = tid & 15, ty = tid >> 4;
    const int bm = blockIdx.x * TILE, bn = blockIdx.y * TILE;
    const int lrow = tid >> 2, lk4 = (tid & 3) << 2;
    float acc[4][4] = {{0.f}};
    for (int k0 = 0; k0 < K; k0 += KT) {
        const float4 a4 = *(const float4*)&A[(size_t)(bm + lrow) * K + k0 + lk4];
        const float4 w4 = *(const float4*)&W[(size_t)(bn + lrow) * K + k0 + lk4];
        __syncthreads();
        As[lk4 + 0][lrow] = a4.x; As[lk4 + 1][lrow] = a4.y;
        As[lk4 + 2][lrow] = a4.z; As[lk4 + 3][lrow] = a4.w;
        Ws[lk4 + 0][lrow] = w4.x; Ws[lk4 + 1][lrow] = w4.y;
        Ws[lk4 + 2][lrow] = w4.z; Ws[lk4 + 3][lrow] = w4.w;
        __syncthreads();
        #pragma unroll
        for (int kk = 0; kk < KT; ++kk) {
            const float4 av = *(const float4*)&As[kk][ty << 2];
            const float4 wv = *(const float4*)&Ws[kk][tx << 2];
            acc[0][0] += av.x * wv.x; acc[0][1] += av.x * wv.y; acc[0][2] += av.x * wv.z; acc[0][3] += av.x * wv.w;
            acc[1][0] += av.y * wv.x; acc[1][1] += av.y * wv.y; acc[1][2] += av.y * wv.z; acc[1][3] += av.y * wv.w;
            acc[2][0] += av.z * wv.x; acc[2][1] += av.z * wv.y; acc[2][2] += av.z * wv.z; acc[2][3] += av.z * wv.w;
            acc[3][0] += av.w * wv.x; acc[3][1] += av.w * wv.y; acc[3][2] += av.w * wv.z; acc[3][3] += av.w * wv.w;
        }
    }
    const float4 bb = *(const float4*)&bias[bn + (tx << 2)];
    #pragma unroll
    for (int i = 0; i < 4; ++i) {
        const int row = bm + (ty << 2) + i;
        float4 o;
        o.x = acc[i][0] + bb.x; o.y = acc[i][1] + bb.y;
        o.z = acc[i][2] + bb.z; o.w = acc[i][3] + bb.w;
        if (SPLIT) {
            const int b = row >> 11, s = row & (SEQ - 1), hh = bn >> 6;
            *(float4*)&C[((size_t)((b * NUM_HEADS + hh) * SEQ + s)) * DK + (tx << 2)] = o;
        } else {
            *(float4*)&C[(size_t)row * N + bn + (tx << 2)] = o;
        }
    }
}

__global__ __launch_bounds__(256, 2) void attn_fp32_kernel(
    const float* __restrict__ Q, const float* __restrict__ K,
    const float* __restrict__ V, const int* __restrict__ mask,
    float* __restrict__ OUT)
{
    const int qb = blockIdx.x, h = blockIdx.y, b = blockIdx.z;
    const int wave = threadIdx.x >> 6, lane = threadIdx.x & 63;
    const int tid = threadIdx.x;
    const int bh = b * NUM_HEADS + h;
    const float* Qb = Q + (size_t)bh * SEQ * DK;
    const float* Kb = K + (size_t)bh * SEQ * DK;
    const float* Vb = V + (size_t)bh * SEQ * DK;
    const int* mb = mask + b * SEQ;
    __shared__ float Ks[64][68];
    __shared__ float Vs[64][68];
    const int row = qb * 256 + wave * 64 + lane;
    float q[DK], ctx[DK];
    #pragma unroll
    for (int d4 = 0; d4 < 16; ++d4) {
        const float4 t = *(const float4*)&Qb[(size_t)row * DK + 4 * d4];
        q[4*d4] = t.x; q[4*d4+1] = t.y; q[4*d4+2] = t.z; q[4*d4+3] = t.w;
        ctx[4*d4] = 0.f; ctx[4*d4+1] = 0.f; ctx[4*d4+2] = 0.f; ctx[4*d4+3] = 0.f;
    }
    float m = -INFINITY, l = 0.f;
    for (int t = 0; t < SEQ / 64; ++t) {
        const int k0 = t * 64;
        const float* Kt = Kb + (size_t)k0 * DK;
        const float* Vt = Vb + (size_t)k0 * DK;
        __syncthreads();
        #pragma unroll
        for (int i = 0; i < 4; ++i) {
            const int f4 = i * 256 + tid;
            const int r = f4 >> 4, c = (f4 & 15) << 2;
            *(float4*)&Ks[r][c] = *(const float4*)&Kt[4 * f4];
            *(float4*)&Vs[r][c] = *(const float4*)&Vt[4 * f4];
        }
        __syncthreads();
        const unsigned long long mbits = __ballot(mb[k0 + lane] != 0);
        if (mbits == 0ULL) continue;
        for (int c0 = 0; c0 < 64; c0 += 16) {
            const unsigned bits = (unsigned)((mbits >> c0) & 0xFFFFULL);
            if (!bits) continue;
            float sc[16];
            #pragma unroll
            for (int j = 0; j < 16; ++j) {
                if (!((bits >> j) & 1u)) { sc[j] = -INFINITY; continue; }
                float a0 = 0.f, a1 = 0.f, a2 = 0.f, a3 = 0.f;
                #pragma unroll
                for (int d4 = 0; d4 < 16; ++d4) {
                    const float4 kv = *(const float4*)&Ks[c0 + j][4 * d4];
                    a0 += q[4*d4] * kv.x; a1 += q[4*d4+1] * kv.y;
                    a2 += q[4*d4+2] * kv.z; a3 += q[4*d4+3] * kv.w;
                }
                sc[j] = ((a0 + a1) + (a2 + a3)) * 0.125f;
            }
            float cmax = sc[0];
            #pragma unroll
            for (int j = 1; j < 16; ++j) cmax = fmaxf(cmax, sc[j]);
            if (cmax > m) {
                const float scale = __expf(m - cmax);
                l *= scale;
                #pragma unroll
                for (int d = 0; d < DK; ++d) ctx[d] *= scale;
                m = cmax;
            }
            #pragma unroll
            for (int j = 0; j < 16; ++j) {
                if (!((bits >> j) & 1u)) continue;
                const float p = __expf(sc[j] - m);
                l += p;
                #pragma unroll
                for (int d4 = 0; d4 < 16; ++d4) {
                    const float4 vv = *(const float4*)&Vs[c0 + j][4 * d4];
                    ctx[4*d4] += p * vv.x; ctx[4*d4+1] += p * vv.y;
                    ctx[4*d4+2] += p * vv.z; ctx[4*d4+3] += p * vv.w;
                }
            }
        }
    }
    const float inv = (l > 0.f) ? (1.f / l) : 0.f;
    float* dst = OUT + ((size_t)(b * SEQ + row)) * D_MODEL + h * DK;
    #pragma unroll
    for (int d4 = 0; d4 < 16; ++d4) {
        float4 o;
        o.x = ctx[4*d4] * inv; o.y = ctx[4*d4+1] * inv;
        o.z = ctx[4*d4+2] * inv; o.w = ctx[4*d4+3] * inv;
        *(float4*)&dst[4 * d4] = o;
    }
}

// ---------------------------------------------------------------------------
extern "C" void kernel_launch(void* const* d_in, const int* in_sizes, int n_in,
                              void* d_out, int out_size, void* d_ws, size_t ws_size,
                              hipStream_t stream)
{
    const float* query = (const float*)d_in[0];
    const float* key_  = (const float*)d_in[1];
    const float* value = (const float*)d_in[2];
    const int*   mask  = (const int*)d_in[3];
    const float* Wq = (const float*)d_in[4];
    const float* bq = (const float*)d_in[5];
    const float* Wk = (const float*)d_in[6];
    const float* bk = (const float*)d_in[7];
    const float* Wv = (const float*)d_in[8];
    const float* bv = (const float*)d_in[9];
    const float* Wo = (const float*)d_in[10];
    const float* bo = (const float*)d_in[11];
    float* out = (float*)d_out;

    const int M = BATCH * SEQ;                            // 4096
    const size_t ACT_B = (size_t)M * 1024 * 2;            // 8.39 MB (fp16)
    const size_t W_B   = (size_t)D_MODEL * 1024 * 2;      // 2.10 MB (fp16)
    const size_t K2_B  = (size_t)32 * SEQ * 64 * 2;       // 8.39 MB
    const size_t VT2_B = (size_t)32 * DK * SEQ * 2;       // 8.39 MB
    const size_t Q2_B  = K2_B;                            // 8.39 MB
    const size_t POS_B = (size_t)BATCH * SEQ * 4 + 256;

    char* base = (char*)d_ws;
    _Float16* actQh = (_Float16*)(base);
    _Float16* actKh = (_Float16*)(base + ACT_B);
    _Float16* actVh = (_Float16*)(base + 2 * ACT_B);
    _Float16* actO  = (_Float16*)(base + 3 * ACT_B);
    _Float16* w2qh  = (_Float16*)(base + 4 * ACT_B);
    _Float16* w2kh  = (_Float16*)((char*)w2qh + W_B);
    _Float16* w2vh  = (_Float16*)((char*)w2kh + W_B);
    _Float16* w2oh  = (_Float16*)((char*)w2vh + W_B);
    _Float16* k2    = (_Float16*)((char*)w2oh + W_B);
    _Float16* vt2   = (_Float16*)((char*)k2 + K2_B);
    _Float16* q2    = (_Float16*)((char*)vt2 + VT2_B);
    int* posArr = (int*)((char*)q2 + Q2_B);
    int* ncArr  = posArr + BATCH * SEQ;
    const size_t need = 4 * ACT_B + 4 * W_B + K2_B + VT2_B + Q2_B + POS_B; // ~67 MB

    if (ws_size >= need) {
        mask_scan_kernel<<<BATCH, 256, 0, stream>>>(mask, posArr, ncArr);

        // all 4 weights -> fp16 (one dispatch)
        conv_f16_kernel<0><<<dim3(D_MODEL / 2, 4), 256, 0, stream>>>(
            Wq, Wk, Wv, Wo, w2qh, w2kh, w2vh, w2oh, D_MODEL, nullptr, nullptr);

        // inputs: query plain, key_/value row-compacted (one dispatch)
        conv_f16_kernel<1><<<dim3(M / 2, 3), 256, 0, stream>>>(
            query, key_, value, nullptr, actQh, actKh, actVh, nullptr,
            M, mask, posArr);

        dim3 ggrid(M / 128, D_MODEL / 64);                // 32 x 16 = 512 blocks
        mfma_gemm_f16_kernel<2><<<ggrid, 256, 0, stream>>>(
            actKh, w2kh, bk, nullptr, k2, ncArr);
        mfma_gemm_f16_kernel<3><<<ggrid, 256, 0, stream>>>(
            actVh, w2vh, bv, nullptr, vt2, ncArr);
        mfma_gemm_f16_kernel<1><<<ggrid, 256, 0, stream>>>(
            actQh, w2qh, bq, nullptr, q2, ncArr);

        attn_mfma_kernel<<<1024, 256, 0, stream>>>(q2, k2, vt2, ncArr, actO);

        mfma_gemm_f16_kernel<0><<<ggrid, 256, 0, stream>>>(
            actO, w2oh, bo, out, nullptr, ncArr);
    } else {
        float* q_ws = (float*)(base);
        float* k_ws = (float*)(base + (size_t)M * D_MODEL * 4);
        float* v_ws = (float*)(base + 2 * (size_t)M * D_MODEL * 4);
        float* c_ws = (float*)(base + 3 * (size_t)M * D_MODEL * 4);
        dim3 ggrid(M / 64, D_MODEL / 64);
        gemm_bias_kernel<1><<<ggrid, 256, 0, stream>>>(query, Wq, bq, q_ws, M, D_MODEL, D_MODEL);
        gemm_bias_kernel<1><<<ggrid, 256, 0, stream>>>(key_,  Wk, bk, k_ws, M, D_MODEL, D_MODEL);
        gemm_bias_kernel<1><<<ggrid, 256, 0, stream>>>(value, Wv, bv, v_ws, M, D_MODEL, D_MODEL);
        dim3 agrid(SEQ / 256, NUM_HEADS, BATCH);
        attn_fp32_kernel<<<agrid, 256, 0, stream>>>(q_ws, k_ws, v_ws, mask, c_ws);
        gemm_bias_kernel<0><<<ggrid, 256, 0, stream>>>(c_ws, Wo, bo, out, M, D_MODEL, D_MODEL);
    }
}

// Round 20
// 133.278 us; speedup vs baseline: 2.3023x; 1.0055x over previous
//
#include <hip/hip_runtime.h>
#include <math.h>

#define D_MODEL 1024
#define NUM_HEADS 16
#define DK 64
#define BATCH 2
#define SEQ 2048

using f32x4  = __attribute__((ext_vector_type(4))) float;
using f16x8  = __attribute__((ext_vector_type(8))) _Float16;

__device__ __forceinline__ void gl_lds16(const void* g, void* l) {
    __builtin_amdgcn_global_load_lds(
        (const __attribute__((address_space(1))) void*)g,
        (__attribute__((address_space(3))) void*)l, 16, 0, 0);
}

// ---------------------------------------------------------------------------
// Per-batch prefix scan of mask: pos[b][s] = #valid keys before s, nc[b]=count
// ---------------------------------------------------------------------------
__global__ __launch_bounds__(256) void mask_scan_kernel(
    const int* __restrict__ mask, int* __restrict__ pos, int* __restrict__ nc)
{
    const int b = blockIdx.x;
    const int tid = threadIdx.x;
    __shared__ int sums[256];
    int v[8]; int cnt = 0;
    const int base = b * SEQ + tid * 8;
    #pragma unroll
    for (int e = 0; e < 8; ++e) { v[e] = (mask[base + e] != 0) ? 1 : 0; cnt += v[e]; }
    sums[tid] = cnt;
    __syncthreads();
    for (int off = 1; off < 256; off <<= 1) {
        int t = (tid >= off) ? sums[tid - off] : 0;
        __syncthreads();
        sums[tid] += t;
        __syncthreads();
    }
    int run = sums[tid] - cnt;           // exclusive prefix
    #pragma unroll
    for (int e = 0; e < 8; ++e) { pos[base + e] = run; run += v[e]; }
    if (tid == 255) nc[b] = sums[255];
}

// ---------------------------------------------------------------------------
// ALL conversions in one dispatch. fp32 [rows][1024] -> fp16 [rows][1024],
// row-XOR swizzle baked in (stored 16B block ss = logical ss ^ (drow&7)).
// y=0..3: weights (rows=1024); y=4: query; y=5/6: key_/value row-compacted.
// grid = (2048, 7); weight streams early-exit past 512 blocks.
// ---------------------------------------------------------------------------
__global__ __launch_bounds__(256) void conv_all_kernel(
    const float* Wq, const float* Wk, const float* Wv, const float* Wo,
    const float* query, const float* key_, const float* value,
    _Float16* w2q, _Float16* w2k, _Float16* w2v, _Float16* w2o,
    _Float16* aq, _Float16* ak, _Float16* av,
    const int* __restrict__ mask, const int* __restrict__ pos)
{
    const int y = blockIdx.y;
    const float* src; _Float16* dst; int rows; bool compact = false;
    switch (y) {
        case 0: src = Wq;    dst = w2q; rows = 1024; break;
        case 1: src = Wk;    dst = w2k; rows = 1024; break;
        case 2: src = Wv;    dst = w2v; rows = 1024; break;
        case 3: src = Wo;    dst = w2o; rows = 1024; break;
        case 4: src = query; dst = aq;  rows = 4096; break;
        case 5: src = key_;  dst = ak;  rows = 4096; compact = true; break;
        default: src = value; dst = av; rows = 4096; compact = true; break;
    }
    const int id = blockIdx.x * 256 + threadIdx.x;
    if (id >= rows * 128) return;
    const int row = id >> 7;
    int drow = row;
    if (compact) {
        if (!mask[row]) return;
        drow = (row >> 11) * SEQ + pos[row];
    }
    const int s  = id & 127;             // 16B block (8 f16) in [0,128)
    const int g  = s >> 3, ss = s & 7;
    const int lb = ss ^ (drow & 7);

    const float* p = src + (size_t)row * 1024 + g * 64 + lb * 8;
    const float4 a = *(const float4*)p;
    const float4 bq = *(const float4*)(p + 4);
    f16x8 o;
    o[0] = (_Float16)a.x;  o[1] = (_Float16)a.y;
    o[2] = (_Float16)a.z;  o[3] = (_Float16)a.w;
    o[4] = (_Float16)bq.x; o[5] = (_Float16)bq.y;
    o[6] = (_Float16)bq.z; o[7] = (_Float16)bq.w;
    *(f16x8*)&dst[(size_t)drow * 1024 + s * 8] = o;
}

// ---------------------------------------------------------------------------
// Merged QKV fp16 MFMA GEMM: grid.z = 0/1/2 -> Q/K/V chain (z slowest-
// varying: Q blocks dispatch first -> same L2 locality as 3 dispatches,
// zero launch gaps). K=1024, 16 k-steps, 128x64 tile, 3-buffer LDS +
// counted vmcnt + raw s_barrier (r13/r16-proven pipeline).
//   z=0: Q2  fp16 [bh][s][64] = 0.125*v, block-XOR by s&7
//   z=1: K2  fp16 [bh][p][64] swz  (rows pre-COMPACTED; store if p<nc)
//   z=2: VT2 fp16 [bh][d][2048] key-block swz (pre-COMPACTED; p<nc)
// z=1/2: whole tile early-exits when its 128-row stripe is >= nc[b].
// ---------------------------------------------------------------------------
__global__ __launch_bounds__(256) void mfma_gemm_qkv_kernel(
    const _Float16* __restrict__ aQ, const _Float16* __restrict__ aK,
    const _Float16* __restrict__ aV,
    const _Float16* __restrict__ wQ, const _Float16* __restrict__ wK,
    const _Float16* __restrict__ wV,
    const float* __restrict__ bQ, const float* __restrict__ bK,
    const float* __restrict__ bV,
    _Float16* __restrict__ q2, _Float16* __restrict__ k2,
    _Float16* __restrict__ vt2, const int* __restrict__ ncArr)
{
    constexpr int KS = 1024;
    __shared__ f16x8 Asl[3][1024];
    __shared__ f16x8 Bsl[3][512];

    const int z = blockIdx.z;
    const _Float16* A2 = (z == 0) ? aQ : (z == 1) ? aK : aV;
    const _Float16* W2 = (z == 0) ? wQ : (z == 1) ? wK : wV;
    const float* bias  = (z == 0) ? bQ : (z == 1) ? bK : bV;

    const int bm = blockIdx.x * 128, bn = blockIdx.y * 64;
    if (z != 0) {
        if ((bm & (SEQ - 1)) >= ncArr[bm >> 11]) return;   // uniform exit
    }

    const int tid = threadIdx.x;
    const int wv = tid >> 6, ln = tid & 63;
    const int wm = wv >> 1, wn = wv & 1;
    const int x = ln & 15, y = ln >> 4;

    f32x4 acc[4][2] = {};

    const _Float16* Ab = A2 + (size_t)bm * KS;
    const _Float16* Bb = W2 + (size_t)bn * KS;
    const int srow = ln >> 3;
    const int scol = (ln & 7) * 8;

    auto stage = [&](int bufi, int kt) {
        #pragma unroll
        for (int c = 0; c < 4; ++c) {
            const int rowb = wv * 32 + c * 8;
            gl_lds16(Ab + (size_t)(rowb + srow) * KS + kt * 64 + scol,
                     &Asl[bufi][rowb << 3]);
        }
        #pragma unroll
        for (int c = 0; c < 2; ++c) {
            const int rowb = wv * 16 + c * 8;
            gl_lds16(Bb + (size_t)(rowb + srow) * KS + kt * 64 + scol,
                     &Bsl[bufi][rowb << 3]);
        }
    };

    stage(0, 0);
    stage(1, 1);

    int buf = 0, sbuf = 2;
    for (int kt = 0; kt < 16; ++kt) {
        if (kt < 15) asm volatile("s_waitcnt vmcnt(6)" ::: "memory");
        else         asm volatile("s_waitcnt vmcnt(0)" ::: "memory");
        __builtin_amdgcn_s_barrier();
        if (kt + 2 < 16) stage(sbuf, kt + 2);
        #pragma unroll
        for (int half = 0; half < 2; ++half) {
            f16x8 af[4], bfr[2];
            #pragma unroll
            for (int mf = 0; mf < 4; ++mf) {
                const int r = wm * 64 + mf * 16 + x;
                af[mf] = Asl[buf][(r << 3) | ((half * 4 + y) ^ (r & 7))];
            }
            #pragma unroll
            for (int nf = 0; nf < 2; ++nf) {
                const int r = wn * 32 + nf * 16 + x;
                bfr[nf] = Bsl[buf][(r << 3) | ((half * 4 + y) ^ (r & 7))];
            }
            #pragma unroll
            for (int mf = 0; mf < 4; ++mf)
                #pragma unroll
                for (int nf = 0; nf < 2; ++nf)
                    acc[mf][nf] = __builtin_amdgcn_mfma_f32_16x16x32_f16(
                        af[mf], bfr[nf], acc[mf][nf], 0, 0, 0);
        }
        buf  = (buf  == 2) ? 0 : buf  + 1;
        sbuf = (sbuf == 2) ? 0 : sbuf + 1;
    }

    // epilogue (C/D: col=lane&15, row=(lane>>4)*4+r)  [m89-verified]
    #pragma unroll
    for (int nf = 0; nf < 2; ++nf) {
        const int n = bn + wn * 32 + nf * 16 + x;
        const float bv = bias[n];
        #pragma unroll
        for (int mf = 0; mf < 4; ++mf) {
            const int mbase = bm + wm * 64 + mf * 16 + y * 4;
            #pragma unroll
            for (int r = 0; r < 4; ++r) {
                const int m = mbase + r;
                const float v = acc[mf][nf][r] + bv;
                const int b = m >> 11, s = m & (SEQ - 1);
                const int hh = n >> 6, dd = n & 63;
                if (z == 0) {
                    const int blk = (dd >> 3) ^ (s & 7), i = dd & 7;
                    q2[((size_t)((b * NUM_HEADS + hh) * SEQ + s)) * 64 +
                       blk * 8 + i] = (_Float16)(v * 0.125f);
                } else if (z == 1) {
                    if (s < ncArr[b]) {          // s IS the compacted index
                        const int blk = (dd >> 3) ^ (s & 7), i = dd & 7;
                        k2[((size_t)((b * NUM_HEADS + hh) * SEQ + s)) * 64 +
                           blk * 8 + i] = (_Float16)v;
                    }
                } else {
                    if (s < ncArr[b]) {
                        const int tile = s >> 6, w = s & 63;
                        const int blk = (w >> 3) ^ (dd & 7), i = w & 7;
                        vt2[((size_t)((b * NUM_HEADS + hh) * DK + dd)) * SEQ +
                            tile * 64 + blk * 8 + i] = (_Float16)v;
                    }
                }
            }
        }
    }
}

// ---------------------------------------------------------------------------
// Output-projection fp16 GEMM (r16-proven): K=1024, fp32 out -> d_out.
// ---------------------------------------------------------------------------
__global__ __launch_bounds__(256) void mfma_gemm_o_kernel(
    const _Float16* __restrict__ A2, const _Float16* __restrict__ W2,
    const float* __restrict__ bias, float* __restrict__ Cf)
{
    constexpr int KS = 1024;
    __shared__ f16x8 Asl[3][1024];
    __shared__ f16x8 Bsl[3][512];

    const int bm = blockIdx.x * 128, bn = blockIdx.y * 64;
    const int tid = threadIdx.x;
    const int wv = tid >> 6, ln = tid & 63;
    const int wm = wv >> 1, wn = wv & 1;
    const int x = ln & 15, y = ln >> 4;

    f32x4 acc[4][2] = {};

    const _Float16* Ab = A2 + (size_t)bm * KS;
    const _Float16* Bb = W2 + (size_t)bn * KS;
    const int srow = ln >> 3;
    const int scol = (ln & 7) * 8;

    auto stage = [&](int bufi, int kt) {
        #pragma unroll
        for (int c = 0; c < 4; ++c) {
            const int rowb = wv * 32 + c * 8;
            gl_lds16(Ab + (size_t)(rowb + srow) * KS + kt * 64 + scol,
                     &Asl[bufi][rowb << 3]);
        }
        #pragma unroll
        for (int c = 0; c < 2; ++c) {
            const int rowb = wv * 16 + c * 8;
            gl_lds16(Bb + (size_t)(rowb + srow) * KS + kt * 64 + scol,
                     &Bsl[bufi][rowb << 3]);
        }
    };

    stage(0, 0);
    stage(1, 1);

    int buf = 0, sbuf = 2;
    for (int kt = 0; kt < 16; ++kt) {
        if (kt < 15) asm volatile("s_waitcnt vmcnt(6)" ::: "memory");
        else         asm volatile("s_waitcnt vmcnt(0)" ::: "memory");
        __builtin_amdgcn_s_barrier();
        if (kt + 2 < 16) stage(sbuf, kt + 2);
        #pragma unroll
        for (int half = 0; half < 2; ++half) {
            f16x8 af[4], bfr[2];
            #pragma unroll
            for (int mf = 0; mf < 4; ++mf) {
                const int r = wm * 64 + mf * 16 + x;
                af[mf] = Asl[buf][(r << 3) | ((half * 4 + y) ^ (r & 7))];
            }
            #pragma unroll
            for (int nf = 0; nf < 2; ++nf) {
                const int r = wn * 32 + nf * 16 + x;
                bfr[nf] = Bsl[buf][(r << 3) | ((half * 4 + y) ^ (r & 7))];
            }
            #pragma unroll
            for (int mf = 0; mf < 4; ++mf)
                #pragma unroll
                for (int nf = 0; nf < 2; ++nf)
                    acc[mf][nf] = __builtin_amdgcn_mfma_f32_16x16x32_f16(
                        af[mf], bfr[nf], acc[mf][nf], 0, 0, 0);
        }
        buf  = (buf  == 2) ? 0 : buf  + 1;
        sbuf = (sbuf == 2) ? 0 : sbuf + 1;
    }

    #pragma unroll
    for (int nf = 0; nf < 2; ++nf) {
        const int n = bn + wn * 32 + nf * 16 + x;
        const float bv = bias[n];
        #pragma unroll
        for (int mf = 0; mf < 4; ++mf) {
            const int mbase = bm + wm * 64 + mf * 16 + y * 4;
            #pragma unroll
            for (int r = 0; r < 4; ++r) {
                const int m = mbase + r;
                Cf[(size_t)m * D_MODEL + n] = acc[mf][nf][r] + bv;
            }
        }
    }
}

// ---------------------------------------------------------------------------
// All-fp16 MFMA flash attention over COMPACTED keys.
// r19: __launch_bounds__(256,4) — 4 x 40960 B = 160 KiB exactly -> 4
// blocks/CU (VGPR 52, no spill risk); EXACT defer-rescale (skip e1 path
// when no lane's max grew — bit-identical since e1 == 1). Double-buffered
// staging + counted vmcnt + setprio (r18-proven).
// ---------------------------------------------------------------------------
__global__ __launch_bounds__(256, 4) void attn_mfma_kernel(
    const _Float16* __restrict__ Q2, const _Float16* __restrict__ K2,
    const _Float16* __restrict__ VT2, const int* __restrict__ ncArr,
    _Float16* __restrict__ ACT)
{
    __shared__ __align__(16) _Float16 SM[20480];   // 40 KB
    // buf0: Ks@0 VTs@4096 | buf1: Ks@8192 VTs@12288 | Pw@16384 (4x1024)

    const int tid = threadIdx.x;
    const int wave = tid >> 6, lane = tid & 63;
    const int lo4 = lane & 15, hi4 = lane >> 4;
    _Float16* Pw = SM + 16384 + wave * 1024;

    const int orig = blockIdx.x;
    const int swz = (orig & 7) * 128 + (orig >> 3);  // 1024%8==0: bijective
    const int bh = swz >> 5, qblk = swz & 31;
    const int b = bh >> 4, h = bh & 15;

    const _Float16* Kb = K2 + (size_t)bh * SEQ * 64;
    const _Float16* Vb = VT2 + (size_t)bh * DK * SEQ;

    const int ncb = ncArr[b];
    const int ntiles = (ncb + 63) >> 6;

    // Q fragments (0.125-scaled fp16, XOR-swizzled by s&7)
    const int qr = qblk * 64 + wave * 16 + lo4;
    const _Float16* Q2row = Q2 + (size_t)(bh * SEQ + qr) * 64;
    f16x8 qf[2];
    #pragma unroll
    for (int c = 0; c < 2; ++c)
        qf[c] = *(const f16x8*)&Q2row[(((c * 4 + hi4) ^ (qr & 7)) * 8)];

    // 4 loads/thread per tile: Ks (512 x16B) | VTs (512 x16B)
    auto stage_kv = [&](int base, int k0) {
        #pragma unroll
        for (int j = 0; j < 4; ++j) {
            const int g = j * 256 + wave * 64;   // wave-uniform dest base
            const int gi = g + lane;
            const _Float16* src;
            if (gi < 512) {
                src = Kb + (size_t)(k0 + (gi >> 3)) * 64 + (gi & 7) * 8;
            } else {
                const int g2 = gi - 512;
                src = Vb + (size_t)(g2 >> 3) * SEQ + k0 + (g2 & 7) * 8;
            }
            gl_lds16(src, SM + base + (size_t)g * 8);
        }
    };

    f32x4 ctx[4] = {};   // ctx^T frags: row d = dt*16+hi4*4+r, col q = lo4
    float m = -INFINITY, l = 0.f;

    stage_kv(0, 0);
    for (int t = 0; t < ntiles; ++t) {
        if (t + 1 < ntiles) {
            stage_kv(((t + 1) & 1) * 8192, (t + 1) * 64);  // prefetch next
            asm volatile("s_waitcnt vmcnt(4)" ::: "memory"); // retire tile t
        } else {
            asm volatile("s_waitcnt vmcnt(0)" ::: "memory");
        }
        __builtin_amdgcn_s_barrier();        // tile t visible to all waves

        const _Float16* Ks = SM + (t & 1) * 8192;
        const _Float16* VTs = Ks + 4096;
        const int k0 = t * 64;

        // S^T = K . Q^T : rows = key, cols = q (single fp16 term)
        f32x4 sc[4];
        __builtin_amdgcn_s_setprio(1);
        #pragma unroll
        for (int kt = 0; kt < 4; ++kt) {
            f32x4 s = {0.f, 0.f, 0.f, 0.f};
            const int row = kt * 16 + lo4;
            const int rx = row & 7;
            #pragma unroll
            for (int c = 0; c < 2; ++c) {
                const f16x8 kf = *(f16x8*)&Ks[row * 64 + (((c * 4 + hi4) ^ rx) * 8)];
                s = __builtin_amdgcn_mfma_f32_16x16x32_f16(kf, qf[c], s, 0, 0, 0);
            }
            sc[kt] = s;
        }
        __builtin_amdgcn_s_setprio(0);

        // row-max; tail tile masks invalid keys (kidx >= ncb) to -1e30
        float cmax = -1e30f;
        if (k0 + 64 <= ncb) {
            #pragma unroll
            for (int kt = 0; kt < 4; ++kt)
                #pragma unroll
                for (int r = 0; r < 4; ++r) cmax = fmaxf(cmax, sc[kt][r]);
        } else {
            #pragma unroll
            for (int kt = 0; kt < 4; ++kt)
                #pragma unroll
                for (int r = 0; r < 4; ++r) {
                    const int kidx = k0 + kt * 16 + hi4 * 4 + r;
                    const float sv = (kidx < ncb) ? sc[kt][r] : -1e30f;
                    sc[kt][r] = sv;
                    cmax = fmaxf(cmax, sv);
                }
        }
        cmax = fmaxf(cmax, __shfl_xor(cmax, 16));
        cmax = fmaxf(cmax, __shfl_xor(cmax, 32));

        // EXACT defer: if no lane's max grew, e1 == 1 -> skip rescale work
        const bool grow = __any(cmax > m);   // wave-uniform branch
        const float mold = m;
        const float mnew = grow ? fmaxf(m, cmax) : m;
        m = mnew;

        float ps = 0.f;
        #pragma unroll
        for (int kt = 0; kt < 4; ++kt) {
            const float pv0 = __expf(sc[kt][0] - mnew);  // -1e30 -> exp = 0
            const float pv1 = __expf(sc[kt][1] - mnew);
            const float pv2 = __expf(sc[kt][2] - mnew);
            const float pv3 = __expf(sc[kt][3] - mnew);
            ps += (pv0 + pv1) + (pv2 + pv3);
            union { _Float16 hh[2]; unsigned u; } pk0, pk1;   // fp16 RNE pack
            pk0.hh[0] = (_Float16)pv0; pk0.hh[1] = (_Float16)pv1;
            pk1.hh[0] = (_Float16)pv2; pk1.hh[1] = (_Float16)pv3;
            const int blk16 = (kt * 2 + (hi4 >> 1)) ^ (lo4 & 7);
            unsigned* dst = (unsigned*)&Pw[lo4 * 64 + blk16 * 8 + (hi4 & 1) * 4];
            dst[0] = pk0.u; dst[1] = pk1.u;
        }
        ps += __shfl_xor(ps, 16);
        ps += __shfl_xor(ps, 32);

        if (grow) {                          // e1==1 exactly when !grow
            const float e1 = __expf(mold - mnew);   // mold=-inf -> 0
            l = l * e1 + ps;
            #pragma unroll
            for (int dt = 0; dt < 4; ++dt)
                #pragma unroll
                for (int r = 0; r < 4; ++r) ctx[dt][r] *= e1;
        } else {
            l += ps;
        }

        // ctx^T += V^T . P^T  (same-wave LDS RAW: compiler orders via lgkmcnt)
        __builtin_amdgcn_s_setprio(1);
        #pragma unroll
        for (int c = 0; c < 2; ++c) {
            const f16x8 pf = *(f16x8*)&Pw[lo4 * 64 + (((c * 4 + hi4) ^ (lo4 & 7)) * 8)];
            #pragma unroll
            for (int dt = 0; dt < 4; ++dt) {
                const int row = dt * 16 + lo4;
                const f16x8 vf =
                    *(f16x8*)&VTs[row * 64 + (((c * 4 + hi4) ^ (row & 7)) * 8)];
                ctx[dt] = __builtin_amdgcn_mfma_f32_16x16x32_f16(vf, pf, ctx[dt], 0, 0, 0);
            }
        }
        __builtin_amdgcn_s_setprio(0);

        __builtin_amdgcn_s_barrier();        // all waves done reading buf t
    }

    // epilogue: normalize, LDS transpose (stride 68, conflict-free),
    // fused fp16 swizzled activation write
    __syncthreads();
    const float inv = (l > 0.f) ? (1.f / l) : 0.f;   // l==0: fully masked -> 0
    float* OutL = (float*)SM;                        // [64 q][68] fp32
    #pragma unroll
    for (int dt = 0; dt < 4; ++dt)
        #pragma unroll
        for (int r = 0; r < 4; ++r)
            OutL[(wave * 16 + lo4) * 68 + dt * 16 + hi4 * 4 + r] = ctx[dt][r] * inv;
    __syncthreads();
    {
        const int row = tid >> 2, cb = (tid & 3) * 16;
        const int mrow = b * SEQ + qblk * 64 + row;      // global act row
        _Float16* arow = ACT + (size_t)mrow * 1024;
        #pragma unroll
        for (int u = 0; u < 2; ++u) {
            const int lb = (cb >> 3) + u;                // logical 8-col block
            const int ss = lb ^ (mrow & 7);              // stored (swizzled)
            f16x8 hv;
            #pragma unroll
            for (int i = 0; i < 8; ++i)
                hv[i] = (_Float16)OutL[row * 68 + cb + u * 8 + i];
            *(f16x8*)&arow[h * 64 + ss * 8] = hv;
        }
    }
}

// ---------------------------------------------------------------------------
// fp32 fallback path (only if ws too small)
// ---------------------------------------------------------------------------
template <int SPLIT>
__global__ __launch_bounds__(256) void gemm_bias_kernel(
    const float* __restrict__ A, const float* __restrict__ W,
    const float* __restrict__ bias, float* __restrict__ C,
    int M, int N, int K)
{
    constexpr int TILE = 64, KT = 16;
    __shared__ float As[KT][TILE + 4];
    __shared__ float Ws[KT][TILE + 4];
    const int tid = threadIdx.x;
    const int tx = tid & 15, ty = tid >> 4;
    const int bm = blockIdx.x * TILE, bn = blockIdx.y * TILE;
    const int lrow = tid >> 2, lk4 = (tid & 3) << 2;
    float acc[4][4] = {{0.f}};
    for (int k0 = 0; k0 < K; k0 += KT) {
        const float4 a4 = *(const float4*)&A[(size_t)(bm + lrow) * K + k0 + lk4];
        const float4 w4 = *(const float4*)&W[(size_t)(bn + lrow) * K + k0 + lk4];
        __syncthreads();
        As[lk4 + 0][lrow] = a4.x; As[lk4 + 1][lrow] = a4.y;
        As[lk4 + 2][lrow] = a4.z; As[lk4 + 3][lrow] = a4.w;
        Ws[lk4 + 0][lrow] = w4.x; Ws[lk4 + 1][lrow] = w4.y;
        Ws[lk4 + 2][lrow] = w4.z; Ws[lk4 + 3][lrow] = w4.w;
        __syncthreads();
        #pragma unroll
        for (int kk = 0; kk < KT; ++kk) {
            const float4 av = *(const float4*)&As[kk][ty << 2];
            const float4 wv = *(const float4*)&Ws[kk][tx << 2];
            acc[0][0] += av.x * wv.x; acc[0][1] += av.x * wv.y; acc[0][2] += av.x * wv.z; acc[0][3] += av.x * wv.w;
            acc[1][0] += av.y * wv.x; acc[1][1] += av.y * wv.y; acc[1][2] += av.y * wv.z; acc[1][3] += av.y * wv.w;
            acc[2][0] += av.z * wv.x; acc[2][1] += av.z * wv.y; acc[2][2] += av.z * wv.z; acc[2][3] += av.z * wv.w;
            acc[3][0] += av.w * wv.x; acc[3][1] += av.w * wv.y; acc[3][2] += av.w * wv.z; acc[3][3] += av.w * wv.w;
        }
    }
    const float4 bb = *(const float4*)&bias[bn + (tx << 2)];
    #pragma unroll
    for (int i = 0; i < 4; ++i) {
        const int row = bm + (ty << 2) + i;
        float4 o;
        o.x = acc[i][0] + bb.x; o.y = acc[i][1] + bb.y;
        o.z = acc[i][2] + bb.z; o.w = acc[i][3] + bb.w;
        if (SPLIT) {
            const int b = row >> 11, s = row & (SEQ - 1), hh = bn >> 6;
            *(float4*)&C[((size_t)((b * NUM_HEADS + hh) * SEQ + s)) * DK + (tx << 2)] = o;
        } else {
            *(float4*)&C[(size_t)row * N + bn + (tx << 2)] = o;
        }
    }
}

__global__ __launch_bounds__(256, 2) void attn_fp32_kernel(
    const float* __restrict__ Q, const float* __restrict__ K,
    const float* __restrict__ V, const int* __restrict__ mask,
    float* __restrict__ OUT)
{
    const int qb = blockIdx.x, h = blockIdx.y, b = blockIdx.z;
    const int wave = threadIdx.x >> 6, lane = threadIdx.x & 63;
    const int tid = threadIdx.x;
    const int bh = b * NUM_HEADS + h;
    const float* Qb = Q + (size_t)bh * SEQ * DK;
    const float* Kb = K + (size_t)bh * SEQ * DK;
    const float* Vb = V + (size_t)bh * SEQ * DK;
    const int* mb = mask + b * SEQ;
    __shared__ float Ks[64][68];
    __shared__ float Vs[64][68];
    const int row = qb * 256 + wave * 64 + lane;
    float q[DK], ctx[DK];
    #pragma unroll
    for (int d4 = 0; d4 < 16; ++d4) {
        const float4 t = *(const float4*)&Qb[(size_t)row * DK + 4 * d4];
        q[4*d4] = t.x; q[4*d4+1] = t.y; q[4*d4+2] = t.z; q[4*d4+3] = t.w;
        ctx[4*d4] = 0.f; ctx[4*d4+1] = 0.f; ctx[4*d4+2] = 0.f; ctx[4*d4+3] = 0.f;
    }
    float m = -INFINITY, l = 0.f;
    for (int t = 0; t < SEQ / 64; ++t) {
        const int k0 = t * 64;
        const float* Kt = Kb + (size_t)k0 * DK;
        const float* Vt = Vb + (size_t)k0 * DK;
        __syncthreads();
        #pragma unroll
        for (int i = 0; i < 4; ++i) {
            const int f4 = i * 256 + tid;
            const int r = f4 >> 4, c = (f4 & 15) << 2;
            *(float4*)&Ks[r][c] = *(const float4*)&Kt[4 * f4];
            *(float4*)&Vs[r][c] = *(const float4*)&Vt[4 * f4];
        }
        __syncthreads();
        const unsigned long long mbits = __ballot(mb[k0 + lane] != 0);
        if (mbits == 0ULL) continue;
        for (int c0 = 0; c0 < 64; c0 += 16) {
            const unsigned bits = (unsigned)((mbits >> c0) & 0xFFFFULL);
            if (!bits) continue;
            float sc[16];
            #pragma unroll
            for (int j = 0; j < 16; ++j) {
                if (!((bits >> j) & 1u)) { sc[j] = -INFINITY; continue; }
                float a0 = 0.f, a1 = 0.f, a2 = 0.f, a3 = 0.f;
                #pragma unroll
                for (int d4 = 0; d4 < 16; ++d4) {
                    const float4 kv = *(const float4*)&Ks[c0 + j][4 * d4];
                    a0 += q[4*d4] * kv.x; a1 += q[4*d4+1] * kv.y;
                    a2 += q[4*d4+2] * kv.z; a3 += q[4*d4+3] * kv.w;
                }
                sc[j] = ((a0 + a1) + (a2 + a3)) * 0.125f;
            }
            float cmax = sc[0];
            #pragma unroll
            for (int j = 1; j < 16; ++j) cmax = fmaxf(cmax, sc[j]);
            if (cmax > m) {
                const float scale = __expf(m - cmax);
                l *= scale;
                #pragma unroll
                for (int d = 0; d < DK; ++d) ctx[d] *= scale;
                m = cmax;
            }
            #pragma unroll
            for (int j = 0; j < 16; ++j) {
                if (!((bits >> j) & 1u)) continue;
                const float p = __expf(sc[j] - m);
                l += p;
                #pragma unroll
                for (int d4 = 0; d4 < 16; ++d4) {
                    const float4 vv = *(const float4*)&Vs[c0 + j][4 * d4];
                    ctx[4*d4] += p * vv.x; ctx[4*d4+1] += p * vv.y;
                    ctx[4*d4+2] += p * vv.z; ctx[4*d4+3] += p * vv.w;
                }
            }
        }
    }
    const float inv = (l > 0.f) ? (1.f / l) : 0.f;
    float* dst = OUT + ((size_t)(b * SEQ + row)) * D_MODEL + h * DK;
    #pragma unroll
    for (int d4 = 0; d4 < 16; ++d4) {
        float4 o;
        o.x = ctx[4*d4] * inv; o.y = ctx[4*d4+1] * inv;
        o.z = ctx[4*d4+2] * inv; o.w = ctx[4*d4+3] * inv;
        *(float4*)&dst[4 * d4] = o;
    }
}

// ---------------------------------------------------------------------------
extern "C" void kernel_launch(void* const* d_in, const int* in_sizes, int n_in,
                              void* d_out, int out_size, void* d_ws, size_t ws_size,
                              hipStream_t stream)
{
    const float* query = (const float*)d_in[0];
    const float* key_  = (const float*)d_in[1];
    const float* value = (const float*)d_in[2];
    const int*   mask  = (const int*)d_in[3];
    const float* Wq = (const float*)d_in[4];
    const float* bq = (const float*)d_in[5];
    const float* Wk = (const float*)d_in[6];
    const float* bk = (const float*)d_in[7];
    const float* Wv = (const float*)d_in[8];
    const float* bv = (const float*)d_in[9];
    const float* Wo = (const float*)d_in[10];
    const float* bo = (const float*)d_in[11];
    float* out = (float*)d_out;

    const int M = BATCH * SEQ;                            // 4096
    const size_t ACT_B = (size_t)M * 1024 * 2;            // 8.39 MB (fp16)
    const size_t W_B   = (size_t)D_MODEL * 1024 * 2;      // 2.10 MB (fp16)
    const size_t K2_B  = (size_t)32 * SEQ * 64 * 2;       // 8.39 MB
    const size_t VT2_B = (size_t)32 * DK * SEQ * 2;       // 8.39 MB
    const size_t Q2_B  = K2_B;                            // 8.39 MB
    const size_t POS_B = (size_t)BATCH * SEQ * 4 + 256;

    char* base = (char*)d_ws;
    _Float16* actQh = (_Float16*)(base);
    _Float16* actKh = (_Float16*)(base + ACT_B);
    _Float16* actVh = (_Float16*)(base + 2 * ACT_B);
    _Float16* actO  = (_Float16*)(base + 3 * ACT_B);
    _Float16* w2qh  = (_Float16*)(base + 4 * ACT_B);
    _Float16* w2kh  = (_Float16*)((char*)w2qh + W_B);
    _Float16* w2vh  = (_Float16*)((char*)w2kh + W_B);
    _Float16* w2oh  = (_Float16*)((char*)w2vh + W_B);
    _Float16* k2    = (_Float16*)((char*)w2oh + W_B);
    _Float16* vt2   = (_Float16*)((char*)k2 + K2_B);
    _Float16* q2    = (_Float16*)((char*)vt2 + VT2_B);
    int* posArr = (int*)((char*)q2 + Q2_B);
    int* ncArr  = posArr + BATCH * SEQ;
    const size_t need = 4 * ACT_B + 4 * W_B + K2_B + VT2_B + Q2_B + POS_B; // ~67 MB

    if (ws_size >= need) {
        mask_scan_kernel<<<BATCH, 256, 0, stream>>>(mask, posArr, ncArr);

        // ALL 7 conversions in one dispatch (weights + inputs)
        conv_all_kernel<<<dim3(2048, 7), 256, 0, stream>>>(
            Wq, Wk, Wv, Wo, query, key_, value,
            w2qh, w2kh, w2vh, w2oh, actQh, actKh, actVh, mask, posArr);

        // QKV projections in one dispatch (z-major: Q then K then V)
        mfma_gemm_qkv_kernel<<<dim3(M / 128, D_MODEL / 64, 3), 256, 0, stream>>>(
            actQh, actKh, actVh, w2qh, w2kh, w2vh, bq, bk, bv,
            q2, k2, vt2, ncArr);

        attn_mfma_kernel<<<1024, 256, 0, stream>>>(q2, k2, vt2, ncArr, actO);

        mfma_gemm_o_kernel<<<dim3(M / 128, D_MODEL / 64), 256, 0, stream>>>(
            actO, w2oh, bo, out);
    } else {
        float* q_ws = (float*)(base);
        float* k_ws = (float*)(base + (size_t)M * D_MODEL * 4);
        float* v_ws = (float*)(base + 2 * (size_t)M * D_MODEL * 4);
        float* c_ws = (float*)(base + 3 * (size_t)M * D_MODEL * 4);
        dim3 ggrid(M / 64, D_MODEL / 64);
        gemm_bias_kernel<1><<<ggrid, 256, 0, stream>>>(query, Wq, bq, q_ws, M, D_MODEL, D_MODEL);
        gemm_bias_kernel<1><<<ggrid, 256, 0, stream>>>(key_,  Wk, bk, k_ws, M, D_MODEL, D_MODEL);
        gemm_bias_kernel<1><<<ggrid, 256, 0, stream>>>(value, Wv, bv, v_ws, M, D_MODEL, D_MODEL);
        dim3 agrid(SEQ / 256, NUM_HEADS, BATCH);
        attn_fp32_kernel<<<agrid, 256, 0, stream>>>(q_ws, k_ws, v_ws, mask, c_ws);
        gemm_bias_kernel<0><<<ggrid, 256, 0, stream>>>(c_ws, Wo, bo, out, M, D_MODEL, D_MODEL);
    }
}

// Round 21
// 130.318 us; speedup vs baseline: 2.3546x; 1.0227x over previous
//
#include <hip/hip_runtime.h>
#include <math.h>

#define D_MODEL 1024
#define NUM_HEADS 16
#define DK 64
#define BATCH 2
#define SEQ 2048

using f32x4  = __attribute__((ext_vector_type(4))) float;
using f16x8  = __attribute__((ext_vector_type(8))) _Float16;

__device__ __forceinline__ void gl_lds16(const void* g, void* l) {
    __builtin_amdgcn_global_load_lds(
        (const __attribute__((address_space(1))) void*)g,
        (__attribute__((address_space(3))) void*)l, 16, 0, 0);
}

// ---------------------------------------------------------------------------
// Per-batch prefix scan of mask: pos[b][s] = #valid keys before s, nc[b]=count
// ---------------------------------------------------------------------------
__global__ __launch_bounds__(256) void mask_scan_kernel(
    const int* __restrict__ mask, int* __restrict__ pos, int* __restrict__ nc)
{
    const int b = blockIdx.x;
    const int tid = threadIdx.x;
    __shared__ int sums[256];
    int v[8]; int cnt = 0;
    const int base = b * SEQ + tid * 8;
    #pragma unroll
    for (int e = 0; e < 8; ++e) { v[e] = (mask[base + e] != 0) ? 1 : 0; cnt += v[e]; }
    sums[tid] = cnt;
    __syncthreads();
    for (int off = 1; off < 256; off <<= 1) {
        int t = (tid >= off) ? sums[tid - off] : 0;
        __syncthreads();
        sums[tid] += t;
        __syncthreads();
    }
    int run = sums[tid] - cnt;           // exclusive prefix
    #pragma unroll
    for (int e = 0; e < 8; ++e) { pos[base + e] = run; run += v[e]; }
    if (tid == 255) nc[b] = sums[255];
}

// ---------------------------------------------------------------------------
// ALL conversions in one dispatch. fp32 [rows][1024] -> fp16 [rows][1024],
// row-XOR swizzle baked in (stored 16B block ss = logical ss ^ (drow&7)).
// y=0..3: weights (rows=1024); y=4: query; y=5/6: key_/value row-compacted.
// grid = (2048, 7); weight streams early-exit past 512 blocks.
// ---------------------------------------------------------------------------
__global__ __launch_bounds__(256) void conv_all_kernel(
    const float* Wq, const float* Wk, const float* Wv, const float* Wo,
    const float* query, const float* key_, const float* value,
    _Float16* w2q, _Float16* w2k, _Float16* w2v, _Float16* w2o,
    _Float16* aq, _Float16* ak, _Float16* av,
    const int* __restrict__ mask, const int* __restrict__ pos)
{
    const int y = blockIdx.y;
    const float* src; _Float16* dst; int rows; bool compact = false;
    switch (y) {
        case 0: src = Wq;    dst = w2q; rows = 1024; break;
        case 1: src = Wk;    dst = w2k; rows = 1024; break;
        case 2: src = Wv;    dst = w2v; rows = 1024; break;
        case 3: src = Wo;    dst = w2o; rows = 1024; break;
        case 4: src = query; dst = aq;  rows = 4096; break;
        case 5: src = key_;  dst = ak;  rows = 4096; compact = true; break;
        default: src = value; dst = av; rows = 4096; compact = true; break;
    }
    const int id = blockIdx.x * 256 + threadIdx.x;
    if (id >= rows * 128) return;
    const int row = id >> 7;
    int drow = row;
    if (compact) {
        if (!mask[row]) return;
        drow = (row >> 11) * SEQ + pos[row];
    }
    const int s  = id & 127;             // 16B block (8 f16) in [0,128)
    const int g  = s >> 3, ss = s & 7;
    const int lb = ss ^ (drow & 7);

    const float* p = src + (size_t)row * 1024 + g * 64 + lb * 8;
    const float4 a = *(const float4*)p;
    const float4 bq = *(const float4*)(p + 4);
    f16x8 o;
    o[0] = (_Float16)a.x;  o[1] = (_Float16)a.y;
    o[2] = (_Float16)a.z;  o[3] = (_Float16)a.w;
    o[4] = (_Float16)bq.x; o[5] = (_Float16)bq.y;
    o[6] = (_Float16)bq.z; o[7] = (_Float16)bq.w;
    *(f16x8*)&dst[(size_t)drow * 1024 + s * 8] = o;
}

// ---------------------------------------------------------------------------
// fp16 MFMA GEMM: K=1024, 16 k-steps, 128x64 tile, 3-buffer LDS + counted
// vmcnt + raw s_barrier (r13/r16/r17-proven pipeline). SEPARATE dispatches
// per MODE (r20 z-merge cost ~10us: heterogeneous blocks straggle).
// MODE epilogue:
//   0: fp32 [M][1024] -> d_out        (output projection)
//   1: Q2  fp16 [bh][s][64] = 0.125*v, block-XOR by s&7
//   2: K2  fp16 [bh][p][64] swz      (rows pre-COMPACTED; store if p<nc)
//   3: VT2 fp16 [bh][d][2048] key-block swz (pre-COMPACTED; store if p<nc)
// MODE 2/3: whole tile early-exits when its 128-row stripe is >= nc[b].
// ---------------------------------------------------------------------------
template <int MODE>
__global__ __launch_bounds__(256) void mfma_gemm_f16_kernel(
    const _Float16* __restrict__ A2, const _Float16* __restrict__ W2,
    const float* __restrict__ bias, float* __restrict__ Cf,
    _Float16* __restrict__ Ch, const int* __restrict__ ncArr)
{
    constexpr int KS = 1024;
    __shared__ f16x8 Asl[3][1024];
    __shared__ f16x8 Bsl[3][512];

    const int bm = blockIdx.x * 128, bn = blockIdx.y * 64;
    if (MODE == 2 || MODE == 3) {
        if ((bm & (SEQ - 1)) >= ncArr[bm >> 11]) return;   // uniform exit
    }

    const int tid = threadIdx.x;
    const int wv = tid >> 6, ln = tid & 63;
    const int wm = wv >> 1, wn = wv & 1;
    const int x = ln & 15, y = ln >> 4;

    f32x4 acc[4][2] = {};

    const _Float16* Ab = A2 + (size_t)bm * KS;
    const _Float16* Bb = W2 + (size_t)bn * KS;
    const int srow = ln >> 3;
    const int scol = (ln & 7) * 8;

    auto stage = [&](int bufi, int kt) {
        #pragma unroll
        for (int c = 0; c < 4; ++c) {
            const int rowb = wv * 32 + c * 8;
            gl_lds16(Ab + (size_t)(rowb + srow) * KS + kt * 64 + scol,
                     &Asl[bufi][rowb << 3]);
        }
        #pragma unroll
        for (int c = 0; c < 2; ++c) {
            const int rowb = wv * 16 + c * 8;
            gl_lds16(Bb + (size_t)(rowb + srow) * KS + kt * 64 + scol,
                     &Bsl[bufi][rowb << 3]);
        }
    };

    stage(0, 0);
    stage(1, 1);

    int buf = 0, sbuf = 2;
    for (int kt = 0; kt < 16; ++kt) {
        if (kt < 15) asm volatile("s_waitcnt vmcnt(6)" ::: "memory");
        else         asm volatile("s_waitcnt vmcnt(0)" ::: "memory");
        __builtin_amdgcn_s_barrier();
        if (kt + 2 < 16) stage(sbuf, kt + 2);
        #pragma unroll
        for (int half = 0; half < 2; ++half) {
            f16x8 af[4], bfr[2];
            #pragma unroll
            for (int mf = 0; mf < 4; ++mf) {
                const int r = wm * 64 + mf * 16 + x;
                af[mf] = Asl[buf][(r << 3) | ((half * 4 + y) ^ (r & 7))];
            }
            #pragma unroll
            for (int nf = 0; nf < 2; ++nf) {
                const int r = wn * 32 + nf * 16 + x;
                bfr[nf] = Bsl[buf][(r << 3) | ((half * 4 + y) ^ (r & 7))];
            }
            #pragma unroll
            for (int mf = 0; mf < 4; ++mf)
                #pragma unroll
                for (int nf = 0; nf < 2; ++nf)
                    acc[mf][nf] = __builtin_amdgcn_mfma_f32_16x16x32_f16(
                        af[mf], bfr[nf], acc[mf][nf], 0, 0, 0);
        }
        buf  = (buf  == 2) ? 0 : buf  + 1;
        sbuf = (sbuf == 2) ? 0 : sbuf + 1;
    }

    // epilogue (C/D: col=lane&15, row=(lane>>4)*4+r)  [m89-verified]
    #pragma unroll
    for (int nf = 0; nf < 2; ++nf) {
        const int n = bn + wn * 32 + nf * 16 + x;
        const float bv = bias[n];
        #pragma unroll
        for (int mf = 0; mf < 4; ++mf) {
            const int mbase = bm + wm * 64 + mf * 16 + y * 4;
            #pragma unroll
            for (int r = 0; r < 4; ++r) {
                const int m = mbase + r;
                const float v = acc[mf][nf][r] + bv;
                const int b = m >> 11, s = m & (SEQ - 1);
                const int hh = n >> 6, dd = n & 63;
                if (MODE == 0) {
                    Cf[(size_t)m * D_MODEL + n] = v;
                } else if (MODE == 1) {
                    const int blk = (dd >> 3) ^ (s & 7), i = dd & 7;
                    Ch[((size_t)((b * NUM_HEADS + hh) * SEQ + s)) * 64 +
                       blk * 8 + i] = (_Float16)(v * 0.125f);
                } else if (MODE == 2) {
                    if (s < ncArr[b]) {          // s IS the compacted index
                        const int blk = (dd >> 3) ^ (s & 7), i = dd & 7;
                        Ch[((size_t)((b * NUM_HEADS + hh) * SEQ + s)) * 64 +
                           blk * 8 + i] = (_Float16)v;
                    }
                } else {
                    if (s < ncArr[b]) {
                        const int tile = s >> 6, w = s & 63;
                        const int blk = (w >> 3) ^ (dd & 7), i = w & 7;
                        Ch[((size_t)((b * NUM_HEADS + hh) * DK + dd)) * SEQ +
                           tile * 64 + blk * 8 + i] = (_Float16)v;
                    }
                }
            }
        }
    }
}

// ---------------------------------------------------------------------------
// All-fp16 MFMA flash attention over COMPACTED keys (r19/r20-proven:
// 4 blocks/CU via __launch_bounds__(256,4) with 40960 B LDS; exact
// defer-rescale; double-buffered staging + counted vmcnt + setprio).
// ---------------------------------------------------------------------------
__global__ __launch_bounds__(256, 4) void attn_mfma_kernel(
    const _Float16* __restrict__ Q2, const _Float16* __restrict__ K2,
    const _Float16* __restrict__ VT2, const int* __restrict__ ncArr,
    _Float16* __restrict__ ACT)
{
    __shared__ __align__(16) _Float16 SM[20480];   // 40 KB
    // buf0: Ks@0 VTs@4096 | buf1: Ks@8192 VTs@12288 | Pw@16384 (4x1024)

    const int tid = threadIdx.x;
    const int wave = tid >> 6, lane = tid & 63;
    const int lo4 = lane & 15, hi4 = lane >> 4;
    _Float16* Pw = SM + 16384 + wave * 1024;

    const int orig = blockIdx.x;
    const int swz = (orig & 7) * 128 + (orig >> 3);  // 1024%8==0: bijective
    const int bh = swz >> 5, qblk = swz & 31;
    const int b = bh >> 4, h = bh & 15;

    const _Float16* Kb = K2 + (size_t)bh * SEQ * 64;
    const _Float16* Vb = VT2 + (size_t)bh * DK * SEQ;

    const int ncb = ncArr[b];
    const int ntiles = (ncb + 63) >> 6;

    // Q fragments (0.125-scaled fp16, XOR-swizzled by s&7)
    const int qr = qblk * 64 + wave * 16 + lo4;
    const _Float16* Q2row = Q2 + (size_t)(bh * SEQ + qr) * 64;
    f16x8 qf[2];
    #pragma unroll
    for (int c = 0; c < 2; ++c)
        qf[c] = *(const f16x8*)&Q2row[(((c * 4 + hi4) ^ (qr & 7)) * 8)];

    // 4 loads/thread per tile: Ks (512 x16B) | VTs (512 x16B)
    auto stage_kv = [&](int base, int k0) {
        #pragma unroll
        for (int j = 0; j < 4; ++j) {
            const int g = j * 256 + wave * 64;   // wave-uniform dest base
            const int gi = g + lane;
            const _Float16* src;
            if (gi < 512) {
                src = Kb + (size_t)(k0 + (gi >> 3)) * 64 + (gi & 7) * 8;
            } else {
                const int g2 = gi - 512;
                src = Vb + (size_t)(g2 >> 3) * SEQ + k0 + (g2 & 7) * 8;
            }
            gl_lds16(src, SM + base + (size_t)g * 8);
        }
    };

    f32x4 ctx[4] = {};   // ctx^T frags: row d = dt*16+hi4*4+r, col q = lo4
    float m = -INFINITY, l = 0.f;

    stage_kv(0, 0);
    for (int t = 0; t < ntiles; ++t) {
        if (t + 1 < ntiles) {
            stage_kv(((t + 1) & 1) * 8192, (t + 1) * 64);  // prefetch next
            asm volatile("s_waitcnt vmcnt(4)" ::: "memory"); // retire tile t
        } else {
            asm volatile("s_waitcnt vmcnt(0)" ::: "memory");
        }
        __builtin_amdgcn_s_barrier();        // tile t visible to all waves

        const _Float16* Ks = SM + (t & 1) * 8192;
        const _Float16* VTs = Ks + 4096;
        const int k0 = t * 64;

        // S^T = K . Q^T : rows = key, cols = q (single fp16 term)
        f32x4 sc[4];
        __builtin_amdgcn_s_setprio(1);
        #pragma unroll
        for (int kt = 0; kt < 4; ++kt) {
            f32x4 s = {0.f, 0.f, 0.f, 0.f};
            const int row = kt * 16 + lo4;
            const int rx = row & 7;
            #pragma unroll
            for (int c = 0; c < 2; ++c) {
                const f16x8 kf = *(f16x8*)&Ks[row * 64 + (((c * 4 + hi4) ^ rx) * 8)];
                s = __builtin_amdgcn_mfma_f32_16x16x32_f16(kf, qf[c], s, 0, 0, 0);
            }
            sc[kt] = s;
        }
        __builtin_amdgcn_s_setprio(0);

        // row-max; tail tile masks invalid keys (kidx >= ncb) to -1e30
        float cmax = -1e30f;
        if (k0 + 64 <= ncb) {
            #pragma unroll
            for (int kt = 0; kt < 4; ++kt)
                #pragma unroll
                for (int r = 0; r < 4; ++r) cmax = fmaxf(cmax, sc[kt][r]);
        } else {
            #pragma unroll
            for (int kt = 0; kt < 4; ++kt)
                #pragma unroll
                for (int r = 0; r < 4; ++r) {
                    const int kidx = k0 + kt * 16 + hi4 * 4 + r;
                    const float sv = (kidx < ncb) ? sc[kt][r] : -1e30f;
                    sc[kt][r] = sv;
                    cmax = fmaxf(cmax, sv);
                }
        }
        cmax = fmaxf(cmax, __shfl_xor(cmax, 16));
        cmax = fmaxf(cmax, __shfl_xor(cmax, 32));

        // EXACT defer: if no lane's max grew, e1 == 1 -> skip rescale work
        const bool grow = __any(cmax > m);   // wave-uniform branch
        const float mold = m;
        const float mnew = grow ? fmaxf(m, cmax) : m;
        m = mnew;

        float ps = 0.f;
        #pragma unroll
        for (int kt = 0; kt < 4; ++kt) {
            const float pv0 = __expf(sc[kt][0] - mnew);  // -1e30 -> exp = 0
            const float pv1 = __expf(sc[kt][1] - mnew);
            const float pv2 = __expf(sc[kt][2] - mnew);
            const float pv3 = __expf(sc[kt][3] - mnew);
            ps += (pv0 + pv1) + (pv2 + pv3);
            union { _Float16 hh[2]; unsigned u; } pk0, pk1;   // fp16 RNE pack
            pk0.hh[0] = (_Float16)pv0; pk0.hh[1] = (_Float16)pv1;
            pk1.hh[0] = (_Float16)pv2; pk1.hh[1] = (_Float16)pv3;
            const int blk16 = (kt * 2 + (hi4 >> 1)) ^ (lo4 & 7);
            unsigned* dst = (unsigned*)&Pw[lo4 * 64 + blk16 * 8 + (hi4 & 1) * 4];
            dst[0] = pk0.u; dst[1] = pk1.u;
        }
        ps += __shfl_xor(ps, 16);
        ps += __shfl_xor(ps, 32);

        if (grow) {                          // e1==1 exactly when !grow
            const float e1 = __expf(mold - mnew);   // mold=-inf -> 0
            l = l * e1 + ps;
            #pragma unroll
            for (int dt = 0; dt < 4; ++dt)
                #pragma unroll
                for (int r = 0; r < 4; ++r) ctx[dt][r] *= e1;
        } else {
            l += ps;
        }

        // ctx^T += V^T . P^T  (same-wave LDS RAW: compiler orders via lgkmcnt)
        __builtin_amdgcn_s_setprio(1);
        #pragma unroll
        for (int c = 0; c < 2; ++c) {
            const f16x8 pf = *(f16x8*)&Pw[lo4 * 64 + (((c * 4 + hi4) ^ (lo4 & 7)) * 8)];
            #pragma unroll
            for (int dt = 0; dt < 4; ++dt) {
                const int row = dt * 16 + lo4;
                const f16x8 vf =
                    *(f16x8*)&VTs[row * 64 + (((c * 4 + hi4) ^ (row & 7)) * 8)];
                ctx[dt] = __builtin_amdgcn_mfma_f32_16x16x32_f16(vf, pf, ctx[dt], 0, 0, 0);
            }
        }
        __builtin_amdgcn_s_setprio(0);

        __builtin_amdgcn_s_barrier();        // all waves done reading buf t
    }

    // epilogue: normalize, LDS transpose (stride 68, conflict-free),
    // fused fp16 swizzled activation write
    __syncthreads();
    const float inv = (l > 0.f) ? (1.f / l) : 0.f;   // l==0: fully masked -> 0
    float* OutL = (float*)SM;                        // [64 q][68] fp32
    #pragma unroll
    for (int dt = 0; dt < 4; ++dt)
        #pragma unroll
        for (int r = 0; r < 4; ++r)
            OutL[(wave * 16 + lo4) * 68 + dt * 16 + hi4 * 4 + r] = ctx[dt][r] * inv;
    __syncthreads();
    {
        const int row = tid >> 2, cb = (tid & 3) * 16;
        const int mrow = b * SEQ + qblk * 64 + row;      // global act row
        _Float16* arow = ACT + (size_t)mrow * 1024;
        #pragma unroll
        for (int u = 0; u < 2; ++u) {
            const int lb = (cb >> 3) + u;                // logical 8-col block
            const int ss = lb ^ (mrow & 7);              // stored (swizzled)
            f16x8 hv;
            #pragma unroll
            for (int i = 0; i < 8; ++i)
                hv[i] = (_Float16)OutL[row * 68 + cb + u * 8 + i];
            *(f16x8*)&arow[h * 64 + ss * 8] = hv;
        }
    }
}

// ---------------------------------------------------------------------------
// fp32 fallback path (only if ws too small)
// ---------------------------------------------------------------------------
template <int SPLIT>
__global__ __launch_bounds__(256) void gemm_bias_kernel(
    const float* __restrict__ A, const float* __restrict__ W,
    const float* __restrict__ bias, float* __restrict__ C,
    int M, int N, int K)
{
    constexpr int TILE = 64, KT = 16;
    __shared__ float As[KT][TILE + 4];
    __shared__ float Ws[KT][TILE + 4];
    const int tid = threadIdx.x;
    const int tx = tid & 15, ty = tid >> 4;
    const int bm = blockIdx.x * TILE, bn = blockIdx.y * TILE;
    const int lrow = tid >> 2, lk4 = (tid & 3) << 2;
    float acc[4][4] = {{0.f}};
    for (int k0 = 0; k0 < K; k0 += KT) {
        const float4 a4 = *(const float4*)&A[(size_t)(bm + lrow) * K + k0 + lk4];
        const float4 w4 = *(const float4*)&W[(size_t)(bn + lrow) * K + k0 + lk4];
        __syncthreads();
        As[lk4 + 0][lrow] = a4.x; As[lk4 + 1][lrow] = a4.y;
        As[lk4 + 2][lrow] = a4.z; As[lk4 + 3][lrow] = a4.w;
        Ws[lk4 + 0][lrow] = w4.x; Ws[lk4 + 1][lrow] = w4.y;
        Ws[lk4 + 2][lrow] = w4.z; Ws[lk4 + 3][lrow] = w4.w;
        __syncthreads();
        #pragma unroll
        for (int kk = 0; kk < KT; ++kk) {
            const float4 av = *(const float4*)&As[kk][ty << 2];
            const float4 wv = *(const float4*)&Ws[kk][tx << 2];
            acc[0][0] += av.x * wv.x; acc[0][1] += av.x * wv.y; acc[0][2] += av.x * wv.z; acc[0][3] += av.x * wv.w;
            acc[1][0] += av.y * wv.x; acc[1][1] += av.y * wv.y; acc[1][2] += av.y * wv.z; acc[1][3] += av.y * wv.w;
            acc[2][0] += av.z * wv.x; acc[2][1] += av.z * wv.y; acc[2][2] += av.z * wv.z; acc[2][3] += av.z * wv.w;
            acc[3][0] += av.w * wv.x; acc[3][1] += av.w * wv.y; acc[3][2] += av.w * wv.z; acc[3][3] += av.w * wv.w;
        }
    }
    const float4 bb = *(const float4*)&bias[bn + (tx << 2)];
    #pragma unroll
    for (int i = 0; i < 4; ++i) {
        const int row = bm + (ty << 2) + i;
        float4 o;
        o.x = acc[i][0] + bb.x; o.y = acc[i][1] + bb.y;
        o.z = acc[i][2] + bb.z; o.w = acc[i][3] + bb.w;
        if (SPLIT) {
            const int b = row >> 11, s = row & (SEQ - 1), hh = bn >> 6;
            *(float4*)&C[((size_t)((b * NUM_HEADS + hh) * SEQ + s)) * DK + (tx << 2)] = o;
        } else {
            *(float4*)&C[(size_t)row * N + bn + (tx << 2)] = o;
        }
    }
}

__global__ __launch_bounds__(256, 2) void attn_fp32_kernel(
    const float* __restrict__ Q, const float* __restrict__ K,
    const float* __restrict__ V, const int* __restrict__ mask,
    float* __restrict__ OUT)
{
    const int qb = blockIdx.x, h = blockIdx.y, b = blockIdx.z;
    const int wave = threadIdx.x >> 6, lane = threadIdx.x & 63;
    const int tid = threadIdx.x;
    const int bh = b * NUM_HEADS + h;
    const float* Qb = Q + (size_t)bh * SEQ * DK;
    const float* Kb = K + (size_t)bh * SEQ * DK;
    const float* Vb = V + (size_t)bh * SEQ * DK;
    const int* mb = mask + b * SEQ;
    __shared__ float Ks[64][68];
    __shared__ float Vs[64][68];
    const int row = qb * 256 + wave * 64 + lane;
    float q[DK], ctx[DK];
    #pragma unroll
    for (int d4 = 0; d4 < 16; ++d4) {
        const float4 t = *(const float4*)&Qb[(size_t)row * DK + 4 * d4];
        q[4*d4] = t.x; q[4*d4+1] = t.y; q[4*d4+2] = t.z; q[4*d4+3] = t.w;
        ctx[4*d4] = 0.f; ctx[4*d4+1] = 0.f; ctx[4*d4+2] = 0.f; ctx[4*d4+3] = 0.f;
    }
    float m = -INFINITY, l = 0.f;
    for (int t = 0; t < SEQ / 64; ++t) {
        const int k0 = t * 64;
        const float* Kt = Kb + (size_t)k0 * DK;
        const float* Vt = Vb + (size_t)k0 * DK;
        __syncthreads();
        #pragma unroll
        for (int i = 0; i < 4; ++i) {
            const int f4 = i * 256 + tid;
            const int r = f4 >> 4, c = (f4 & 15) << 2;
            *(float4*)&Ks[r][c] = *(const float4*)&Kt[4 * f4];
            *(float4*)&Vs[r][c] = *(const float4*)&Vt[4 * f4];
        }
        __syncthreads();
        const unsigned long long mbits = __ballot(mb[k0 + lane] != 0);
        if (mbits == 0ULL) continue;
        for (int c0 = 0; c0 < 64; c0 += 16) {
            const unsigned bits = (unsigned)((mbits >> c0) & 0xFFFFULL);
            if (!bits) continue;
            float sc[16];
            #pragma unroll
            for (int j = 0; j < 16; ++j) {
                if (!((bits >> j) & 1u)) { sc[j] = -INFINITY; continue; }
                float a0 = 0.f, a1 = 0.f, a2 = 0.f, a3 = 0.f;
                #pragma unroll
                for (int d4 = 0; d4 < 16; ++d4) {
                    const float4 kv = *(const float4*)&Ks[c0 + j][4 * d4];
                    a0 += q[4*d4] * kv.x; a1 += q[4*d4+1] * kv.y;
                    a2 += q[4*d4+2] * kv.z; a3 += q[4*d4+3] * kv.w;
                }
                sc[j] = ((a0 + a1) + (a2 + a3)) * 0.125f;
            }
            float cmax = sc[0];
            #pragma unroll
            for (int j = 1; j < 16; ++j) cmax = fmaxf(cmax, sc[j]);
            if (cmax > m) {
                const float scale = __expf(m - cmax);
                l *= scale;
                #pragma unroll
                for (int d = 0; d < DK; ++d) ctx[d] *= scale;
                m = cmax;
            }
            #pragma unroll
            for (int j = 0; j < 16; ++j) {
                if (!((bits >> j) & 1u)) continue;
                const float p = __expf(sc[j] - m);
                l += p;
                #pragma unroll
                for (int d4 = 0; d4 < 16; ++d4) {
                    const float4 vv = *(const float4*)&Vs[c0 + j][4 * d4];
                    ctx[4*d4] += p * vv.x; ctx[4*d4+1] += p * vv.y;
                    ctx[4*d4+2] += p * vv.z; ctx[4*d4+3] += p * vv.w;
                }
            }
        }
    }
    const float inv = (l > 0.f) ? (1.f / l) : 0.f;
    float* dst = OUT + ((size_t)(b * SEQ + row)) * D_MODEL + h * DK;
    #pragma unroll
    for (int d4 = 0; d4 < 16; ++d4) {
        float4 o;
        o.x = ctx[4*d4] * inv; o.y = ctx[4*d4+1] * inv;
        o.z = ctx[4*d4+2] * inv; o.w = ctx[4*d4+3] * inv;
        *(float4*)&dst[4 * d4] = o;
    }
}

// ---------------------------------------------------------------------------
extern "C" void kernel_launch(void* const* d_in, const int* in_sizes, int n_in,
                              void* d_out, int out_size, void* d_ws, size_t ws_size,
                              hipStream_t stream)
{
    const float* query = (const float*)d_in[0];
    const float* key_  = (const float*)d_in[1];
    const float* value = (const float*)d_in[2];
    const int*   mask  = (const int*)d_in[3];
    const float* Wq = (const float*)d_in[4];
    const float* bq = (const float*)d_in[5];
    const float* Wk = (const float*)d_in[6];
    const float* bk = (const float*)d_in[7];
    const float* Wv = (const float*)d_in[8];
    const float* bv = (const float*)d_in[9];
    const float* Wo = (const float*)d_in[10];
    const float* bo = (const float*)d_in[11];
    float* out = (float*)d_out;

    const int M = BATCH * SEQ;                            // 4096
    const size_t ACT_B = (size_t)M * 1024 * 2;            // 8.39 MB (fp16)
    const size_t W_B   = (size_t)D_MODEL * 1024 * 2;      // 2.10 MB (fp16)
    const size_t K2_B  = (size_t)32 * SEQ * 64 * 2;       // 8.39 MB
    const size_t VT2_B = (size_t)32 * DK * SEQ * 2;       // 8.39 MB
    const size_t Q2_B  = K2_B;                            // 8.39 MB
    const size_t POS_B = (size_t)BATCH * SEQ * 4 + 256;

    char* base = (char*)d_ws;
    _Float16* actQh = (_Float16*)(base);
    _Float16* actKh = (_Float16*)(base + ACT_B);
    _Float16* actVh = (_Float16*)(base + 2 * ACT_B);
    _Float16* actO  = (_Float16*)(base + 3 * ACT_B);
    _Float16* w2qh  = (_Float16*)(base + 4 * ACT_B);
    _Float16* w2kh  = (_Float16*)((char*)w2qh + W_B);
    _Float16* w2vh  = (_Float16*)((char*)w2kh + W_B);
    _Float16* w2oh  = (_Float16*)((char*)w2vh + W_B);
    _Float16* k2    = (_Float16*)((char*)w2oh + W_B);
    _Float16* vt2   = (_Float16*)((char*)k2 + K2_B);
    _Float16* q2    = (_Float16*)((char*)vt2 + VT2_B);
    int* posArr = (int*)((char*)q2 + Q2_B);
    int* ncArr  = posArr + BATCH * SEQ;
    const size_t need = 4 * ACT_B + 4 * W_B + K2_B + VT2_B + Q2_B + POS_B; // ~67 MB

    if (ws_size >= need) {
        mask_scan_kernel<<<BATCH, 256, 0, stream>>>(mask, posArr, ncArr);

        // ALL 7 conversions in one dispatch (weights + inputs)
        conv_all_kernel<<<dim3(2048, 7), 256, 0, stream>>>(
            Wq, Wk, Wv, Wo, query, key_, value,
            w2qh, w2kh, w2vh, w2oh, actQh, actKh, actVh, mask, posArr);

        dim3 ggrid(M / 128, D_MODEL / 64);                // 32 x 16 = 512 blocks
        mfma_gemm_f16_kernel<2><<<ggrid, 256, 0, stream>>>(
            actKh, w2kh, bk, nullptr, k2, ncArr);
        mfma_gemm_f16_kernel<3><<<ggrid, 256, 0, stream>>>(
            actVh, w2vh, bv, nullptr, vt2, ncArr);
        mfma_gemm_f16_kernel<1><<<ggrid, 256, 0, stream>>>(
            actQh, w2qh, bq, nullptr, q2, ncArr);

        attn_mfma_kernel<<<1024, 256, 0, stream>>>(q2, k2, vt2, ncArr, actO);

        mfma_gemm_f16_kernel<0><<<ggrid, 256, 0, stream>>>(
            actO, w2oh, bo, out, nullptr, ncArr);
    } else {
        float* q_ws = (float*)(base);
        float* k_ws = (float*)(base + (size_t)M * D_MODEL * 4);
        float* v_ws = (float*)(base + 2 * (size_t)M * D_MODEL * 4);
        float* c_ws = (float*)(base + 3 * (size_t)M * D_MODEL * 4);
        dim3 ggrid(M / 64, D_MODEL / 64);
        gemm_bias_kernel<1><<<ggrid, 256, 0, stream>>>(query, Wq, bq, q_ws, M, D_MODEL, D_MODEL);
        gemm_bias_kernel<1><<<ggrid, 256, 0, stream>>>(key_,  Wk, bk, k_ws, M, D_MODEL, D_MODEL);
        gemm_bias_kernel<1><<<ggrid, 256, 0, stream>>>(value, Wv, bv, v_ws, M, D_MODEL, D_MODEL);
        dim3 agrid(SEQ / 256, NUM_HEADS, BATCH);
        attn_fp32_kernel<<<agrid, 256, 0, stream>>>(q_ws, k_ws, v_ws, mask, c_ws);
        gemm_bias_kernel<0><<<ggrid, 256, 0, stream>>>(c_ws, Wo, bo, out, M, D_MODEL, D_MODEL);
    }
}